// Round 10
// baseline (261.073 us; speedup 1.0000x reference)
//
#include <hip/hip_runtime.h>
#include <hip/hip_bf16.h>
#include <math.h>

#define BB 2
#define SS 2048
#define EE 512
#define HH 8
#define NN (BB*SS)
#define JC1 8   // denoms j-chunks (256 j each)
#define JCP 4   // fused ew+pv j-chunks (512 j each)

typedef __attribute__((ext_vector_type(8))) short short8;
typedef __attribute__((ext_vector_type(4))) float f32x4;

__device__ __forceinline__ float b2f(short v){
    return __uint_as_float(((unsigned)(unsigned short)v) << 16);
}
__device__ __forceinline__ unsigned f2bf(float f){
    unsigned u = __float_as_uint(f);
    u += 0x7fffu + ((u >> 16) & 1u);
    return u >> 16;
}
__device__ __forceinline__ void stage16_f32(const float* __restrict__ src,
                                            __hip_bfloat16* dst){
    const float4 f0 = *reinterpret_cast<const float4*>(src);
    const float4 f1 = *reinterpret_cast<const float4*>(src + 4);
    const float4 f2 = *reinterpret_cast<const float4*>(src + 8);
    const float4 f3 = *reinterpret_cast<const float4*>(src + 12);
    uint4 o0, o1;
    o0.x = f2bf(f0.x) | (f2bf(f0.y) << 16);
    o0.y = f2bf(f0.z) | (f2bf(f0.w) << 16);
    o0.z = f2bf(f1.x) | (f2bf(f1.y) << 16);
    o0.w = f2bf(f1.z) | (f2bf(f1.w) << 16);
    o1.x = f2bf(f2.x) | (f2bf(f2.y) << 16);
    o1.y = f2bf(f2.z) | (f2bf(f2.w) << 16);
    o1.z = f2bf(f3.x) | (f2bf(f3.y) << 16);
    o1.w = f2bf(f3.z) | (f2bf(f3.w) << 16);
    *reinterpret_cast<uint4*>(dst) = o0;
    *reinterpret_cast<uint4*>(dst + 8) = o1;
}
__device__ __forceinline__ void stage16_b16(const __hip_bfloat16* __restrict__ src,
                                            __hip_bfloat16* dst){
    const uint4* s = reinterpret_cast<const uint4*>(src);
    uint4* d = reinterpret_cast<uint4*>(dst);
    d[0] = s[0]; d[1] = s[1];
}

// ---------------- one-time f32 -> bf16 conversion of x + 6 weights ----------------
__global__ void conv_bf16(
    const float* s0, const float* s1, const float* s2, const float* s3,
    const float* s4, const float* s5, const float* s6,
    __hip_bfloat16* d0, __hip_bfloat16* d1, __hip_bfloat16* d2, __hip_bfloat16* d3,
    __hip_bfloat16* d4, __hip_bfloat16* d5, __hip_bfloat16* d6)
{
    const int which = blockIdx.y;
    const float* s; __hip_bfloat16* d; int n;
    switch (which) {
        case 0: s = s0; d = d0; n = 2097152; break;
        case 1: s = s1; d = d1; n = 262144; break;
        case 2: s = s2; d = d2; n = 262144; break;
        case 3: s = s3; d = d3; n = 262144; break;
        case 4: s = s4; d = d4; n = 266240; break;
        case 5: s = s5; d = d5; n = 262144; break;
        default: s = s6; d = d6; n = 262144; break;
    }
    const int base = (blockIdx.x * 256 + threadIdx.x) * 4;
    if (base >= n) return;
    const float4 f = *reinterpret_cast<const float4*>(s + base);
    uint2 o;
    o.x = f2bf(f.x) | (f2bf(f.y) << 16);
    o.y = f2bf(f.z) | (f2bf(f.w) << 16);
    *reinterpret_cast<uint2*>(d + base) = o;
}

// ---------------- fused QKV projection (MFMA) ----------------
template<int B16>
__global__ __launch_bounds__(256) void qkv_gemm(
    const void* __restrict__ x,
    const void* __restrict__ Wq, const float* __restrict__ bq,
    const void* __restrict__ Wk, const float* __restrict__ bk,
    const void* __restrict__ Wv, const float* __restrict__ bv,
    __hip_bfloat16* __restrict__ qb,
    __hip_bfloat16* __restrict__ kb,
    __hip_bfloat16* __restrict__ vT)
{
    __shared__ __hip_bfloat16 As[64][72];
    __shared__ __hip_bfloat16 Bs[64][72];
    const int tid = threadIdx.x;
    const int which = blockIdx.x >> 3;
    const int col0 = (blockIdx.x & 7) * 64;
    const int row0 = blockIdx.y * 64;
    const int wv = tid >> 6, lane = tid & 63, quad = lane >> 4, m16 = lane & 15;
    const int sr = tid >> 2;
    const int sc = (tid & 3) * 16;
    const void* W    = (which == 0) ? Wq : (which == 1) ? Wk : Wv;
    const float* bias = (which == 0) ? bq : (which == 1) ? bk : bv;

    f32x4 acc[4];
    #pragma unroll
    for (int nt = 0; nt < 4; ++nt) acc[nt] = (f32x4){0.f, 0.f, 0.f, 0.f};

    for (int k0 = 0; k0 < 512; k0 += 64) {
        if (B16) {
            stage16_b16((const __hip_bfloat16*)x + (size_t)(row0 + sr) * EE + k0 + sc, &As[sr][sc]);
            stage16_b16((const __hip_bfloat16*)W + (size_t)(col0 + sr) * EE + k0 + sc, &Bs[sr][sc]);
        } else {
            stage16_f32((const float*)x + (size_t)(row0 + sr) * EE + k0 + sc, &As[sr][sc]);
            stage16_f32((const float*)W + (size_t)(col0 + sr) * EE + k0 + sc, &Bs[sr][sc]);
        }
        __syncthreads();
        #pragma unroll
        for (int ks = 0; ks < 2; ++ks) {
            const short8 a = *reinterpret_cast<const short8*>(
                &As[wv * 16 + m16][ks * 32 + quad * 8]);
            #pragma unroll
            for (int nt = 0; nt < 4; ++nt) {
                const short8 b = *reinterpret_cast<const short8*>(
                    &Bs[nt * 16 + m16][ks * 32 + quad * 8]);
                acc[nt] = __builtin_amdgcn_mfma_f32_16x16x32_bf16(a, b, acc[nt], 0, 0, 0);
            }
        }
        __syncthreads();
    }

    if (which == 2) {
        #pragma unroll
        for (int nt = 0; nt < 4; ++nt) {
            const float bb = bias[col0 + nt * 16 + m16];
            #pragma unroll
            for (int r = 0; r < 4; ++r)
                Bs[wv * 16 + quad * 4 + r][nt * 16 + m16] =
                    __float2bfloat16(acc[nt][r] + bb);
        }
        __syncthreads();
        const int bb2 = row0 >> 11;
        const int j0 = row0 & (SS - 1);
        const int er = tid >> 2;
        const int js = (tid & 3) * 16;
        unsigned pk[8];
        #pragma unroll
        for (int p = 0; p < 8; ++p) {
            const unsigned lo = *reinterpret_cast<const unsigned short*>(&Bs[js + 2*p][er]);
            const unsigned hi = *reinterpret_cast<const unsigned short*>(&Bs[js + 2*p + 1][er]);
            pk[p] = lo | (hi << 16);
        }
        uint4 s0; s0.x = pk[0]; s0.y = pk[1]; s0.z = pk[2]; s0.w = pk[3];
        uint4 s1; s1.x = pk[4]; s1.y = pk[5]; s1.z = pk[6]; s1.w = pk[7];
        __hip_bfloat16* dst = vT + ((size_t)(bb2 * EE + col0 + er)) * SS + j0 + js;
        *reinterpret_cast<uint4*>(dst) = s0;
        *reinterpret_cast<uint4*>(dst + 8) = s1;
    } else {
        __hip_bfloat16* C = (which == 0) ? qb : kb;
        #pragma unroll
        for (int nt = 0; nt < 4; ++nt) {
            const int gn = col0 + nt * 16 + m16;
            const float bb = bias[gn];
            #pragma unroll
            for (int r = 0; r < 4; ++r) {
                const int gm = row0 + wv * 16 + quad * 4 + r;
                C[(size_t)gm * EE + gn] = __float2bfloat16(acc[nt][r] + bb);
            }
        }
    }
}

// ---------------- MFMA GEMM (MLP1 / MLP2 / out-proj) ----------------
template<int MODE, int AB16, int WB16, int CF32>
__global__ __launch_bounds__(256) void gemm_bt(
    const void* __restrict__ Av,
    const void* __restrict__ Wv_,
    const float* __restrict__ bias,
    void* __restrict__ Cv,
    int ldb)
{
    __shared__ __hip_bfloat16 As[64][72];
    __shared__ __hip_bfloat16 Bs[64][72];
    const int tid = threadIdx.x;
    const int col0 = blockIdx.x * 64;
    const int row0 = blockIdx.y * 64;
    const int wv = tid >> 6, lane = tid & 63, quad = lane >> 4, m16 = lane & 15;
    const int sr = tid >> 2;
    const int sc = (tid & 3) * 16;

    f32x4 acc[4];
    #pragma unroll
    for (int nt = 0; nt < 4; ++nt) acc[nt] = (f32x4){0.f, 0.f, 0.f, 0.f};

    for (int k0 = 0; k0 < 512; k0 += 64) {
        if (AB16)
            stage16_b16((const __hip_bfloat16*)Av + (size_t)(row0 + sr) * EE + k0 + sc, &As[sr][sc]);
        else
            stage16_f32((const float*)Av + (size_t)(row0 + sr) * EE + k0 + sc, &As[sr][sc]);
        if (WB16)
            stage16_b16((const __hip_bfloat16*)Wv_ + (size_t)(col0 + sr) * ldb + k0 + sc, &Bs[sr][sc]);
        else
            stage16_f32((const float*)Wv_ + (size_t)(col0 + sr) * ldb + k0 + sc, &Bs[sr][sc]);
        __syncthreads();
        #pragma unroll
        for (int ks = 0; ks < 2; ++ks) {
            const short8 a = *reinterpret_cast<const short8*>(
                &As[wv * 16 + m16][ks * 32 + quad * 8]);
            #pragma unroll
            for (int nt = 0; nt < 4; ++nt) {
                const short8 b = *reinterpret_cast<const short8*>(
                    &Bs[nt * 16 + m16][ks * 32 + quad * 8]);
                acc[nt] = __builtin_amdgcn_mfma_f32_16x16x32_bf16(a, b, acc[nt], 0, 0, 0);
            }
        }
        __syncthreads();
    }

    #pragma unroll
    for (int nt = 0; nt < 4; ++nt) {
        const int gn = col0 + nt * 16 + m16;
        float bb = bias[gn];
        if (MODE == 1) {
            float ts = 0.f;
            #pragma unroll
            for (int h = 0; h < 8; ++h) {
                const size_t wi = (size_t)gn * ldb + 512 + h;
                ts += WB16 ? (float)((const __hip_bfloat16*)Wv_)[wi]
                           : ((const float*)Wv_)[wi];
            }
            bb += ts * (1.0f / (float)SS);
        }
        #pragma unroll
        for (int r = 0; r < 4; ++r) {
            const int gm = row0 + wv * 16 + quad * 4 + r;
            const size_t ci = (size_t)gm * EE + gn;
            float c = acc[nt][r] + bb;
            if (MODE == 1) c = 0.5f * c * (1.0f + erff(c * 0.70710678118654752f));
            if (MODE == 2) c += (float)((const __hip_bfloat16*)Cv)[ci];
            if (CF32) ((float*)Cv)[ci] = c;
            else      ((__hip_bfloat16*)Cv)[ci] = __float2bfloat16(c);
        }
    }
}

// ---------------- K1: partial softmax denominators (R4-verbatim) ----------------
// Double-buffered K tile, 1 barrier per 16-j tile, issue-early/write-late.
// Staging conflict-free: lane t writes 16B at col t*8 + k*128.
__global__ __launch_bounds__(256) void attn_denoms(
    const __hip_bfloat16* __restrict__ qws,
    const __hip_bfloat16* __restrict__ kws,
    float* __restrict__ dnP,
    int* __restrict__ cntI)
{
    __shared__ __hip_bfloat16 KL[2][16][520];   // 33.3 KB
    const int tid = threadIdx.x;
    const int wv = tid >> 6, lane = tid & 63, quad = lane >> 4, m16 = lane & 15;
    const int jc = blockIdx.x;              // 8 chunks x 256 j
    const int it = blockIdx.y;              // 32 tiles x 64 i
    const int b  = blockIdx.z;
    const size_t g0 = (size_t)b * SS + it * 64;
    const size_t gb = (size_t)b * SS;

    if (jc == 0 && tid < 64) cntI[g0 + tid] = 0;

    short8 aq[HH][2];
    #pragma unroll
    for (int h = 0; h < HH; ++h)
        #pragma unroll
        for (int ks = 0; ks < 2; ++ks)
            aq[h][ks] = *reinterpret_cast<const short8*>(
                qws + (g0 + wv * 16 + m16) * EE + h * 64 + ks * 32 + quad * 8);

    float dph[HH][4];
    #pragma unroll
    for (int h = 0; h < HH; ++h)
        #pragma unroll
        for (int r = 0; r < 4; ++r) dph[h][r] = 0.f;

    const int srow = tid >> 4, t4 = tid & 15;
    {   // initial stage: tile 0 -> KL[0] (conflict-free pattern)
        #pragma unroll
        for (int k = 0; k < 4; ++k)
            *reinterpret_cast<uint4*>(&KL[0][srow][t4 * 8 + k * 128]) =
                *reinterpret_cast<const uint4*>(
                    kws + (gb + jc * 256 + srow) * EE + t4 * 8 + k * 128);
    }

    for (int jt = 0; jt < 16; ++jt) {
        __syncthreads();                       // KL[jt&1] ready
        uint4 kr[4];
        if (jt + 1 < 16) {                     // issue-early: next tile -> regs
            #pragma unroll
            for (int k = 0; k < 4; ++k)
                kr[k] = *reinterpret_cast<const uint4*>(
                    kws + (gb + jc * 256 + (jt + 1) * 16 + srow) * EE + t4 * 8 + k * 128);
        }
        #pragma unroll
        for (int h = 0; h < HH; ++h) {
            const short8 b0 = *reinterpret_cast<const short8*>(&KL[jt & 1][m16][h * 64 + quad * 8]);
            const short8 b1 = *reinterpret_cast<const short8*>(&KL[jt & 1][m16][h * 64 + 32 + quad * 8]);
            f32x4 c = {0.f, 0.f, 0.f, 0.f};
            c = __builtin_amdgcn_mfma_f32_16x16x32_bf16(aq[h][0], b0, c, 0, 0, 0);
            c = __builtin_amdgcn_mfma_f32_16x16x32_bf16(aq[h][1], b1, c, 0, 0, 0);
            #pragma unroll
            for (int r = 0; r < 4; ++r) dph[h][r] += __expf(c[r] * 0.125f);
        }
        if (jt + 1 < 16) {                     // write-late into the spare buffer
            #pragma unroll
            for (int k = 0; k < 4; ++k)
                *reinterpret_cast<uint4*>(&KL[(jt + 1) & 1][srow][t4 * 8 + k * 128]) = kr[k];
        }
    }

    #pragma unroll
    for (int h = 0; h < HH; ++h)
        #pragma unroll
        for (int off = 1; off <= 8; off <<= 1)
            #pragma unroll
            for (int r = 0; r < 4; ++r) dph[h][r] += __shfl_xor(dph[h][r], off, 64);
    if (m16 == 0) {
        const size_t i = (size_t)it * 64 + wv * 16 + quad * 4;
        #pragma unroll
        for (int h = 0; h < HH; ++h)
            #pragma unroll
            for (int r = 0; r < 4; ++r)
                dnP[((size_t)(jc * BB + b) * SS + i + r) * HH + h] = dph[h][r];
    }
}

// ---------------- K2: fused ew + PV (R4 structure, e-split across 2 blocks) ----------------
// Block = 32 i x 512 j x 256 e (eh half). Grid (8, 64, 2) = 1024 blocks ->
// 4 blocks/CU (LDS 36.9 KB). Both eh blocks compute identical scores (MFMA
// was 9.5% util -> duplication nearly free); PV only for own 256 e-cols
// (acc 64->32 regs). Threshold/slot atomics gated to eh==0 (exact semantics).
// R9 bug fixed: epilogue copy-out now writes all 4 uint4 (32 elems) per
// thread (was 2 -> half the pvP columns never written, absmax 1.17e-2).
__global__ __launch_bounds__(256, 2) void attn_ewpv(
    const __hip_bfloat16* __restrict__ qws,
    const __hip_bfloat16* __restrict__ kws,
    const __hip_bfloat16* __restrict__ vTg,
    const float* __restrict__ dnP,
    int* __restrict__ cntI,
    int* __restrict__ slotJ,
    float* __restrict__ slotW,
    __hip_bfloat16* __restrict__ pvP)
{
    __shared__ __hip_bfloat16 KL[32][520];     // 33.3 KB (reused as epilogue bounce)
    __shared__ __hip_bfloat16 ewT[32][40];     // 2.6 KB
    __shared__ float invd[HH][32];             // 1 KB
    const int tid = threadIdx.x;
    const int wv = tid >> 6, lane = tid & 63, quad = lane >> 4, m16 = lane & 15;
    const int bx = blockIdx.x;               // 8 = 4 jc x 2 eh
    const int jc = bx >> 1;                  // 4 chunks x 512 j
    const int eh = bx & 1;                   // e-half (0: e<256, 1: e>=256)
    const int it = blockIdx.y;               // 64 tiles x 32 i
    const int b  = blockIdx.z;
    const size_t gb = (size_t)b * SS;
    const size_t g0 = gb + it * 32;
    const int ih = wv & 1;                   // i-half for score phase
    const int jh = wv >> 1;                  // j-half for score phase

    {   // denominators -> 0.125/D (head-mean folded in); 256 thr = HH*32 exactly
        const int h = tid >> 5, i = tid & 31;
        float s = 0.f;
        #pragma unroll
        for (int c = 0; c < JC1; ++c)
            s += dnP[((size_t)(c * BB + b) * SS + it * 32 + i) * HH + h];
        invd[h][i] = 0.125f / s;
    }

    short8 aq[HH][2];
    #pragma unroll
    for (int h = 0; h < HH; ++h)
        #pragma unroll
        for (int ks = 0; ks < 2; ++ks)
            aq[h][ks] = *reinterpret_cast<const short8*>(
                qws + (g0 + ih * 16 + m16) * EE + h * 64 + ks * 32 + quad * 8);

    f32x4 acc[2][4];
    #pragma unroll
    for (int mf = 0; mf < 2; ++mf)
        #pragma unroll
        for (int nf = 0; nf < 4; ++nf) acc[mf][nf] = (f32x4){0.f, 0.f, 0.f, 0.f};

    const int krow = tid >> 4, kcol = (tid & 15) * 32;
    // per-lane V row base: e = eh*256 + wv*64 + nf*16 + m16, k-offset quad*8
    const __hip_bfloat16* vrow0 =
        vTg + ((size_t)b * EE + eh * 256 + wv * 64 + m16) * SS + quad * 8;

    for (int st = 0; st < 16; ++st) {
        const int j0 = jc * 512 + st * 32;
        // stage K subtile [32 j][512 feat] (global -> reg -> LDS, short-lived)
        #pragma unroll
        for (int rr = 0; rr < 2; ++rr) {
            const uint4* src = reinterpret_cast<const uint4*>(
                kws + (gb + j0 + rr * 16 + krow) * EE + kcol);
            uint4* dst = reinterpret_cast<uint4*>(&KL[rr * 16 + krow][kcol]);
            dst[0] = src[0]; dst[1] = src[1]; dst[2] = src[2]; dst[3] = src[3];
        }
        __syncthreads();                       // KL ready; prev-step PV done w/ ewT

        // scores: wave's (ih, jh) quadrant of the 32x32 tile, all heads
        float wsum[4] = {0.f, 0.f, 0.f, 0.f};
        #pragma unroll
        for (int h = 0; h < HH; ++h) {
            const short8 b0 = *reinterpret_cast<const short8*>(
                &KL[jh * 16 + m16][h * 64 + quad * 8]);
            const short8 b1 = *reinterpret_cast<const short8*>(
                &KL[jh * 16 + m16][h * 64 + 32 + quad * 8]);
            f32x4 c = {0.f, 0.f, 0.f, 0.f};
            c = __builtin_amdgcn_mfma_f32_16x16x32_bf16(aq[h][0], b0, c, 0, 0, 0);
            c = __builtin_amdgcn_mfma_f32_16x16x32_bf16(aq[h][1], b1, c, 0, 0, 0);
            #pragma unroll
            for (int r = 0; r < 4; ++r)
                wsum[r] += __expf(c[r] * 0.125f) * invd[h][ih * 16 + quad * 4 + r];
        }
        #pragma unroll
        for (int r = 0; r < 4; ++r) {
            const __hip_bfloat16 wb = __float2bfloat16(wsum[r]);
            ewT[ih * 16 + quad * 4 + r][jh * 16 + m16] = wb;
            if (eh == 0 && (float)wb > 0.1f) { // rare: adjacency crossing (eh0 only)
                const int li = ih * 16 + quad * 4 + r;
                const int idx = atomicAdd(&cntI[g0 + li], 1);
                if (idx < 16) {
                    slotJ[((size_t)g0 + li) * 16 + idx] = j0 + jh * 16 + m16;
                    slotW[((size_t)g0 + li) * 16 + idx] = (float)wb;
                }
            }
        }
        __syncthreads();                       // ewT ready

        // PV: V B-frags straight from global (L2-resident), consumed immediately
        {
            short8 vb[4];
            #pragma unroll
            for (int nf = 0; nf < 4; ++nf)
                vb[nf] = *reinterpret_cast<const short8*>(vrow0 + (size_t)(nf * 16) * SS + j0);
            const short8 a0 = *reinterpret_cast<const short8*>(&ewT[m16][quad * 8]);
            const short8 a1 = *reinterpret_cast<const short8*>(&ewT[16 + m16][quad * 8]);
            #pragma unroll
            for (int nf = 0; nf < 4; ++nf) {
                acc[0][nf] = __builtin_amdgcn_mfma_f32_16x16x32_bf16(a0, vb[nf], acc[0][nf], 0, 0, 0);
                acc[1][nf] = __builtin_amdgcn_mfma_f32_16x16x32_bf16(a1, vb[nf], acc[1][nf], 0, 0, 0);
            }
        }
    }

    // epilogue: bounce acc through KL (cols 0..255 = this eh half) for
    // coalesced bf16 writes. 32 rows x 256 cols; 8 thr/row x 32 elems each.
    #pragma unroll
    for (int mf = 0; mf < 2; ++mf)
        #pragma unroll
        for (int nf = 0; nf < 4; ++nf)
            #pragma unroll
            for (int r = 0; r < 4; ++r)
                KL[mf * 16 + quad * 4 + r][wv * 64 + nf * 16 + m16] =
                    __float2bfloat16(acc[mf][nf][r]);
    __syncthreads();
    const int orow = tid >> 3;                 // 32 rows x 8 threads
    const int oc = (tid & 7) * 32;             // 8 x 32 elements = 256
    const uint4* s = reinterpret_cast<const uint4*>(&KL[orow][oc]);
    uint4* d = reinterpret_cast<uint4*>(
        pvP + ((size_t)jc * NN + g0 + orow) * EE + eh * 256 + oc);
    #pragma unroll
    for (int q = 0; q < 4; ++q) d[q] = s[q];   // 4 x 16B = 32 elems (R9 bug: was 2)

}

// ---------------- K3: combine PV partials + rare messages path ----------------
__global__ __launch_bounds__(256) void pv_combine(
    const __hip_bfloat16* __restrict__ pvP,
    const int* __restrict__ cntI,
    const int* __restrict__ slotJ,
    const float* __restrict__ slotW,
    const float* __restrict__ x,
    __hip_bfloat16* __restrict__ u1out)
{
    const int tid = threadIdx.x;
    const int row = blockIdx.x * 4 + (tid >> 6);   // [0, NN)
    const int e0 = (tid & 63) * 8;
    float s[8] = {0.f, 0.f, 0.f, 0.f, 0.f, 0.f, 0.f, 0.f};
    #pragma unroll
    for (int c = 0; c < JCP; ++c) {
        const short8 v = *reinterpret_cast<const short8*>(
            pvP + ((size_t)c * NN + row) * EE + e0);
        #pragma unroll
        for (int k = 0; k < 8; ++k) s[k] += b2f(v[k]);
    }
    const int cn = cntI[row];
    if (cn > 0) {                                  // exact rare path: masked mean
        const float inv = 1.f / (float)cn;
        const int ns = cn < 16 ? cn : 16;
        const int b = row >> 11;
        for (int t = 0; t < ns; ++t) {
            const int j = slotJ[(size_t)row * 16 + t];
            const float w = slotW[(size_t)row * 16 + t] * inv;
            const float* xr = x + ((size_t)b * SS + j) * EE + e0;
            #pragma unroll
            for (int k = 0; k < 8; ++k) s[k] += w * xr[k];
        }
    }
    short8 o;
    #pragma unroll
    for (int k = 0; k < 8; ++k) o[k] = (short)f2bf(s[k]);
    *reinterpret_cast<short8*>(u1out + (size_t)row * EE + e0) = o;
}

extern "C" void kernel_launch(void* const* d_in, const int* in_sizes, int n_in,
                              void* d_out, int out_size, void* d_ws, size_t ws_size,
                              hipStream_t stream)
{
    const float* x   = (const float*)d_in[0];
    const float* Wq  = (const float*)d_in[1];
    const float* bq  = (const float*)d_in[2];
    const float* Wk  = (const float*)d_in[3];
    const float* bk  = (const float*)d_in[4];
    const float* Wv  = (const float*)d_in[5];
    const float* bv  = (const float*)d_in[6];
    const float* Wm1 = (const float*)d_in[7];
    const float* bm1 = (const float*)d_in[8];
    const float* Wm2 = (const float*)d_in[9];
    const float* bm2 = (const float*)d_in[10];
    const float* Wo  = (const float*)d_in[11];
    const float* bo  = (const float*)d_in[12];

    char* ws = (char*)d_ws;
    const size_t MB = 1024 * 1024;
    __hip_bfloat16* qb = (__hip_bfloat16*)(ws + 0);        // q -> u1 -> t   4MB
    __hip_bfloat16* kb = (__hip_bfloat16*)(ws + 4*MB);     // k -> hm        4MB
    __hip_bfloat16* vT = (__hip_bfloat16*)(ws + 8*MB);     // V^T [b][e][j]  4MB
    __hip_bfloat16* pvP = (__hip_bfloat16*)(ws + 12*MB);   // PV partials [4][NN][EE] 16MB
    float* dnP = (float*)(ws + 28*MB);                     // denom partials 1MB
    int*   cntI = (int*)(ws + 29*MB);                      // neighbor cnt  16KB
    int*   slotJ = (int*)(ws + 29*MB + 64*1024);           // crossing j    256KB
    float* slotW = (float*)(ws + 29*MB + 384*1024);        // crossing w    256KB
    const bool EXT = (ws_size >= 38 * MB);
    __hip_bfloat16* xb   = (__hip_bfloat16*)(ws + 30*MB);          // 4MB
    __hip_bfloat16* wqb  = (__hip_bfloat16*)(ws + 34*MB);
    __hip_bfloat16* wkb  = (__hip_bfloat16*)(ws + 34*MB + 512*1024);
    __hip_bfloat16* wvb  = (__hip_bfloat16*)(ws + 35*MB);
    __hip_bfloat16* wm1b = (__hip_bfloat16*)(ws + 35*MB + 512*1024);
    __hip_bfloat16* wm2b = (__hip_bfloat16*)(ws + 36*MB + 256*1024);
    __hip_bfloat16* wob  = (__hip_bfloat16*)(ws + 36*MB + 768*1024);

    dim3 blk(256, 1, 1);
    dim3 gg(EE / 64, NN / 64, 1);

    if (EXT) {
        conv_bf16<<<dim3(2048, 7, 1), blk, 0, stream>>>(
            x, Wq, Wk, Wv, Wm1, Wm2, Wo, xb, wqb, wkb, wvb, wm1b, wm2b, wob);
        qkv_gemm<1><<<dim3(24, NN / 64, 1), blk, 0, stream>>>(
            xb, wqb, bq, wkb, bk, wvb, bv, qb, kb, vT);
    } else {
        qkv_gemm<0><<<dim3(24, NN / 64, 1), blk, 0, stream>>>(
            x, Wq, bq, Wk, bk, Wv, bv, qb, kb, vT);
    }
    attn_denoms<<<dim3(JC1, SS / 64, BB), blk, 0, stream>>>(qb, kb, dnP, cntI);
    attn_ewpv<<<dim3(JCP * 2, SS / 32, BB), blk, 0, stream>>>(
        qb, kb, vT, dnP, cntI, slotJ, slotW, pvP);
    pv_combine<<<dim3(NN / 4, 1, 1), blk, 0, stream>>>(
        pvP, cntI, slotJ, slotW, x, qb);                            // u1 -> qb
    if (EXT) {
        gemm_bt<1,1,1,0><<<gg, blk, 0, stream>>>(xb, wm1b, bm1, kb, EE + HH);
        gemm_bt<2,1,1,0><<<gg, blk, 0, stream>>>(kb, wm2b, bm2, qb, EE);
        gemm_bt<0,1,1,1><<<gg, blk, 0, stream>>>(qb, wob, bo, d_out, EE);
    } else {
        gemm_bt<1,0,0,0><<<gg, blk, 0, stream>>>(x, Wm1, bm1, kb, EE + HH);
        gemm_bt<2,1,0,0><<<gg, blk, 0, stream>>>(kb, Wm2, bm2, qb, EE);
        gemm_bt<0,1,0,1><<<gg, blk, 0, stream>>>(qb, Wo, bo, d_out, EE);
    }
}

// Round 11
// 221.950 us; speedup vs baseline: 1.1763x; 1.1763x over previous
//
#include <hip/hip_runtime.h>
#include <hip/hip_bf16.h>
#include <math.h>

#define BB 2
#define SS 2048
#define EE 512
#define HH 8
#define NN (BB*SS)
#define JC1 8   // denoms j-chunks (256 j each)
#define JCP 4   // fused ew+pv j-chunks (512 j each)

typedef __attribute__((ext_vector_type(8))) short short8;
typedef __attribute__((ext_vector_type(4))) float f32x4;

__device__ __forceinline__ float b2f(short v){
    return __uint_as_float(((unsigned)(unsigned short)v) << 16);
}
__device__ __forceinline__ unsigned f2bf(float f){
    unsigned u = __float_as_uint(f);
    u += 0x7fffu + ((u >> 16) & 1u);
    return u >> 16;
}
__device__ __forceinline__ void stage16_f32(const float* __restrict__ src,
                                            __hip_bfloat16* dst){
    const float4 f0 = *reinterpret_cast<const float4*>(src);
    const float4 f1 = *reinterpret_cast<const float4*>(src + 4);
    const float4 f2 = *reinterpret_cast<const float4*>(src + 8);
    const float4 f3 = *reinterpret_cast<const float4*>(src + 12);
    uint4 o0, o1;
    o0.x = f2bf(f0.x) | (f2bf(f0.y) << 16);
    o0.y = f2bf(f0.z) | (f2bf(f0.w) << 16);
    o0.z = f2bf(f1.x) | (f2bf(f1.y) << 16);
    o0.w = f2bf(f1.z) | (f2bf(f1.w) << 16);
    o1.x = f2bf(f2.x) | (f2bf(f2.y) << 16);
    o1.y = f2bf(f2.z) | (f2bf(f2.w) << 16);
    o1.z = f2bf(f3.x) | (f2bf(f3.y) << 16);
    o1.w = f2bf(f3.z) | (f2bf(f3.w) << 16);
    *reinterpret_cast<uint4*>(dst) = o0;
    *reinterpret_cast<uint4*>(dst + 8) = o1;
}
__device__ __forceinline__ void stage16_b16(const __hip_bfloat16* __restrict__ src,
                                            __hip_bfloat16* dst){
    const uint4* s = reinterpret_cast<const uint4*>(src);
    uint4* d = reinterpret_cast<uint4*>(dst);
    d[0] = s[0]; d[1] = s[1];
}

// ---------------- one-time f32 -> bf16 conversion of x + 6 weights ----------------
__global__ void conv_bf16(
    const float* s0, const float* s1, const float* s2, const float* s3,
    const float* s4, const float* s5, const float* s6,
    __hip_bfloat16* d0, __hip_bfloat16* d1, __hip_bfloat16* d2, __hip_bfloat16* d3,
    __hip_bfloat16* d4, __hip_bfloat16* d5, __hip_bfloat16* d6)
{
    const int which = blockIdx.y;
    const float* s; __hip_bfloat16* d; int n;
    switch (which) {
        case 0: s = s0; d = d0; n = 2097152; break;
        case 1: s = s1; d = d1; n = 262144; break;
        case 2: s = s2; d = d2; n = 262144; break;
        case 3: s = s3; d = d3; n = 262144; break;
        case 4: s = s4; d = d4; n = 266240; break;
        case 5: s = s5; d = d5; n = 262144; break;
        default: s = s6; d = d6; n = 262144; break;
    }
    const int base = (blockIdx.x * 256 + threadIdx.x) * 4;
    if (base >= n) return;
    const float4 f = *reinterpret_cast<const float4*>(s + base);
    uint2 o;
    o.x = f2bf(f.x) | (f2bf(f.y) << 16);
    o.y = f2bf(f.z) | (f2bf(f.w) << 16);
    *reinterpret_cast<uint2*>(d + base) = o;
}

// ---------------- fused QKV projection (MFMA) ----------------
template<int B16>
__global__ __launch_bounds__(256) void qkv_gemm(
    const void* __restrict__ x,
    const void* __restrict__ Wq, const float* __restrict__ bq,
    const void* __restrict__ Wk, const float* __restrict__ bk,
    const void* __restrict__ Wv, const float* __restrict__ bv,
    __hip_bfloat16* __restrict__ qb,
    __hip_bfloat16* __restrict__ kb,
    __hip_bfloat16* __restrict__ vT)
{
    __shared__ __hip_bfloat16 As[64][72];
    __shared__ __hip_bfloat16 Bs[64][72];
    const int tid = threadIdx.x;
    const int which = blockIdx.x >> 3;
    const int col0 = (blockIdx.x & 7) * 64;
    const int row0 = blockIdx.y * 64;
    const int wv = tid >> 6, lane = tid & 63, quad = lane >> 4, m16 = lane & 15;
    const int sr = tid >> 2;
    const int sc = (tid & 3) * 16;
    const void* W    = (which == 0) ? Wq : (which == 1) ? Wk : Wv;
    const float* bias = (which == 0) ? bq : (which == 1) ? bk : bv;

    f32x4 acc[4];
    #pragma unroll
    for (int nt = 0; nt < 4; ++nt) acc[nt] = (f32x4){0.f, 0.f, 0.f, 0.f};

    for (int k0 = 0; k0 < 512; k0 += 64) {
        if (B16) {
            stage16_b16((const __hip_bfloat16*)x + (size_t)(row0 + sr) * EE + k0 + sc, &As[sr][sc]);
            stage16_b16((const __hip_bfloat16*)W + (size_t)(col0 + sr) * EE + k0 + sc, &Bs[sr][sc]);
        } else {
            stage16_f32((const float*)x + (size_t)(row0 + sr) * EE + k0 + sc, &As[sr][sc]);
            stage16_f32((const float*)W + (size_t)(col0 + sr) * EE + k0 + sc, &Bs[sr][sc]);
        }
        __syncthreads();
        #pragma unroll
        for (int ks = 0; ks < 2; ++ks) {
            const short8 a = *reinterpret_cast<const short8*>(
                &As[wv * 16 + m16][ks * 32 + quad * 8]);
            #pragma unroll
            for (int nt = 0; nt < 4; ++nt) {
                const short8 b = *reinterpret_cast<const short8*>(
                    &Bs[nt * 16 + m16][ks * 32 + quad * 8]);
                acc[nt] = __builtin_amdgcn_mfma_f32_16x16x32_bf16(a, b, acc[nt], 0, 0, 0);
            }
        }
        __syncthreads();
    }

    if (which == 2) {
        #pragma unroll
        for (int nt = 0; nt < 4; ++nt) {
            const float bb = bias[col0 + nt * 16 + m16];
            #pragma unroll
            for (int r = 0; r < 4; ++r)
                Bs[wv * 16 + quad * 4 + r][nt * 16 + m16] =
                    __float2bfloat16(acc[nt][r] + bb);
        }
        __syncthreads();
        const int bb2 = row0 >> 11;
        const int j0 = row0 & (SS - 1);
        const int er = tid >> 2;
        const int js = (tid & 3) * 16;
        unsigned pk[8];
        #pragma unroll
        for (int p = 0; p < 8; ++p) {
            const unsigned lo = *reinterpret_cast<const unsigned short*>(&Bs[js + 2*p][er]);
            const unsigned hi = *reinterpret_cast<const unsigned short*>(&Bs[js + 2*p + 1][er]);
            pk[p] = lo | (hi << 16);
        }
        uint4 s0; s0.x = pk[0]; s0.y = pk[1]; s0.z = pk[2]; s0.w = pk[3];
        uint4 s1; s1.x = pk[4]; s1.y = pk[5]; s1.z = pk[6]; s1.w = pk[7];
        __hip_bfloat16* dst = vT + ((size_t)(bb2 * EE + col0 + er)) * SS + j0 + js;
        *reinterpret_cast<uint4*>(dst) = s0;
        *reinterpret_cast<uint4*>(dst + 8) = s1;
    } else {
        __hip_bfloat16* C = (which == 0) ? qb : kb;
        #pragma unroll
        for (int nt = 0; nt < 4; ++nt) {
            const int gn = col0 + nt * 16 + m16;
            const float bb = bias[gn];
            #pragma unroll
            for (int r = 0; r < 4; ++r) {
                const int gm = row0 + wv * 16 + quad * 4 + r;
                C[(size_t)gm * EE + gn] = __float2bfloat16(acc[nt][r] + bb);
            }
        }
    }
}

// ---------------- MFMA GEMM (MLP1 / MLP2 / out-proj) ----------------
template<int MODE, int AB16, int WB16, int CF32>
__global__ __launch_bounds__(256) void gemm_bt(
    const void* __restrict__ Av,
    const void* __restrict__ Wv_,
    const float* __restrict__ bias,
    void* __restrict__ Cv,
    int ldb)
{
    __shared__ __hip_bfloat16 As[64][72];
    __shared__ __hip_bfloat16 Bs[64][72];
    const int tid = threadIdx.x;
    const int col0 = blockIdx.x * 64;
    const int row0 = blockIdx.y * 64;
    const int wv = tid >> 6, lane = tid & 63, quad = lane >> 4, m16 = lane & 15;
    const int sr = tid >> 2;
    const int sc = (tid & 3) * 16;

    f32x4 acc[4];
    #pragma unroll
    for (int nt = 0; nt < 4; ++nt) acc[nt] = (f32x4){0.f, 0.f, 0.f, 0.f};

    for (int k0 = 0; k0 < 512; k0 += 64) {
        if (AB16)
            stage16_b16((const __hip_bfloat16*)Av + (size_t)(row0 + sr) * EE + k0 + sc, &As[sr][sc]);
        else
            stage16_f32((const float*)Av + (size_t)(row0 + sr) * EE + k0 + sc, &As[sr][sc]);
        if (WB16)
            stage16_b16((const __hip_bfloat16*)Wv_ + (size_t)(col0 + sr) * ldb + k0 + sc, &Bs[sr][sc]);
        else
            stage16_f32((const float*)Wv_ + (size_t)(col0 + sr) * ldb + k0 + sc, &Bs[sr][sc]);
        __syncthreads();
        #pragma unroll
        for (int ks = 0; ks < 2; ++ks) {
            const short8 a = *reinterpret_cast<const short8*>(
                &As[wv * 16 + m16][ks * 32 + quad * 8]);
            #pragma unroll
            for (int nt = 0; nt < 4; ++nt) {
                const short8 b = *reinterpret_cast<const short8*>(
                    &Bs[nt * 16 + m16][ks * 32 + quad * 8]);
                acc[nt] = __builtin_amdgcn_mfma_f32_16x16x32_bf16(a, b, acc[nt], 0, 0, 0);
            }
        }
        __syncthreads();
    }

    #pragma unroll
    for (int nt = 0; nt < 4; ++nt) {
        const int gn = col0 + nt * 16 + m16;
        float bb = bias[gn];
        if (MODE == 1) {
            float ts = 0.f;
            #pragma unroll
            for (int h = 0; h < 8; ++h) {
                const size_t wi = (size_t)gn * ldb + 512 + h;
                ts += WB16 ? (float)((const __hip_bfloat16*)Wv_)[wi]
                           : ((const float*)Wv_)[wi];
            }
            bb += ts * (1.0f / (float)SS);
        }
        #pragma unroll
        for (int r = 0; r < 4; ++r) {
            const int gm = row0 + wv * 16 + quad * 4 + r;
            const size_t ci = (size_t)gm * EE + gn;
            float c = acc[nt][r] + bb;
            if (MODE == 1) c = 0.5f * c * (1.0f + erff(c * 0.70710678118654752f));
            if (MODE == 2) c += (float)((const __hip_bfloat16*)Cv)[ci];
            if (CF32) ((float*)Cv)[ci] = c;
            else      ((__hip_bfloat16*)Cv)[ci] = __float2bfloat16(c);
        }
    }
}

// ---------------- K1: partial softmax denominators (R7 32-i split, proven) ----------------
// Block = 32 i, waves split (ih, hh): 16 i x 4 heads each, fully independent.
// grid (8, 64, 2) = 1024 blocks -> 4 blocks/CU (33.3 KB LDS). Double-buffered
// K tile, issue-early/write-late, conflict-free staging. No launch_bounds
// min-arg (it silently caps VGPR — R5/R7 lesson); occupancy is LDS-limited.
__global__ __launch_bounds__(256) void attn_denoms(
    const __hip_bfloat16* __restrict__ qws,
    const __hip_bfloat16* __restrict__ kws,
    float* __restrict__ dnP,
    int* __restrict__ cntI)
{
    __shared__ __hip_bfloat16 KL[2][16][520];   // 33.3 KB
    const int tid = threadIdx.x;
    const int wv = tid >> 6, lane = tid & 63, quad = lane >> 4, m16 = lane & 15;
    const int jc = blockIdx.x;              // 8 chunks x 256 j
    const int it = blockIdx.y;              // 64 tiles x 32 i
    const int b  = blockIdx.z;
    const size_t g0 = (size_t)b * SS + it * 32;
    const size_t gb = (size_t)b * SS;
    const int ih = wv & 1, hh = wv >> 1;

    if (jc == 0 && tid < 32) cntI[g0 + tid] = 0;

    short8 aq[4][2];
    #pragma unroll
    for (int hp = 0; hp < 4; ++hp)
        #pragma unroll
        for (int ks = 0; ks < 2; ++ks)
            aq[hp][ks] = *reinterpret_cast<const short8*>(
                qws + (g0 + ih * 16 + m16) * EE + (hh * 4 + hp) * 64 + ks * 32 + quad * 8);

    float dph[4][4];
    #pragma unroll
    for (int hp = 0; hp < 4; ++hp)
        #pragma unroll
        for (int r = 0; r < 4; ++r) dph[hp][r] = 0.f;

    const int srow = tid >> 4, t4 = tid & 15;
    {   // initial stage: tile 0 -> KL[0] (conflict-free pattern)
        #pragma unroll
        for (int k = 0; k < 4; ++k)
            *reinterpret_cast<uint4*>(&KL[0][srow][t4 * 8 + k * 128]) =
                *reinterpret_cast<const uint4*>(
                    kws + (gb + jc * 256 + srow) * EE + t4 * 8 + k * 128);
    }

    for (int jt = 0; jt < 16; ++jt) {
        __syncthreads();                       // KL[jt&1] ready
        uint4 kr[4];
        if (jt + 1 < 16) {                     // issue-early: next tile -> regs
            #pragma unroll
            for (int k = 0; k < 4; ++k)
                kr[k] = *reinterpret_cast<const uint4*>(
                    kws + (gb + jc * 256 + (jt + 1) * 16 + srow) * EE + t4 * 8 + k * 128);
        }
        #pragma unroll
        for (int hp = 0; hp < 4; ++hp) {
            const short8 b0 = *reinterpret_cast<const short8*>(
                &KL[jt & 1][m16][(hh * 4 + hp) * 64 + quad * 8]);
            const short8 b1 = *reinterpret_cast<const short8*>(
                &KL[jt & 1][m16][(hh * 4 + hp) * 64 + 32 + quad * 8]);
            f32x4 c = {0.f, 0.f, 0.f, 0.f};
            c = __builtin_amdgcn_mfma_f32_16x16x32_bf16(aq[hp][0], b0, c, 0, 0, 0);
            c = __builtin_amdgcn_mfma_f32_16x16x32_bf16(aq[hp][1], b1, c, 0, 0, 0);
            #pragma unroll
            for (int r = 0; r < 4; ++r) dph[hp][r] += __expf(c[r] * 0.125f);
        }
        if (jt + 1 < 16) {                     // write-late into the spare buffer
            #pragma unroll
            for (int k = 0; k < 4; ++k)
                *reinterpret_cast<uint4*>(&KL[(jt + 1) & 1][srow][t4 * 8 + k * 128]) = kr[k];
        }
    }

    #pragma unroll
    for (int hp = 0; hp < 4; ++hp)
        #pragma unroll
        for (int off = 1; off <= 8; off <<= 1)
            #pragma unroll
            for (int r = 0; r < 4; ++r) dph[hp][r] += __shfl_xor(dph[hp][r], off, 64);
    if (m16 == 0) {
        const size_t i = (size_t)it * 32 + ih * 16 + quad * 4;
        #pragma unroll
        for (int hp = 0; hp < 4; ++hp)
            #pragma unroll
            for (int r = 0; r < 4; ++r)
                dnP[((size_t)(jc * BB + b) * SS + i + r) * HH + hh * 4 + hp] = dph[hp][r];
    }
}

// ---------------- K2: fused ew + PV (R4-exact, 67 us proven) ----------------
// Block = 32 i x 512 j. LDS: KL 33.3 + ewT 2.6 + invd 1 = 36.9 KB.
// Per step: stage K -> LDS; sync; scores -> ewT; sync; V frags global -> regs
// (late, minimal live range) -> PV MFMA. No VL staging (V has zero intra-block
// reuse); no K prefetch regs (R2's spill source). 2 barriers/step. Best of
// R4-R10 sweep: every structural variant (512-thr, 16-i, gload_lds 1-barrier,
// e-split) lost to this schedule.
__global__ __launch_bounds__(256, 2) void attn_ewpv(
    const __hip_bfloat16* __restrict__ qws,
    const __hip_bfloat16* __restrict__ kws,
    const __hip_bfloat16* __restrict__ vTg,
    const float* __restrict__ dnP,
    int* __restrict__ cntI,
    int* __restrict__ slotJ,
    float* __restrict__ slotW,
    __hip_bfloat16* __restrict__ pvP)
{
    __shared__ __hip_bfloat16 KL[32][520];     // 33.3 KB (reused as epilogue bounce)
    __shared__ __hip_bfloat16 ewT[32][40];     // 2.6 KB
    __shared__ float invd[HH][32];             // 1 KB
    const int tid = threadIdx.x;
    const int wv = tid >> 6, lane = tid & 63, quad = lane >> 4, m16 = lane & 15;
    const int jc = blockIdx.x;               // 4 chunks x 512 j
    const int it = blockIdx.y;               // 64 tiles x 32 i
    const int b  = blockIdx.z;
    const size_t gb = (size_t)b * SS;
    const size_t g0 = gb + it * 32;
    const int ih = wv & 1;                   // i-half for score phase
    const int jh = wv >> 1;                  // j-half for score phase

    {   // denominators -> 0.125/D (head-mean folded in); 256 thr = HH*32 exactly
        const int h = tid >> 5, i = tid & 31;
        float s = 0.f;
        #pragma unroll
        for (int c = 0; c < JC1; ++c)
            s += dnP[((size_t)(c * BB + b) * SS + it * 32 + i) * HH + h];
        invd[h][i] = 0.125f / s;
    }

    short8 aq[HH][2];
    #pragma unroll
    for (int h = 0; h < HH; ++h)
        #pragma unroll
        for (int ks = 0; ks < 2; ++ks)
            aq[h][ks] = *reinterpret_cast<const short8*>(
                qws + (g0 + ih * 16 + m16) * EE + h * 64 + ks * 32 + quad * 8);

    f32x4 acc[2][8];
    #pragma unroll
    for (int mf = 0; mf < 2; ++mf)
        #pragma unroll
        for (int nf = 0; nf < 8; ++nf) acc[mf][nf] = (f32x4){0.f, 0.f, 0.f, 0.f};

    const int krow = tid >> 4, kcol = (tid & 15) * 32;
    // per-lane V row base: e = wv*128 + nf*16 + m16, k-offset quad*8
    const __hip_bfloat16* vrow0 = vTg + ((size_t)b * EE + wv * 128 + m16) * SS + quad * 8;

    for (int st = 0; st < 16; ++st) {
        const int j0 = jc * 512 + st * 32;
        // stage K subtile [32 j][512 feat] (global -> reg -> LDS, short-lived temps)
        #pragma unroll
        for (int rr = 0; rr < 2; ++rr) {
            const uint4* src = reinterpret_cast<const uint4*>(
                kws + (gb + j0 + rr * 16 + krow) * EE + kcol);
            uint4* dst = reinterpret_cast<uint4*>(&KL[rr * 16 + krow][kcol]);
            dst[0] = src[0]; dst[1] = src[1]; dst[2] = src[2]; dst[3] = src[3];
        }
        __syncthreads();                       // KL ready; prev-step PV done w/ ewT

        // scores: wave's (ih, jh) quadrant of the 32x32 tile, all heads
        float wsum[4] = {0.f, 0.f, 0.f, 0.f};
        #pragma unroll
        for (int h = 0; h < HH; ++h) {
            const short8 b0 = *reinterpret_cast<const short8*>(
                &KL[jh * 16 + m16][h * 64 + quad * 8]);
            const short8 b1 = *reinterpret_cast<const short8*>(
                &KL[jh * 16 + m16][h * 64 + 32 + quad * 8]);
            f32x4 c = {0.f, 0.f, 0.f, 0.f};
            c = __builtin_amdgcn_mfma_f32_16x16x32_bf16(aq[h][0], b0, c, 0, 0, 0);
            c = __builtin_amdgcn_mfma_f32_16x16x32_bf16(aq[h][1], b1, c, 0, 0, 0);
            #pragma unroll
            for (int r = 0; r < 4; ++r)
                wsum[r] += __expf(c[r] * 0.125f) * invd[h][ih * 16 + quad * 4 + r];
        }
        #pragma unroll
        for (int r = 0; r < 4; ++r) {
            const __hip_bfloat16 wb = __float2bfloat16(wsum[r]);
            ewT[ih * 16 + quad * 4 + r][jh * 16 + m16] = wb;
            if ((float)wb > 0.1f) {            // rare: adjacency crossing
                const int li = ih * 16 + quad * 4 + r;
                const int idx = atomicAdd(&cntI[g0 + li], 1);
                if (idx < 16) {
                    slotJ[((size_t)g0 + li) * 16 + idx] = j0 + jh * 16 + m16;
                    slotW[((size_t)g0 + li) * 16 + idx] = (float)wb;
                }
            }
        }
        __syncthreads();                       // ewT ready

        // PV: V B-frags straight from global (L2-resident), consumed immediately
        {
            short8 vb[8];
            #pragma unroll
            for (int nf = 0; nf < 8; ++nf)
                vb[nf] = *reinterpret_cast<const short8*>(vrow0 + (size_t)(nf * 16) * SS + j0);
            const short8 a0 = *reinterpret_cast<const short8*>(&ewT[m16][quad * 8]);
            const short8 a1 = *reinterpret_cast<const short8*>(&ewT[16 + m16][quad * 8]);
            #pragma unroll
            for (int nf = 0; nf < 8; ++nf) {
                acc[0][nf] = __builtin_amdgcn_mfma_f32_16x16x32_bf16(a0, vb[nf], acc[0][nf], 0, 0, 0);
                acc[1][nf] = __builtin_amdgcn_mfma_f32_16x16x32_bf16(a1, vb[nf], acc[1][nf], 0, 0, 0);
            }
        }
    }

    // epilogue: bounce acc through KL for coalesced bf16 writes
    #pragma unroll
    for (int mf = 0; mf < 2; ++mf)
        #pragma unroll
        for (int nf = 0; nf < 8; ++nf)
            #pragma unroll
            for (int r = 0; r < 4; ++r)
                KL[mf * 16 + quad * 4 + r][wv * 128 + nf * 16 + m16] =
                    __float2bfloat16(acc[mf][nf][r]);
    __syncthreads();
    const int orow = tid >> 3;
    const int oc = (tid & 7) * 64;
    const uint4* s = reinterpret_cast<const uint4*>(&KL[orow][oc]);
    uint4* d = reinterpret_cast<uint4*>(
        pvP + ((size_t)jc * NN + g0 + orow) * EE + oc);
    #pragma unroll
    for (int q = 0; q < 8; ++q) d[q] = s[q];
}

// ---------------- K3: combine PV partials + rare messages path ----------------
__global__ __launch_bounds__(256) void pv_combine(
    const __hip_bfloat16* __restrict__ pvP,
    const int* __restrict__ cntI,
    const int* __restrict__ slotJ,
    const float* __restrict__ slotW,
    const float* __restrict__ x,
    __hip_bfloat16* __restrict__ u1out)
{
    const int tid = threadIdx.x;
    const int row = blockIdx.x * 4 + (tid >> 6);   // [0, NN)
    const int e0 = (tid & 63) * 8;
    float s[8] = {0.f, 0.f, 0.f, 0.f, 0.f, 0.f, 0.f, 0.f};
    #pragma unroll
    for (int c = 0; c < JCP; ++c) {
        const short8 v = *reinterpret_cast<const short8*>(
            pvP + ((size_t)c * NN + row) * EE + e0);
        #pragma unroll
        for (int k = 0; k < 8; ++k) s[k] += b2f(v[k]);
    }
    const int cn = cntI[row];
    if (cn > 0) {                                  // exact rare path: masked mean
        const float inv = 1.f / (float)cn;
        const int ns = cn < 16 ? cn : 16;
        const int b = row >> 11;
        for (int t = 0; t < ns; ++t) {
            const int j = slotJ[(size_t)row * 16 + t];
            const float w = slotW[(size_t)row * 16 + t] * inv;
            const float* xr = x + ((size_t)b * SS + j) * EE + e0;
            #pragma unroll
            for (int k = 0; k < 8; ++k) s[k] += w * xr[k];
        }
    }
    short8 o;
    #pragma unroll
    for (int k = 0; k < 8; ++k) o[k] = (short)f2bf(s[k]);
    *reinterpret_cast<short8*>(u1out + (size_t)row * EE + e0) = o;
}

extern "C" void kernel_launch(void* const* d_in, const int* in_sizes, int n_in,
                              void* d_out, int out_size, void* d_ws, size_t ws_size,
                              hipStream_t stream)
{
    const float* x   = (const float*)d_in[0];
    const float* Wq  = (const float*)d_in[1];
    const float* bq  = (const float*)d_in[2];
    const float* Wk  = (const float*)d_in[3];
    const float* bk  = (const float*)d_in[4];
    const float* Wv  = (const float*)d_in[5];
    const float* bv  = (const float*)d_in[6];
    const float* Wm1 = (const float*)d_in[7];
    const float* bm1 = (const float*)d_in[8];
    const float* Wm2 = (const float*)d_in[9];
    const float* bm2 = (const float*)d_in[10];
    const float* Wo  = (const float*)d_in[11];
    const float* bo  = (const float*)d_in[12];

    char* ws = (char*)d_ws;
    const size_t MB = 1024 * 1024;
    __hip_bfloat16* qb = (__hip_bfloat16*)(ws + 0);        // q -> u1 -> t   4MB
    __hip_bfloat16* kb = (__hip_bfloat16*)(ws + 4*MB);     // k -> hm        4MB
    __hip_bfloat16* vT = (__hip_bfloat16*)(ws + 8*MB);     // V^T [b][e][j]  4MB
    __hip_bfloat16* pvP = (__hip_bfloat16*)(ws + 12*MB);   // PV partials [4][NN][EE] 16MB
    float* dnP = (float*)(ws + 28*MB);                     // denom partials 1MB
    int*   cntI = (int*)(ws + 29*MB);                      // neighbor cnt  16KB
    int*   slotJ = (int*)(ws + 29*MB + 64*1024);           // crossing j    256KB
    float* slotW = (float*)(ws + 29*MB + 384*1024);        // crossing w    256KB
    const bool EXT = (ws_size >= 38 * MB);
    __hip_bfloat16* xb   = (__hip_bfloat16*)(ws + 30*MB);          // 4MB
    __hip_bfloat16* wqb  = (__hip_bfloat16*)(ws + 34*MB);
    __hip_bfloat16* wkb  = (__hip_bfloat16*)(ws + 34*MB + 512*1024);
    __hip_bfloat16* wvb  = (__hip_bfloat16*)(ws + 35*MB);
    __hip_bfloat16* wm1b = (__hip_bfloat16*)(ws + 35*MB + 512*1024);
    __hip_bfloat16* wm2b = (__hip_bfloat16*)(ws + 36*MB + 256*1024);
    __hip_bfloat16* wob  = (__hip_bfloat16*)(ws + 36*MB + 768*1024);

    dim3 blk(256, 1, 1);
    dim3 gg(EE / 64, NN / 64, 1);

    if (EXT) {
        conv_bf16<<<dim3(2048, 7, 1), blk, 0, stream>>>(
            x, Wq, Wk, Wv, Wm1, Wm2, Wo, xb, wqb, wkb, wvb, wm1b, wm2b, wob);
        qkv_gemm<1><<<dim3(24, NN / 64, 1), blk, 0, stream>>>(
            xb, wqb, bq, wkb, bk, wvb, bv, qb, kb, vT);
    } else {
        qkv_gemm<0><<<dim3(24, NN / 64, 1), blk, 0, stream>>>(
            x, Wq, bq, Wk, bk, Wv, bv, qb, kb, vT);
    }
    attn_denoms<<<dim3(JC1, SS / 32, BB), blk, 0, stream>>>(qb, kb, dnP, cntI);
    attn_ewpv<<<dim3(JCP, SS / 32, BB), blk, 0, stream>>>(
        qb, kb, vT, dnP, cntI, slotJ, slotW, pvP);
    pv_combine<<<dim3(NN / 4, 1, 1), blk, 0, stream>>>(
        pvP, cntI, slotJ, slotW, x, qb);                            // u1 -> qb
    if (EXT) {
        gemm_bt<1,1,1,0><<<gg, blk, 0, stream>>>(xb, wm1b, bm1, kb, EE + HH);
        gemm_bt<2,1,1,0><<<gg, blk, 0, stream>>>(kb, wm2b, bm2, qb, EE);
        gemm_bt<0,1,1,1><<<gg, blk, 0, stream>>>(qb, wob, bo, d_out, EE);
    } else {
        gemm_bt<1,0,0,0><<<gg, blk, 0, stream>>>(x, Wm1, bm1, kb, EE + HH);
        gemm_bt<2,1,0,0><<<gg, blk, 0, stream>>>(kb, Wm2, bm2, qb, EE);
        gemm_bt<0,1,0,1><<<gg, blk, 0, stream>>>(qb, Wo, bo, d_out, EE);
    }
}

// Round 12
// 219.793 us; speedup vs baseline: 1.1878x; 1.0098x over previous
//
#include <hip/hip_runtime.h>
#include <hip/hip_bf16.h>
#include <math.h>

#define BB 2
#define SS 2048
#define EE 512
#define HH 8
#define NN (BB*SS)
#define JC1 8   // denoms j-chunks (256 j each)
#define JCP 4   // fused ew+pv j-chunks (512 j each)

typedef __attribute__((ext_vector_type(8))) short short8;
typedef __attribute__((ext_vector_type(4))) float f32x4;

__device__ __forceinline__ float b2f(short v){
    return __uint_as_float(((unsigned)(unsigned short)v) << 16);
}
__device__ __forceinline__ unsigned f2bf(float f){
    unsigned u = __float_as_uint(f);
    u += 0x7fffu + ((u >> 16) & 1u);
    return u >> 16;
}
__device__ __forceinline__ void stage16_f32(const float* __restrict__ src,
                                            __hip_bfloat16* dst){
    const float4 f0 = *reinterpret_cast<const float4*>(src);
    const float4 f1 = *reinterpret_cast<const float4*>(src + 4);
    const float4 f2 = *reinterpret_cast<const float4*>(src + 8);
    const float4 f3 = *reinterpret_cast<const float4*>(src + 12);
    uint4 o0, o1;
    o0.x = f2bf(f0.x) | (f2bf(f0.y) << 16);
    o0.y = f2bf(f0.z) | (f2bf(f0.w) << 16);
    o0.z = f2bf(f1.x) | (f2bf(f1.y) << 16);
    o0.w = f2bf(f1.z) | (f2bf(f1.w) << 16);
    o1.x = f2bf(f2.x) | (f2bf(f2.y) << 16);
    o1.y = f2bf(f2.z) | (f2bf(f2.w) << 16);
    o1.z = f2bf(f3.x) | (f2bf(f3.y) << 16);
    o1.w = f2bf(f3.z) | (f2bf(f3.w) << 16);
    *reinterpret_cast<uint4*>(dst) = o0;
    *reinterpret_cast<uint4*>(dst + 8) = o1;
}
__device__ __forceinline__ void stage16_b16(const __hip_bfloat16* __restrict__ src,
                                            __hip_bfloat16* dst){
    const uint4* s = reinterpret_cast<const uint4*>(src);
    uint4* d = reinterpret_cast<uint4*>(dst);
    d[0] = s[0]; d[1] = s[1];
}
// pack 16 f32 (4x float4 in regs) -> 16 bf16 in LDS
__device__ __forceinline__ void pack16(const float4* f, __hip_bfloat16* dst){
    uint4 o0, o1;
    o0.x = f2bf(f[0].x) | (f2bf(f[0].y) << 16);
    o0.y = f2bf(f[0].z) | (f2bf(f[0].w) << 16);
    o0.z = f2bf(f[1].x) | (f2bf(f[1].y) << 16);
    o0.w = f2bf(f[1].z) | (f2bf(f[1].w) << 16);
    o1.x = f2bf(f[2].x) | (f2bf(f[2].y) << 16);
    o1.y = f2bf(f[2].z) | (f2bf(f[2].w) << 16);
    o1.z = f2bf(f[3].x) | (f2bf(f[3].y) << 16);
    o1.w = f2bf(f[3].z) | (f2bf(f[3].w) << 16);
    *reinterpret_cast<uint4*>(dst) = o0;
    *reinterpret_cast<uint4*>(dst + 8) = o1;
}

// ---------------- one-time f32 -> bf16 conversion of x + 6 weights ----------------
__global__ void conv_bf16(
    const float* s0, const float* s1, const float* s2, const float* s3,
    const float* s4, const float* s5, const float* s6,
    __hip_bfloat16* d0, __hip_bfloat16* d1, __hip_bfloat16* d2, __hip_bfloat16* d3,
    __hip_bfloat16* d4, __hip_bfloat16* d5, __hip_bfloat16* d6)
{
    const int which = blockIdx.y;
    const float* s; __hip_bfloat16* d; int n;
    switch (which) {
        case 0: s = s0; d = d0; n = 2097152; break;
        case 1: s = s1; d = d1; n = 262144; break;
        case 2: s = s2; d = d2; n = 262144; break;
        case 3: s = s3; d = d3; n = 262144; break;
        case 4: s = s4; d = d4; n = 266240; break;
        case 5: s = s5; d = d5; n = 262144; break;
        default: s = s6; d = d6; n = 262144; break;
    }
    const int base = (blockIdx.x * 256 + threadIdx.x) * 4;
    if (base >= n) return;
    const float4 f = *reinterpret_cast<const float4*>(s + base);
    uint2 o;
    o.x = f2bf(f.x) | (f2bf(f.y) << 16);
    o.y = f2bf(f.z) | (f2bf(f.w) << 16);
    *reinterpret_cast<uint2*>(d + base) = o;
}

// ---------------- fused QKV projection (MFMA) — R11-verbatim ----------------
template<int B16>
__global__ __launch_bounds__(256) void qkv_gemm(
    const void* __restrict__ x,
    const void* __restrict__ Wq, const float* __restrict__ bq,
    const void* __restrict__ Wk, const float* __restrict__ bk,
    const void* __restrict__ Wv, const float* __restrict__ bv,
    __hip_bfloat16* __restrict__ qb,
    __hip_bfloat16* __restrict__ kb,
    __hip_bfloat16* __restrict__ vT)
{
    __shared__ __hip_bfloat16 As[64][72];
    __shared__ __hip_bfloat16 Bs[64][72];
    const int tid = threadIdx.x;
    const int which = blockIdx.x >> 3;
    const int col0 = (blockIdx.x & 7) * 64;
    const int row0 = blockIdx.y * 64;
    const int wv = tid >> 6, lane = tid & 63, quad = lane >> 4, m16 = lane & 15;
    const int sr = tid >> 2;
    const int sc = (tid & 3) * 16;
    const void* W    = (which == 0) ? Wq : (which == 1) ? Wk : Wv;
    const float* bias = (which == 0) ? bq : (which == 1) ? bk : bv;

    f32x4 acc[4];
    #pragma unroll
    for (int nt = 0; nt < 4; ++nt) acc[nt] = (f32x4){0.f, 0.f, 0.f, 0.f};

    for (int k0 = 0; k0 < 512; k0 += 64) {
        if (B16) {
            stage16_b16((const __hip_bfloat16*)x + (size_t)(row0 + sr) * EE + k0 + sc, &As[sr][sc]);
            stage16_b16((const __hip_bfloat16*)W + (size_t)(col0 + sr) * EE + k0 + sc, &Bs[sr][sc]);
        } else {
            stage16_f32((const float*)x + (size_t)(row0 + sr) * EE + k0 + sc, &As[sr][sc]);
            stage16_f32((const float*)W + (size_t)(col0 + sr) * EE + k0 + sc, &Bs[sr][sc]);
        }
        __syncthreads();
        #pragma unroll
        for (int ks = 0; ks < 2; ++ks) {
            const short8 a = *reinterpret_cast<const short8*>(
                &As[wv * 16 + m16][ks * 32 + quad * 8]);
            #pragma unroll
            for (int nt = 0; nt < 4; ++nt) {
                const short8 b = *reinterpret_cast<const short8*>(
                    &Bs[nt * 16 + m16][ks * 32 + quad * 8]);
                acc[nt] = __builtin_amdgcn_mfma_f32_16x16x32_bf16(a, b, acc[nt], 0, 0, 0);
            }
        }
        __syncthreads();
    }

    if (which == 2) {
        #pragma unroll
        for (int nt = 0; nt < 4; ++nt) {
            const float bb = bias[col0 + nt * 16 + m16];
            #pragma unroll
            for (int r = 0; r < 4; ++r)
                Bs[wv * 16 + quad * 4 + r][nt * 16 + m16] =
                    __float2bfloat16(acc[nt][r] + bb);
        }
        __syncthreads();
        const int bb2 = row0 >> 11;
        const int j0 = row0 & (SS - 1);
        const int er = tid >> 2;
        const int js = (tid & 3) * 16;
        unsigned pk[8];
        #pragma unroll
        for (int p = 0; p < 8; ++p) {
            const unsigned lo = *reinterpret_cast<const unsigned short*>(&Bs[js + 2*p][er]);
            const unsigned hi = *reinterpret_cast<const unsigned short*>(&Bs[js + 2*p + 1][er]);
            pk[p] = lo | (hi << 16);
        }
        uint4 s0; s0.x = pk[0]; s0.y = pk[1]; s0.z = pk[2]; s0.w = pk[3];
        uint4 s1; s1.x = pk[4]; s1.y = pk[5]; s1.z = pk[6]; s1.w = pk[7];
        __hip_bfloat16* dst = vT + ((size_t)(bb2 * EE + col0 + er)) * SS + j0 + js;
        *reinterpret_cast<uint4*>(dst) = s0;
        *reinterpret_cast<uint4*>(dst + 8) = s1;
    } else {
        __hip_bfloat16* C = (which == 0) ? qb : kb;
        #pragma unroll
        for (int nt = 0; nt < 4; ++nt) {
            const int gn = col0 + nt * 16 + m16;
            const float bb = bias[gn];
            #pragma unroll
            for (int r = 0; r < 4; ++r) {
                const int gm = row0 + wv * 16 + quad * 4 + r;
                C[(size_t)gm * EE + gn] = __float2bfloat16(acc[nt][r] + bb);
            }
        }
    }
}

// ---------------- MFMA GEMM (MLP1 / MLP2+combine / out-proj) ----------------
// Double-buffered LDS, 1 barrier per k-step (issue-early/write-late, proven in
// denoms): per step {sync; next tile -> regs; MFMA cur; write regs -> spare}.
// LDS 36.9 KB (grid 512 = 2 blocks/CU regardless). MODE==2 fuses the former
// pv_combine: output = MLP2 + bias + sum(pvP partials) + rare slot path
// (one fewer bf16 rounding than the separate-kernel version).
template<int MODE, int AB16, int WB16, int CF32>
__global__ __launch_bounds__(256) void gemm_bt(
    const void* __restrict__ Av,
    const void* __restrict__ Wv_,
    const float* __restrict__ bias,
    void* __restrict__ Cv,
    int ldb,
    const __hip_bfloat16* __restrict__ pvPp,
    const int* __restrict__ cntIp,
    const int* __restrict__ slotJp,
    const float* __restrict__ slotWp,
    const float* __restrict__ xf)
{
    __shared__ __hip_bfloat16 As[2][64][72];
    __shared__ __hip_bfloat16 Bs[2][64][72];
    const int tid = threadIdx.x;
    const int col0 = blockIdx.x * 64;
    const int row0 = blockIdx.y * 64;
    const int wv = tid >> 6, lane = tid & 63, quad = lane >> 4, m16 = lane & 15;
    const int sr = tid >> 2;
    const int sc = (tid & 3) * 16;

    f32x4 acc[4];
    #pragma unroll
    for (int nt = 0; nt < 4; ++nt) acc[nt] = (f32x4){0.f, 0.f, 0.f, 0.f};

    {   // prologue: tile 0 -> buffer 0
        if (AB16)
            stage16_b16((const __hip_bfloat16*)Av + (size_t)(row0 + sr) * EE + sc, &As[0][sr][sc]);
        else
            stage16_f32((const float*)Av + (size_t)(row0 + sr) * EE + sc, &As[0][sr][sc]);
        if (WB16)
            stage16_b16((const __hip_bfloat16*)Wv_ + (size_t)(col0 + sr) * ldb + sc, &Bs[0][sr][sc]);
        else
            stage16_f32((const float*)Wv_ + (size_t)(col0 + sr) * ldb + sc, &Bs[0][sr][sc]);
    }

    for (int kt = 0; kt < 8; ++kt) {
        __syncthreads();                       // buffer kt&1 ready
        uint4 ra[2], rb[2];
        float4 fa[4], fb[4];
        if (kt + 1 < 8) {                      // issue-early: next tile -> regs
            const int k0 = (kt + 1) * 64;
            if (AB16) {
                const uint4* s = reinterpret_cast<const uint4*>(
                    (const __hip_bfloat16*)Av + (size_t)(row0 + sr) * EE + k0 + sc);
                ra[0] = s[0]; ra[1] = s[1];
            } else {
                const float4* s = reinterpret_cast<const float4*>(
                    (const float*)Av + (size_t)(row0 + sr) * EE + k0 + sc);
                fa[0] = s[0]; fa[1] = s[1]; fa[2] = s[2]; fa[3] = s[3];
            }
            if (WB16) {
                const uint4* s = reinterpret_cast<const uint4*>(
                    (const __hip_bfloat16*)Wv_ + (size_t)(col0 + sr) * ldb + k0 + sc);
                rb[0] = s[0]; rb[1] = s[1];
            } else {
                const float4* s = reinterpret_cast<const float4*>(
                    (const float*)Wv_ + (size_t)(col0 + sr) * ldb + k0 + sc);
                fb[0] = s[0]; fb[1] = s[1]; fb[2] = s[2]; fb[3] = s[3];
            }
        }
        const int cur = kt & 1;
        #pragma unroll
        for (int ks = 0; ks < 2; ++ks) {
            const short8 a = *reinterpret_cast<const short8*>(
                &As[cur][wv * 16 + m16][ks * 32 + quad * 8]);
            #pragma unroll
            for (int nt = 0; nt < 4; ++nt) {
                const short8 b = *reinterpret_cast<const short8*>(
                    &Bs[cur][nt * 16 + m16][ks * 32 + quad * 8]);
                acc[nt] = __builtin_amdgcn_mfma_f32_16x16x32_bf16(a, b, acc[nt], 0, 0, 0);
            }
        }
        if (kt + 1 < 8) {                      // write-late into the spare buffer
            const int nb = (kt + 1) & 1;
            if (AB16) {
                uint4* d = reinterpret_cast<uint4*>(&As[nb][sr][sc]);
                d[0] = ra[0]; d[1] = ra[1];
            } else pack16(fa, &As[nb][sr][sc]);
            if (WB16) {
                uint4* d = reinterpret_cast<uint4*>(&Bs[nb][sr][sc]);
                d[0] = rb[0]; d[1] = rb[1];
            } else pack16(fb, &Bs[nb][sr][sc]);
        }
    }

    if (MODE == 2) {                           // MLP2 + fused pv-combine
        #pragma unroll
        for (int r = 0; r < 4; ++r) {
            const int gm = row0 + wv * 16 + quad * 4 + r;
            const int cn = cntIp[gm];
            const int bloc = gm >> 11;
            #pragma unroll
            for (int nt = 0; nt < 4; ++nt) {
                const int gn = col0 + nt * 16 + m16;
                const size_t ci = (size_t)gm * EE + gn;
                float c = acc[nt][r] + bias[gn];
                #pragma unroll
                for (int cc = 0; cc < JCP; ++cc)
                    c += b2f(reinterpret_cast<const short*>(pvPp)
                             [(size_t)cc * NN * EE + ci]);
                if (cn > 0) {                  // exact rare path: masked mean
                    const float inv = 1.f / (float)cn;
                    const int ns = cn < 16 ? cn : 16;
                    for (int t = 0; t < ns; ++t) {
                        const int j = slotJp[(size_t)gm * 16 + t];
                        c += slotWp[(size_t)gm * 16 + t] * inv *
                             xf[((size_t)bloc * SS + j) * EE + gn];
                    }
                }
                ((__hip_bfloat16*)Cv)[ci] = __float2bfloat16(c);
            }
        }
        return;
    }

    #pragma unroll
    for (int nt = 0; nt < 4; ++nt) {
        const int gn = col0 + nt * 16 + m16;
        float bb = bias[gn];
        if (MODE == 1) {
            float ts = 0.f;
            #pragma unroll
            for (int h = 0; h < 8; ++h) {
                const size_t wi = (size_t)gn * ldb + 512 + h;
                ts += WB16 ? (float)((const __hip_bfloat16*)Wv_)[wi]
                           : ((const float*)Wv_)[wi];
            }
            bb += ts * (1.0f / (float)SS);
        }
        #pragma unroll
        for (int r = 0; r < 4; ++r) {
            const int gm = row0 + wv * 16 + quad * 4 + r;
            const size_t ci = (size_t)gm * EE + gn;
            float c = acc[nt][r] + bb;
            if (MODE == 1) c = 0.5f * c * (1.0f + erff(c * 0.70710678118654752f));
            if (CF32) ((float*)Cv)[ci] = c;
            else      ((__hip_bfloat16*)Cv)[ci] = __float2bfloat16(c);
        }
    }
}

// ---------------- K1: partial softmax denominators (R11-verbatim, 32-i split) ----------------
__global__ __launch_bounds__(256) void attn_denoms(
    const __hip_bfloat16* __restrict__ qws,
    const __hip_bfloat16* __restrict__ kws,
    float* __restrict__ dnP,
    int* __restrict__ cntI)
{
    __shared__ __hip_bfloat16 KL[2][16][520];   // 33.3 KB
    const int tid = threadIdx.x;
    const int wv = tid >> 6, lane = tid & 63, quad = lane >> 4, m16 = lane & 15;
    const int jc = blockIdx.x;              // 8 chunks x 256 j
    const int it = blockIdx.y;              // 64 tiles x 32 i
    const int b  = blockIdx.z;
    const size_t g0 = (size_t)b * SS + it * 32;
    const size_t gb = (size_t)b * SS;
    const int ih = wv & 1, hh = wv >> 1;

    if (jc == 0 && tid < 32) cntI[g0 + tid] = 0;

    short8 aq[4][2];
    #pragma unroll
    for (int hp = 0; hp < 4; ++hp)
        #pragma unroll
        for (int ks = 0; ks < 2; ++ks)
            aq[hp][ks] = *reinterpret_cast<const short8*>(
                qws + (g0 + ih * 16 + m16) * EE + (hh * 4 + hp) * 64 + ks * 32 + quad * 8);

    float dph[4][4];
    #pragma unroll
    for (int hp = 0; hp < 4; ++hp)
        #pragma unroll
        for (int r = 0; r < 4; ++r) dph[hp][r] = 0.f;

    const int srow = tid >> 4, t4 = tid & 15;
    {   // initial stage: tile 0 -> KL[0] (conflict-free pattern)
        #pragma unroll
        for (int k = 0; k < 4; ++k)
            *reinterpret_cast<uint4*>(&KL[0][srow][t4 * 8 + k * 128]) =
                *reinterpret_cast<const uint4*>(
                    kws + (gb + jc * 256 + srow) * EE + t4 * 8 + k * 128);
    }

    for (int jt = 0; jt < 16; ++jt) {
        __syncthreads();                       // KL[jt&1] ready
        uint4 kr[4];
        if (jt + 1 < 16) {                     // issue-early: next tile -> regs
            #pragma unroll
            for (int k = 0; k < 4; ++k)
                kr[k] = *reinterpret_cast<const uint4*>(
                    kws + (gb + jc * 256 + (jt + 1) * 16 + srow) * EE + t4 * 8 + k * 128);
        }
        #pragma unroll
        for (int hp = 0; hp < 4; ++hp) {
            const short8 b0 = *reinterpret_cast<const short8*>(
                &KL[jt & 1][m16][(hh * 4 + hp) * 64 + quad * 8]);
            const short8 b1 = *reinterpret_cast<const short8*>(
                &KL[jt & 1][m16][(hh * 4 + hp) * 64 + 32 + quad * 8]);
            f32x4 c = {0.f, 0.f, 0.f, 0.f};
            c = __builtin_amdgcn_mfma_f32_16x16x32_bf16(aq[hp][0], b0, c, 0, 0, 0);
            c = __builtin_amdgcn_mfma_f32_16x16x32_bf16(aq[hp][1], b1, c, 0, 0, 0);
            #pragma unroll
            for (int r = 0; r < 4; ++r) dph[hp][r] += __expf(c[r] * 0.125f);
        }
        if (jt + 1 < 16) {                     // write-late into the spare buffer
            #pragma unroll
            for (int k = 0; k < 4; ++k)
                *reinterpret_cast<uint4*>(&KL[(jt + 1) & 1][srow][t4 * 8 + k * 128]) = kr[k];
        }
    }

    #pragma unroll
    for (int hp = 0; hp < 4; ++hp)
        #pragma unroll
        for (int off = 1; off <= 8; off <<= 1)
            #pragma unroll
            for (int r = 0; r < 4; ++r) dph[hp][r] += __shfl_xor(dph[hp][r], off, 64);
    if (m16 == 0) {
        const size_t i = (size_t)it * 32 + ih * 16 + quad * 4;
        #pragma unroll
        for (int hp = 0; hp < 4; ++hp)
            #pragma unroll
            for (int r = 0; r < 4; ++r)
                dnP[((size_t)(jc * BB + b) * SS + i + r) * HH + hh * 4 + hp] = dph[hp][r];
    }
}

// ---------------- K2: fused ew + PV (R4-exact, 67 us proven) ----------------
__global__ __launch_bounds__(256, 2) void attn_ewpv(
    const __hip_bfloat16* __restrict__ qws,
    const __hip_bfloat16* __restrict__ kws,
    const __hip_bfloat16* __restrict__ vTg,
    const float* __restrict__ dnP,
    int* __restrict__ cntI,
    int* __restrict__ slotJ,
    float* __restrict__ slotW,
    __hip_bfloat16* __restrict__ pvP)
{
    __shared__ __hip_bfloat16 KL[32][520];     // 33.3 KB (reused as epilogue bounce)
    __shared__ __hip_bfloat16 ewT[32][40];     // 2.6 KB
    __shared__ float invd[HH][32];             // 1 KB
    const int tid = threadIdx.x;
    const int wv = tid >> 6, lane = tid & 63, quad = lane >> 4, m16 = lane & 15;
    const int jc = blockIdx.x;               // 4 chunks x 512 j
    const int it = blockIdx.y;               // 64 tiles x 32 i
    const int b  = blockIdx.z;
    const size_t gb = (size_t)b * SS;
    const size_t g0 = gb + it * 32;
    const int ih = wv & 1;                   // i-half for score phase
    const int jh = wv >> 1;                  // j-half for score phase

    {   // denominators -> 0.125/D (head-mean folded in); 256 thr = HH*32 exactly
        const int h = tid >> 5, i = tid & 31;
        float s = 0.f;
        #pragma unroll
        for (int c = 0; c < JC1; ++c)
            s += dnP[((size_t)(c * BB + b) * SS + it * 32 + i) * HH + h];
        invd[h][i] = 0.125f / s;
    }

    short8 aq[HH][2];
    #pragma unroll
    for (int h = 0; h < HH; ++h)
        #pragma unroll
        for (int ks = 0; ks < 2; ++ks)
            aq[h][ks] = *reinterpret_cast<const short8*>(
                qws + (g0 + ih * 16 + m16) * EE + h * 64 + ks * 32 + quad * 8);

    f32x4 acc[2][8];
    #pragma unroll
    for (int mf = 0; mf < 2; ++mf)
        #pragma unroll
        for (int nf = 0; nf < 8; ++nf) acc[mf][nf] = (f32x4){0.f, 0.f, 0.f, 0.f};

    const int krow = tid >> 4, kcol = (tid & 15) * 32;
    // per-lane V row base: e = wv*128 + nf*16 + m16, k-offset quad*8
    const __hip_bfloat16* vrow0 = vTg + ((size_t)b * EE + wv * 128 + m16) * SS + quad * 8;

    for (int st = 0; st < 16; ++st) {
        const int j0 = jc * 512 + st * 32;
        // stage K subtile [32 j][512 feat] (global -> reg -> LDS, short-lived temps)
        #pragma unroll
        for (int rr = 0; rr < 2; ++rr) {
            const uint4* src = reinterpret_cast<const uint4*>(
                kws + (gb + j0 + rr * 16 + krow) * EE + kcol);
            uint4* dst = reinterpret_cast<uint4*>(&KL[rr * 16 + krow][kcol]);
            dst[0] = src[0]; dst[1] = src[1]; dst[2] = src[2]; dst[3] = src[3];
        }
        __syncthreads();                       // KL ready; prev-step PV done w/ ewT

        // scores: wave's (ih, jh) quadrant of the 32x32 tile, all heads
        float wsum[4] = {0.f, 0.f, 0.f, 0.f};
        #pragma unroll
        for (int h = 0; h < HH; ++h) {
            const short8 b0 = *reinterpret_cast<const short8*>(
                &KL[jh * 16 + m16][h * 64 + quad * 8]);
            const short8 b1 = *reinterpret_cast<const short8*>(
                &KL[jh * 16 + m16][h * 64 + 32 + quad * 8]);
            f32x4 c = {0.f, 0.f, 0.f, 0.f};
            c = __builtin_amdgcn_mfma_f32_16x16x32_bf16(aq[h][0], b0, c, 0, 0, 0);
            c = __builtin_amdgcn_mfma_f32_16x16x32_bf16(aq[h][1], b1, c, 0, 0, 0);
            #pragma unroll
            for (int r = 0; r < 4; ++r)
                wsum[r] += __expf(c[r] * 0.125f) * invd[h][ih * 16 + quad * 4 + r];
        }
        #pragma unroll
        for (int r = 0; r < 4; ++r) {
            const __hip_bfloat16 wb = __float2bfloat16(wsum[r]);
            ewT[ih * 16 + quad * 4 + r][jh * 16 + m16] = wb;
            if ((float)wb > 0.1f) {            // rare: adjacency crossing
                const int li = ih * 16 + quad * 4 + r;
                const int idx = atomicAdd(&cntI[g0 + li], 1);
                if (idx < 16) {
                    slotJ[((size_t)g0 + li) * 16 + idx] = j0 + jh * 16 + m16;
                    slotW[((size_t)g0 + li) * 16 + idx] = (float)wb;
                }
            }
        }
        __syncthreads();                       // ewT ready

        // PV: V B-frags straight from global (L2-resident), consumed immediately
        {
            short8 vb[8];
            #pragma unroll
            for (int nf = 0; nf < 8; ++nf)
                vb[nf] = *reinterpret_cast<const short8*>(vrow0 + (size_t)(nf * 16) * SS + j0);
            const short8 a0 = *reinterpret_cast<const short8*>(&ewT[m16][quad * 8]);
            const short8 a1 = *reinterpret_cast<const short8*>(&ewT[16 + m16][quad * 8]);
            #pragma unroll
            for (int nf = 0; nf < 8; ++nf) {
                acc[0][nf] = __builtin_amdgcn_mfma_f32_16x16x32_bf16(a0, vb[nf], acc[0][nf], 0, 0, 0);
                acc[1][nf] = __builtin_amdgcn_mfma_f32_16x16x32_bf16(a1, vb[nf], acc[1][nf], 0, 0, 0);
            }
        }
    }

    // epilogue: bounce acc through KL for coalesced bf16 writes
    #pragma unroll
    for (int mf = 0; mf < 2; ++mf)
        #pragma unroll
        for (int nf = 0; nf < 8; ++nf)
            #pragma unroll
            for (int r = 0; r < 4; ++r)
                KL[mf * 16 + quad * 4 + r][wv * 128 + nf * 16 + m16] =
                    __float2bfloat16(acc[mf][nf][r]);
    __syncthreads();
    const int orow = tid >> 3;
    const int oc = (tid & 7) * 64;
    const uint4* s = reinterpret_cast<const uint4*>(&KL[orow][oc]);
    uint4* d = reinterpret_cast<uint4*>(
        pvP + ((size_t)jc * NN + g0 + orow) * EE + oc);
    #pragma unroll
    for (int q = 0; q < 8; ++q) d[q] = s[q];
}

extern "C" void kernel_launch(void* const* d_in, const int* in_sizes, int n_in,
                              void* d_out, int out_size, void* d_ws, size_t ws_size,
                              hipStream_t stream)
{
    const float* x   = (const float*)d_in[0];
    const float* Wq  = (const float*)d_in[1];
    const float* bq  = (const float*)d_in[2];
    const float* Wk  = (const float*)d_in[3];
    const float* bk  = (const float*)d_in[4];
    const float* Wv  = (const float*)d_in[5];
    const float* bv  = (const float*)d_in[6];
    const float* Wm1 = (const float*)d_in[7];
    const float* bm1 = (const float*)d_in[8];
    const float* Wm2 = (const float*)d_in[9];
    const float* bm2 = (const float*)d_in[10];
    const float* Wo  = (const float*)d_in[11];
    const float* bo  = (const float*)d_in[12];

    char* ws = (char*)d_ws;
    const size_t MB = 1024 * 1024;
    __hip_bfloat16* qb = (__hip_bfloat16*)(ws + 0);        // q            4MB
    __hip_bfloat16* kb = (__hip_bfloat16*)(ws + 4*MB);     // k -> hm      4MB
    __hip_bfloat16* vT = (__hip_bfloat16*)(ws + 8*MB);     // V^T [b][e][j] 4MB
    __hip_bfloat16* pvP = (__hip_bfloat16*)(ws + 12*MB);   // PV partials [4][NN][EE] 16MB
    float* dnP = (float*)(ws + 28*MB);                     // denom partials 1MB
    int*   cntI = (int*)(ws + 29*MB);                      // neighbor cnt  16KB
    int*   slotJ = (int*)(ws + 29*MB + 64*1024);           // crossing j    256KB
    float* slotW = (float*)(ws + 29*MB + 384*1024);        // crossing w    256KB
    const bool EXT = (ws_size >= 38 * MB);
    __hip_bfloat16* xb   = (__hip_bfloat16*)(ws + 30*MB);          // 4MB
    __hip_bfloat16* wqb  = (__hip_bfloat16*)(ws + 34*MB);
    __hip_bfloat16* wkb  = (__hip_bfloat16*)(ws + 34*MB + 512*1024);
    __hip_bfloat16* wvb  = (__hip_bfloat16*)(ws + 35*MB);
    __hip_bfloat16* wm1b = (__hip_bfloat16*)(ws + 35*MB + 512*1024);
    __hip_bfloat16* wm2b = (__hip_bfloat16*)(ws + 36*MB + 256*1024);
    __hip_bfloat16* wob  = (__hip_bfloat16*)(ws + 36*MB + 768*1024);

    dim3 blk(256, 1, 1);
    dim3 gg(EE / 64, NN / 64, 1);

    if (EXT) {
        conv_bf16<<<dim3(2048, 7, 1), blk, 0, stream>>>(
            x, Wq, Wk, Wv, Wm1, Wm2, Wo, xb, wqb, wkb, wvb, wm1b, wm2b, wob);
        qkv_gemm<1><<<dim3(24, NN / 64, 1), blk, 0, stream>>>(
            xb, wqb, bq, wkb, bk, wvb, bv, qb, kb, vT);
    } else {
        qkv_gemm<0><<<dim3(24, NN / 64, 1), blk, 0, stream>>>(
            x, Wq, bq, Wk, bk, Wv, bv, qb, kb, vT);
    }
    attn_denoms<<<dim3(JC1, SS / 32, BB), blk, 0, stream>>>(qb, kb, dnP, cntI);
    attn_ewpv<<<dim3(JCP, SS / 32, BB), blk, 0, stream>>>(
        qb, kb, vT, dnP, cntI, slotJ, slotW, pvP);
    if (EXT) {
        gemm_bt<1,1,1,0><<<gg, blk, 0, stream>>>(xb, wm1b, bm1, kb, EE + HH,
            nullptr, nullptr, nullptr, nullptr, nullptr);
        gemm_bt<2,1,1,0><<<gg, blk, 0, stream>>>(kb, wm2b, bm2, qb, EE,
            pvP, cntI, slotJ, slotW, x);
        gemm_bt<0,1,1,1><<<gg, blk, 0, stream>>>(qb, wob, bo, d_out, EE,
            nullptr, nullptr, nullptr, nullptr, nullptr);
    } else {
        gemm_bt<1,0,0,0><<<gg, blk, 0, stream>>>(x, Wm1, bm1, kb, EE + HH,
            nullptr, nullptr, nullptr, nullptr, nullptr);
        gemm_bt<2,1,0,0><<<gg, blk, 0, stream>>>(kb, Wm2, bm2, qb, EE,
            pvP, cntI, slotJ, slotW, x);
        gemm_bt<0,1,0,1><<<gg, blk, 0, stream>>>(qb, Wo, bo, d_out, EE,
            nullptr, nullptr, nullptr, nullptr, nullptr);
    }
}

// Round 13
// 219.682 us; speedup vs baseline: 1.1884x; 1.0005x over previous
//
#include <hip/hip_runtime.h>
#include <hip/hip_bf16.h>
#include <math.h>

#define BB 2
#define SS 2048
#define EE 512
#define HH 8
#define NN (BB*SS)
#define JC1 8   // denoms j-chunks (256 j each)
#define JCP 4   // fused ew+pv j-chunks (512 j each)

typedef __attribute__((ext_vector_type(8))) short short8;
typedef __attribute__((ext_vector_type(4))) float f32x4;
typedef const __attribute__((address_space(1))) unsigned int gu32;
typedef __attribute__((address_space(3))) unsigned int lu32;

__device__ __forceinline__ float b2f(short v){
    return __uint_as_float(((unsigned)(unsigned short)v) << 16);
}
__device__ __forceinline__ unsigned f2bf(float f){
    unsigned u = __float_as_uint(f);
    u += 0x7fffu + ((u >> 16) & 1u);
    return u >> 16;
}
__device__ __forceinline__ void stage16_f32(const float* __restrict__ src,
                                            __hip_bfloat16* dst){
    const float4 f0 = *reinterpret_cast<const float4*>(src);
    const float4 f1 = *reinterpret_cast<const float4*>(src + 4);
    const float4 f2 = *reinterpret_cast<const float4*>(src + 8);
    const float4 f3 = *reinterpret_cast<const float4*>(src + 12);
    uint4 o0, o1;
    o0.x = f2bf(f0.x) | (f2bf(f0.y) << 16);
    o0.y = f2bf(f0.z) | (f2bf(f0.w) << 16);
    o0.z = f2bf(f1.x) | (f2bf(f1.y) << 16);
    o0.w = f2bf(f1.z) | (f2bf(f1.w) << 16);
    o1.x = f2bf(f2.x) | (f2bf(f2.y) << 16);
    o1.y = f2bf(f2.z) | (f2bf(f2.w) << 16);
    o1.z = f2bf(f3.x) | (f2bf(f3.y) << 16);
    o1.w = f2bf(f3.z) | (f2bf(f3.w) << 16);
    *reinterpret_cast<uint4*>(dst) = o0;
    *reinterpret_cast<uint4*>(dst + 8) = o1;
}
__device__ __forceinline__ void stage16_b16(const __hip_bfloat16* __restrict__ src,
                                            __hip_bfloat16* dst){
    const uint4* s = reinterpret_cast<const uint4*>(src);
    uint4* d = reinterpret_cast<uint4*>(dst);
    d[0] = s[0]; d[1] = s[1];
}
// pack 16 f32 (4x float4 in regs) -> 16 bf16 in LDS
__device__ __forceinline__ void pack16(const float4* f, __hip_bfloat16* dst){
    uint4 o0, o1;
    o0.x = f2bf(f[0].x) | (f2bf(f[0].y) << 16);
    o0.y = f2bf(f[0].z) | (f2bf(f[0].w) << 16);
    o0.z = f2bf(f[1].x) | (f2bf(f[1].y) << 16);
    o0.w = f2bf(f[1].z) | (f2bf(f[1].w) << 16);
    o1.x = f2bf(f[2].x) | (f2bf(f[2].y) << 16);
    o1.y = f2bf(f[2].z) | (f2bf(f[2].w) << 16);
    o1.z = f2bf(f[3].x) | (f2bf(f[3].y) << 16);
    o1.w = f2bf(f[3].z) | (f2bf(f[3].w) << 16);
    *reinterpret_cast<uint4*>(dst) = o0;
    *reinterpret_cast<uint4*>(dst + 8) = o1;
}

// ---------------- one-time f32 -> bf16 conversion of x + 6 weights ----------------
__global__ void conv_bf16(
    const float* s0, const float* s1, const float* s2, const float* s3,
    const float* s4, const float* s5, const float* s6,
    __hip_bfloat16* d0, __hip_bfloat16* d1, __hip_bfloat16* d2, __hip_bfloat16* d3,
    __hip_bfloat16* d4, __hip_bfloat16* d5, __hip_bfloat16* d6)
{
    const int which = blockIdx.y;
    const float* s; __hip_bfloat16* d; int n;
    switch (which) {
        case 0: s = s0; d = d0; n = 2097152; break;
        case 1: s = s1; d = d1; n = 262144; break;
        case 2: s = s2; d = d2; n = 262144; break;
        case 3: s = s3; d = d3; n = 262144; break;
        case 4: s = s4; d = d4; n = 266240; break;
        case 5: s = s5; d = d5; n = 262144; break;
        default: s = s6; d = d6; n = 262144; break;
    }
    const int base = (blockIdx.x * 256 + threadIdx.x) * 4;
    if (base >= n) return;
    const float4 f = *reinterpret_cast<const float4*>(s + base);
    uint2 o;
    o.x = f2bf(f.x) | (f2bf(f.y) << 16);
    o.y = f2bf(f.z) | (f2bf(f.w) << 16);
    *reinterpret_cast<uint2*>(d + base) = o;
}

// ---------------- fused QKV projection (MFMA) — R11-verbatim ----------------
template<int B16>
__global__ __launch_bounds__(256) void qkv_gemm(
    const void* __restrict__ x,
    const void* __restrict__ Wq, const float* __restrict__ bq,
    const void* __restrict__ Wk, const float* __restrict__ bk,
    const void* __restrict__ Wv, const float* __restrict__ bv,
    __hip_bfloat16* __restrict__ qb,
    __hip_bfloat16* __restrict__ kb,
    __hip_bfloat16* __restrict__ vT)
{
    __shared__ __hip_bfloat16 As[64][72];
    __shared__ __hip_bfloat16 Bs[64][72];
    const int tid = threadIdx.x;
    const int which = blockIdx.x >> 3;
    const int col0 = (blockIdx.x & 7) * 64;
    const int row0 = blockIdx.y * 64;
    const int wv = tid >> 6, lane = tid & 63, quad = lane >> 4, m16 = lane & 15;
    const int sr = tid >> 2;
    const int sc = (tid & 3) * 16;
    const void* W    = (which == 0) ? Wq : (which == 1) ? Wk : Wv;
    const float* bias = (which == 0) ? bq : (which == 1) ? bk : bv;

    f32x4 acc[4];
    #pragma unroll
    for (int nt = 0; nt < 4; ++nt) acc[nt] = (f32x4){0.f, 0.f, 0.f, 0.f};

    for (int k0 = 0; k0 < 512; k0 += 64) {
        if (B16) {
            stage16_b16((const __hip_bfloat16*)x + (size_t)(row0 + sr) * EE + k0 + sc, &As[sr][sc]);
            stage16_b16((const __hip_bfloat16*)W + (size_t)(col0 + sr) * EE + k0 + sc, &Bs[sr][sc]);
        } else {
            stage16_f32((const float*)x + (size_t)(row0 + sr) * EE + k0 + sc, &As[sr][sc]);
            stage16_f32((const float*)W + (size_t)(col0 + sr) * EE + k0 + sc, &Bs[sr][sc]);
        }
        __syncthreads();
        #pragma unroll
        for (int ks = 0; ks < 2; ++ks) {
            const short8 a = *reinterpret_cast<const short8*>(
                &As[wv * 16 + m16][ks * 32 + quad * 8]);
            #pragma unroll
            for (int nt = 0; nt < 4; ++nt) {
                const short8 b = *reinterpret_cast<const short8*>(
                    &Bs[nt * 16 + m16][ks * 32 + quad * 8]);
                acc[nt] = __builtin_amdgcn_mfma_f32_16x16x32_bf16(a, b, acc[nt], 0, 0, 0);
            }
        }
        __syncthreads();
    }

    if (which == 2) {
        #pragma unroll
        for (int nt = 0; nt < 4; ++nt) {
            const float bb = bias[col0 + nt * 16 + m16];
            #pragma unroll
            for (int r = 0; r < 4; ++r)
                Bs[wv * 16 + quad * 4 + r][nt * 16 + m16] =
                    __float2bfloat16(acc[nt][r] + bb);
        }
        __syncthreads();
        const int bb2 = row0 >> 11;
        const int j0 = row0 & (SS - 1);
        const int er = tid >> 2;
        const int js = (tid & 3) * 16;
        unsigned pk[8];
        #pragma unroll
        for (int p = 0; p < 8; ++p) {
            const unsigned lo = *reinterpret_cast<const unsigned short*>(&Bs[js + 2*p][er]);
            const unsigned hi = *reinterpret_cast<const unsigned short*>(&Bs[js + 2*p + 1][er]);
            pk[p] = lo | (hi << 16);
        }
        uint4 s0; s0.x = pk[0]; s0.y = pk[1]; s0.z = pk[2]; s0.w = pk[3];
        uint4 s1; s1.x = pk[4]; s1.y = pk[5]; s1.z = pk[6]; s1.w = pk[7];
        __hip_bfloat16* dst = vT + ((size_t)(bb2 * EE + col0 + er)) * SS + j0 + js;
        *reinterpret_cast<uint4*>(dst) = s0;
        *reinterpret_cast<uint4*>(dst + 8) = s1;
    } else {
        __hip_bfloat16* C = (which == 0) ? qb : kb;
        #pragma unroll
        for (int nt = 0; nt < 4; ++nt) {
            const int gn = col0 + nt * 16 + m16;
            const float bb = bias[gn];
            #pragma unroll
            for (int r = 0; r < 4; ++r) {
                const int gm = row0 + wv * 16 + quad * 4 + r;
                C[(size_t)gm * EE + gn] = __float2bfloat16(acc[nt][r] + bb);
            }
        }
    }
}

// ---------------- MFMA GEMM (MLP1 / MLP2+combine / out-proj) — R12-verbatim ----------------
template<int MODE, int AB16, int WB16, int CF32>
__global__ __launch_bounds__(256) void gemm_bt(
    const void* __restrict__ Av,
    const void* __restrict__ Wv_,
    const float* __restrict__ bias,
    void* __restrict__ Cv,
    int ldb,
    const __hip_bfloat16* __restrict__ pvPp,
    const int* __restrict__ cntIp,
    const int* __restrict__ slotJp,
    const float* __restrict__ slotWp,
    const float* __restrict__ xf)
{
    __shared__ __hip_bfloat16 As[2][64][72];
    __shared__ __hip_bfloat16 Bs[2][64][72];
    const int tid = threadIdx.x;
    const int col0 = blockIdx.x * 64;
    const int row0 = blockIdx.y * 64;
    const int wv = tid >> 6, lane = tid & 63, quad = lane >> 4, m16 = lane & 15;
    const int sr = tid >> 2;
    const int sc = (tid & 3) * 16;

    f32x4 acc[4];
    #pragma unroll
    for (int nt = 0; nt < 4; ++nt) acc[nt] = (f32x4){0.f, 0.f, 0.f, 0.f};

    {   // prologue: tile 0 -> buffer 0
        if (AB16)
            stage16_b16((const __hip_bfloat16*)Av + (size_t)(row0 + sr) * EE + sc, &As[0][sr][sc]);
        else
            stage16_f32((const float*)Av + (size_t)(row0 + sr) * EE + sc, &As[0][sr][sc]);
        if (WB16)
            stage16_b16((const __hip_bfloat16*)Wv_ + (size_t)(col0 + sr) * ldb + sc, &Bs[0][sr][sc]);
        else
            stage16_f32((const float*)Wv_ + (size_t)(col0 + sr) * ldb + sc, &Bs[0][sr][sc]);
    }

    for (int kt = 0; kt < 8; ++kt) {
        __syncthreads();                       // buffer kt&1 ready
        uint4 ra[2], rb[2];
        float4 fa[4], fb[4];
        if (kt + 1 < 8) {                      // issue-early: next tile -> regs
            const int k0 = (kt + 1) * 64;
            if (AB16) {
                const uint4* s = reinterpret_cast<const uint4*>(
                    (const __hip_bfloat16*)Av + (size_t)(row0 + sr) * EE + k0 + sc);
                ra[0] = s[0]; ra[1] = s[1];
            } else {
                const float4* s = reinterpret_cast<const float4*>(
                    (const float*)Av + (size_t)(row0 + sr) * EE + k0 + sc);
                fa[0] = s[0]; fa[1] = s[1]; fa[2] = s[2]; fa[3] = s[3];
            }
            if (WB16) {
                const uint4* s = reinterpret_cast<const uint4*>(
                    (const __hip_bfloat16*)Wv_ + (size_t)(col0 + sr) * ldb + k0 + sc);
                rb[0] = s[0]; rb[1] = s[1];
            } else {
                const float4* s = reinterpret_cast<const float4*>(
                    (const float*)Wv_ + (size_t)(col0 + sr) * ldb + k0 + sc);
                fb[0] = s[0]; fb[1] = s[1]; fb[2] = s[2]; fb[3] = s[3];
            }
        }
        const int cur = kt & 1;
        #pragma unroll
        for (int ks = 0; ks < 2; ++ks) {
            const short8 a = *reinterpret_cast<const short8*>(
                &As[cur][wv * 16 + m16][ks * 32 + quad * 8]);
            #pragma unroll
            for (int nt = 0; nt < 4; ++nt) {
                const short8 b = *reinterpret_cast<const short8*>(
                    &Bs[cur][nt * 16 + m16][ks * 32 + quad * 8]);
                acc[nt] = __builtin_amdgcn_mfma_f32_16x16x32_bf16(a, b, acc[nt], 0, 0, 0);
            }
        }
        if (kt + 1 < 8) {                      // write-late into the spare buffer
            const int nb = (kt + 1) & 1;
            if (AB16) {
                uint4* d = reinterpret_cast<uint4*>(&As[nb][sr][sc]);
                d[0] = ra[0]; d[1] = ra[1];
            } else pack16(fa, &As[nb][sr][sc]);
            if (WB16) {
                uint4* d = reinterpret_cast<uint4*>(&Bs[nb][sr][sc]);
                d[0] = rb[0]; d[1] = rb[1];
            } else pack16(fb, &Bs[nb][sr][sc]);
        }
    }

    if (MODE == 2) {                           // MLP2 + fused pv-combine
        #pragma unroll
        for (int r = 0; r < 4; ++r) {
            const int gm = row0 + wv * 16 + quad * 4 + r;
            const int cn = cntIp[gm];
            const int bloc = gm >> 11;
            #pragma unroll
            for (int nt = 0; nt < 4; ++nt) {
                const int gn = col0 + nt * 16 + m16;
                const size_t ci = (size_t)gm * EE + gn;
                float c = acc[nt][r] + bias[gn];
                #pragma unroll
                for (int cc = 0; cc < JCP; ++cc)
                    c += b2f(reinterpret_cast<const short*>(pvPp)
                             [(size_t)cc * NN * EE + ci]);
                if (cn > 0) {                  // exact rare path: masked mean
                    const float inv = 1.f / (float)cn;
                    const int ns = cn < 16 ? cn : 16;
                    for (int t = 0; t < ns; ++t) {
                        const int j = slotJp[(size_t)gm * 16 + t];
                        c += slotWp[(size_t)gm * 16 + t] * inv *
                             xf[((size_t)bloc * SS + j) * EE + gn];
                    }
                }
                ((__hip_bfloat16*)Cv)[ci] = __float2bfloat16(c);
            }
        }
        return;
    }

    #pragma unroll
    for (int nt = 0; nt < 4; ++nt) {
        const int gn = col0 + nt * 16 + m16;
        float bb = bias[gn];
        if (MODE == 1) {
            float ts = 0.f;
            #pragma unroll
            for (int h = 0; h < 8; ++h) {
                const size_t wi = (size_t)gn * ldb + 512 + h;
                ts += WB16 ? (float)((const __hip_bfloat16*)Wv_)[wi]
                           : ((const float*)Wv_)[wi];
            }
            bb += ts * (1.0f / (float)SS);
        }
        #pragma unroll
        for (int r = 0; r < 4; ++r) {
            const int gm = row0 + wv * 16 + quad * 4 + r;
            const size_t ci = (size_t)gm * EE + gn;
            float c = acc[nt][r] + bb;
            if (MODE == 1) c = 0.5f * c * (1.0f + erff(c * 0.70710678118654752f));
            if (CF32) ((float*)Cv)[ci] = c;
            else      ((__hip_bfloat16*)Cv)[ci] = __float2bfloat16(c);
        }
    }
}

// ---------------- K1: partial softmax denominators (32-i split + gload_lds) ----------------
// Double-buffered K tile via global_load_lds (zero staging VGPR/VALU, HW
// direct-to-LDS DMA; dest linear per row, content identical to reg path).
// Issue next tile BEFORE compute; the barrier's vmcnt drain publishes it.
__global__ __launch_bounds__(256) void attn_denoms(
    const __hip_bfloat16* __restrict__ qws,
    const __hip_bfloat16* __restrict__ kws,
    float* __restrict__ dnP,
    int* __restrict__ cntI)
{
    __shared__ __hip_bfloat16 KL[2][16][520];   // 33.3 KB
    const int tid = threadIdx.x;
    const int wv = tid >> 6, lane = tid & 63, quad = lane >> 4, m16 = lane & 15;
    const int jc = blockIdx.x;              // 8 chunks x 256 j
    const int it = blockIdx.y;              // 64 tiles x 32 i
    const int b  = blockIdx.z;
    const size_t g0 = (size_t)b * SS + it * 32;
    const size_t gb = (size_t)b * SS;
    const int ih = wv & 1, hh = wv >> 1;

    if (jc == 0 && tid < 32) cntI[g0 + tid] = 0;

    short8 aq[4][2];
    #pragma unroll
    for (int hp = 0; hp < 4; ++hp)
        #pragma unroll
        for (int ks = 0; ks < 2; ++ks)
            aq[hp][ks] = *reinterpret_cast<const short8*>(
                qws + (g0 + ih * 16 + m16) * EE + (hh * 4 + hp) * 64 + ks * 32 + quad * 8);

    float dph[4][4];
    #pragma unroll
    for (int hp = 0; hp < 4; ++hp)
        #pragma unroll
        for (int r = 0; r < 4; ++r) dph[hp][r] = 0.f;

    {   // prologue: tile 0 -> KL[0]; each wave stages 4 rows (1 DMA per row)
        #pragma unroll
        for (int rr = 0; rr < 4; ++rr) {
            const int row = wv * 4 + rr;
            const __hip_bfloat16* g = kws + (gb + jc * 256 + row) * EE + lane * 8;
            __builtin_amdgcn_global_load_lds(
                (gu32*)(const void*)g, (lu32*)(void*)&KL[0][row][0], 16, 0, 0);
        }
    }

    for (int jt = 0; jt < 16; ++jt) {
        __syncthreads();                       // vmcnt drained: KL[jt&1] ready
        if (jt + 1 < 16) {                     // issue next tile into spare buffer
            #pragma unroll
            for (int rr = 0; rr < 4; ++rr) {
                const int row = wv * 4 + rr;
                const __hip_bfloat16* g =
                    kws + (gb + jc * 256 + (jt + 1) * 16 + row) * EE + lane * 8;
                __builtin_amdgcn_global_load_lds(
                    (gu32*)(const void*)g,
                    (lu32*)(void*)&KL[(jt + 1) & 1][row][0], 16, 0, 0);
            }
        }
        __builtin_amdgcn_s_setprio(1);
        #pragma unroll
        for (int hp = 0; hp < 4; ++hp) {
            const short8 b0 = *reinterpret_cast<const short8*>(
                &KL[jt & 1][m16][(hh * 4 + hp) * 64 + quad * 8]);
            const short8 b1 = *reinterpret_cast<const short8*>(
                &KL[jt & 1][m16][(hh * 4 + hp) * 64 + 32 + quad * 8]);
            f32x4 c = {0.f, 0.f, 0.f, 0.f};
            c = __builtin_amdgcn_mfma_f32_16x16x32_bf16(aq[hp][0], b0, c, 0, 0, 0);
            c = __builtin_amdgcn_mfma_f32_16x16x32_bf16(aq[hp][1], b1, c, 0, 0, 0);
            #pragma unroll
            for (int r = 0; r < 4; ++r) dph[hp][r] += __expf(c[r] * 0.125f);
        }
        __builtin_amdgcn_s_setprio(0);
    }

    #pragma unroll
    for (int hp = 0; hp < 4; ++hp)
        #pragma unroll
        for (int off = 1; off <= 8; off <<= 1)
            #pragma unroll
            for (int r = 0; r < 4; ++r) dph[hp][r] += __shfl_xor(dph[hp][r], off, 64);
    if (m16 == 0) {
        const size_t i = (size_t)it * 32 + ih * 16 + quad * 4;
        #pragma unroll
        for (int hp = 0; hp < 4; ++hp)
            #pragma unroll
            for (int r = 0; r < 4; ++r)
                dnP[((size_t)(jc * BB + b) * SS + i + r) * HH + hh * 4 + hp] = dph[hp][r];
    }
}

// ---------------- K2: fused ew + PV (R4 schedule + gload_lds staging) ----------------
// Identical 2-barrier schedule and layout to the proven 67-us kernel; ONLY the
// K staging changed: global_load_lds width-16, one DMA per row (64 lanes x 16B
// = 1024B contiguous). Kills the 8-way ds_write staging bank conflicts and the
// VGPR round-trip. Reads unchanged (linear [32][520], 2-way = free). setprio
// around MFMA clusters (T5: 2 independent blocks/CU = phase diversity).
__global__ __launch_bounds__(256, 2) void attn_ewpv(
    const __hip_bfloat16* __restrict__ qws,
    const __hip_bfloat16* __restrict__ kws,
    const __hip_bfloat16* __restrict__ vTg,
    const float* __restrict__ dnP,
    int* __restrict__ cntI,
    int* __restrict__ slotJ,
    float* __restrict__ slotW,
    __hip_bfloat16* __restrict__ pvP)
{
    __shared__ __hip_bfloat16 KL[32][520];     // 33.3 KB (reused as epilogue bounce)
    __shared__ __hip_bfloat16 ewT[32][40];     // 2.6 KB
    __shared__ float invd[HH][32];             // 1 KB
    const int tid = threadIdx.x;
    const int wv = tid >> 6, lane = tid & 63, quad = lane >> 4, m16 = lane & 15;
    const int jc = blockIdx.x;               // 4 chunks x 512 j
    const int it = blockIdx.y;               // 64 tiles x 32 i
    const int b  = blockIdx.z;
    const size_t gb = (size_t)b * SS;
    const size_t g0 = gb + it * 32;
    const int ih = wv & 1;                   // i-half for score phase
    const int jh = wv >> 1;                  // j-half for score phase

    {   // denominators -> 0.125/D (head-mean folded in); 256 thr = HH*32 exactly
        const int h = tid >> 5, i = tid & 31;
        float s = 0.f;
        #pragma unroll
        for (int c = 0; c < JC1; ++c)
            s += dnP[((size_t)(c * BB + b) * SS + it * 32 + i) * HH + h];
        invd[h][i] = 0.125f / s;
    }

    short8 aq[HH][2];
    #pragma unroll
    for (int h = 0; h < HH; ++h)
        #pragma unroll
        for (int ks = 0; ks < 2; ++ks)
            aq[h][ks] = *reinterpret_cast<const short8*>(
                qws + (g0 + ih * 16 + m16) * EE + h * 64 + ks * 32 + quad * 8);

    f32x4 acc[2][8];
    #pragma unroll
    for (int mf = 0; mf < 2; ++mf)
        #pragma unroll
        for (int nf = 0; nf < 8; ++nf) acc[mf][nf] = (f32x4){0.f, 0.f, 0.f, 0.f};

    // per-lane V row base: e = wv*128 + nf*16 + m16, k-offset quad*8
    const __hip_bfloat16* vrow0 = vTg + ((size_t)b * EE + wv * 128 + m16) * SS + quad * 8;

    for (int st = 0; st < 16; ++st) {
        const int j0 = jc * 512 + st * 32;
        // stage K subtile [32 j][512 feat]: 8 DMAs per wave, 1 per row
        #pragma unroll
        for (int rr = 0; rr < 8; ++rr) {
            const int row = wv * 8 + rr;
            const __hip_bfloat16* g = kws + (gb + j0 + row) * EE + lane * 8;
            __builtin_amdgcn_global_load_lds(
                (gu32*)(const void*)g, (lu32*)(void*)&KL[row][0], 16, 0, 0);
        }
        __syncthreads();                       // vmcnt drained: KL ready; ewT free

        // scores: wave's (ih, jh) quadrant of the 32x32 tile, all heads
        float wsum[4] = {0.f, 0.f, 0.f, 0.f};
        __builtin_amdgcn_s_setprio(1);
        #pragma unroll
        for (int h = 0; h < HH; ++h) {
            const short8 b0 = *reinterpret_cast<const short8*>(
                &KL[jh * 16 + m16][h * 64 + quad * 8]);
            const short8 b1 = *reinterpret_cast<const short8*>(
                &KL[jh * 16 + m16][h * 64 + 32 + quad * 8]);
            f32x4 c = {0.f, 0.f, 0.f, 0.f};
            c = __builtin_amdgcn_mfma_f32_16x16x32_bf16(aq[h][0], b0, c, 0, 0, 0);
            c = __builtin_amdgcn_mfma_f32_16x16x32_bf16(aq[h][1], b1, c, 0, 0, 0);
            #pragma unroll
            for (int r = 0; r < 4; ++r)
                wsum[r] += __expf(c[r] * 0.125f) * invd[h][ih * 16 + quad * 4 + r];
        }
        __builtin_amdgcn_s_setprio(0);
        #pragma unroll
        for (int r = 0; r < 4; ++r) {
            const __hip_bfloat16 wb = __float2bfloat16(wsum[r]);
            ewT[ih * 16 + quad * 4 + r][jh * 16 + m16] = wb;
            if ((float)wb > 0.1f) {            // rare: adjacency crossing
                const int li = ih * 16 + quad * 4 + r;
                const int idx = atomicAdd(&cntI[g0 + li], 1);
                if (idx < 16) {
                    slotJ[((size_t)g0 + li) * 16 + idx] = j0 + jh * 16 + m16;
                    slotW[((size_t)g0 + li) * 16 + idx] = (float)wb;
                }
            }
        }
        __syncthreads();                       // ewT ready

        // PV: V B-frags straight from global (L2-resident), consumed immediately
        {
            short8 vb[8];
            #pragma unroll
            for (int nf = 0; nf < 8; ++nf)
                vb[nf] = *reinterpret_cast<const short8*>(vrow0 + (size_t)(nf * 16) * SS + j0);
            const short8 a0 = *reinterpret_cast<const short8*>(&ewT[m16][quad * 8]);
            const short8 a1 = *reinterpret_cast<const short8*>(&ewT[16 + m16][quad * 8]);
            __builtin_amdgcn_s_setprio(1);
            #pragma unroll
            for (int nf = 0; nf < 8; ++nf) {
                acc[0][nf] = __builtin_amdgcn_mfma_f32_16x16x32_bf16(a0, vb[nf], acc[0][nf], 0, 0, 0);
                acc[1][nf] = __builtin_amdgcn_mfma_f32_16x16x32_bf16(a1, vb[nf], acc[1][nf], 0, 0, 0);
            }
            __builtin_amdgcn_s_setprio(0);
        }
    }

    // epilogue: bounce acc through KL for coalesced bf16 writes
    #pragma unroll
    for (int mf = 0; mf < 2; ++mf)
        #pragma unroll
        for (int nf = 0; nf < 8; ++nf)
            #pragma unroll
            for (int r = 0; r < 4; ++r)
                KL[mf * 16 + quad * 4 + r][wv * 128 + nf * 16 + m16] =
                    __float2bfloat16(acc[mf][nf][r]);
    __syncthreads();
    const int orow = tid >> 3;
    const int oc = (tid & 7) * 64;
    const uint4* s = reinterpret_cast<const uint4*>(&KL[orow][oc]);
    uint4* d = reinterpret_cast<uint4*>(
        pvP + ((size_t)jc * NN + g0 + orow) * EE + oc);
    #pragma unroll
    for (int q = 0; q < 8; ++q) d[q] = s[q];
}

extern "C" void kernel_launch(void* const* d_in, const int* in_sizes, int n_in,
                              void* d_out, int out_size, void* d_ws, size_t ws_size,
                              hipStream_t stream)
{
    const float* x   = (const float*)d_in[0];
    const float* Wq  = (const float*)d_in[1];
    const float* bq  = (const float*)d_in[2];
    const float* Wk  = (const float*)d_in[3];
    const float* bk  = (const float*)d_in[4];
    const float* Wv  = (const float*)d_in[5];
    const float* bv  = (const float*)d_in[6];
    const float* Wm1 = (const float*)d_in[7];
    const float* bm1 = (const float*)d_in[8];
    const float* Wm2 = (const float*)d_in[9];
    const float* bm2 = (const float*)d_in[10];
    const float* Wo  = (const float*)d_in[11];
    const float* bo  = (const float*)d_in[12];

    char* ws = (char*)d_ws;
    const size_t MB = 1024 * 1024;
    __hip_bfloat16* qb = (__hip_bfloat16*)(ws + 0);        // q            4MB
    __hip_bfloat16* kb = (__hip_bfloat16*)(ws + 4*MB);     // k -> hm      4MB
    __hip_bfloat16* vT = (__hip_bfloat16*)(ws + 8*MB);     // V^T [b][e][j] 4MB
    __hip_bfloat16* pvP = (__hip_bfloat16*)(ws + 12*MB);   // PV partials [4][NN][EE] 16MB
    float* dnP = (float*)(ws + 28*MB);                     // denom partials 1MB
    int*   cntI = (int*)(ws + 29*MB);                      // neighbor cnt  16KB
    int*   slotJ = (int*)(ws + 29*MB + 64*1024);           // crossing j    256KB
    float* slotW = (float*)(ws + 29*MB + 384*1024);        // crossing w    256KB
    const bool EXT = (ws_size >= 38 * MB);
    __hip_bfloat16* xb   = (__hip_bfloat16*)(ws + 30*MB);          // 4MB
    __hip_bfloat16* wqb  = (__hip_bfloat16*)(ws + 34*MB);
    __hip_bfloat16* wkb  = (__hip_bfloat16*)(ws + 34*MB + 512*1024);
    __hip_bfloat16* wvb  = (__hip_bfloat16*)(ws + 35*MB);
    __hip_bfloat16* wm1b = (__hip_bfloat16*)(ws + 35*MB + 512*1024);
    __hip_bfloat16* wm2b = (__hip_bfloat16*)(ws + 36*MB + 256*1024);
    __hip_bfloat16* wob  = (__hip_bfloat16*)(ws + 36*MB + 768*1024);

    dim3 blk(256, 1, 1);
    dim3 gg(EE / 64, NN / 64, 1);

    if (EXT) {
        conv_bf16<<<dim3(2048, 7, 1), blk, 0, stream>>>(
            x, Wq, Wk, Wv, Wm1, Wm2, Wo, xb, wqb, wkb, wvb, wm1b, wm2b, wob);
        qkv_gemm<1><<<dim3(24, NN / 64, 1), blk, 0, stream>>>(
            xb, wqb, bq, wkb, bk, wvb, bv, qb, kb, vT);
    } else {
        qkv_gemm<0><<<dim3(24, NN / 64, 1), blk, 0, stream>>>(
            x, Wq, bq, Wk, bk, Wv, bv, qb, kb, vT);
    }
    attn_denoms<<<dim3(JC1, SS / 32, BB), blk, 0, stream>>>(qb, kb, dnP, cntI);
    attn_ewpv<<<dim3(JCP, SS / 32, BB), blk, 0, stream>>>(
        qb, kb, vT, dnP, cntI, slotJ, slotW, pvP);
    if (EXT) {
        gemm_bt<1,1,1,0><<<gg, blk, 0, stream>>>(xb, wm1b, bm1, kb, EE + HH,
            nullptr, nullptr, nullptr, nullptr, nullptr);
        gemm_bt<2,1,1,0><<<gg, blk, 0, stream>>>(kb, wm2b, bm2, qb, EE,
            pvP, cntI, slotJ, slotW, x);
        gemm_bt<0,1,1,1><<<gg, blk, 0, stream>>>(qb, wob, bo, d_out, EE,
            nullptr, nullptr, nullptr, nullptr, nullptr);
    } else {
        gemm_bt<1,0,0,0><<<gg, blk, 0, stream>>>(x, Wm1, bm1, kb, EE + HH,
            nullptr, nullptr, nullptr, nullptr, nullptr);
        gemm_bt<2,1,0,0><<<gg, blk, 0, stream>>>(kb, Wm2, bm2, qb, EE,
            pvP, cntI, slotJ, slotW, x);
        gemm_bt<0,1,0,1><<<gg, blk, 0, stream>>>(qb, Wo, bo, d_out, EE,
            nullptr, nullptr, nullptr, nullptr, nullptr);
    }
}

// Round 14
// 217.294 us; speedup vs baseline: 1.2015x; 1.0110x over previous
//
#include <hip/hip_runtime.h>
#include <hip/hip_bf16.h>
#include <math.h>

#define BB 2
#define SS 2048
#define EE 512
#define HH 8
#define NN (BB*SS)
#define JC1 8   // denoms j-chunks (256 j each)
#define JCP 4   // fused ew+pv j-chunks (512 j each)

typedef __attribute__((ext_vector_type(8))) short short8;
typedef __attribute__((ext_vector_type(4))) float f32x4;
typedef const __attribute__((address_space(1))) unsigned int gu32;
typedef __attribute__((address_space(3))) unsigned int lu32;

__device__ __forceinline__ float b2f(short v){
    return __uint_as_float(((unsigned)(unsigned short)v) << 16);
}
__device__ __forceinline__ unsigned f2bf(float f){
    unsigned u = __float_as_uint(f);
    u += 0x7fffu + ((u >> 16) & 1u);
    return u >> 16;
}
__device__ __forceinline__ void stage16_f32(const float* __restrict__ src,
                                            __hip_bfloat16* dst){
    const float4 f0 = *reinterpret_cast<const float4*>(src);
    const float4 f1 = *reinterpret_cast<const float4*>(src + 4);
    const float4 f2 = *reinterpret_cast<const float4*>(src + 8);
    const float4 f3 = *reinterpret_cast<const float4*>(src + 12);
    uint4 o0, o1;
    o0.x = f2bf(f0.x) | (f2bf(f0.y) << 16);
    o0.y = f2bf(f0.z) | (f2bf(f0.w) << 16);
    o0.z = f2bf(f1.x) | (f2bf(f1.y) << 16);
    o0.w = f2bf(f1.z) | (f2bf(f1.w) << 16);
    o1.x = f2bf(f2.x) | (f2bf(f2.y) << 16);
    o1.y = f2bf(f2.z) | (f2bf(f2.w) << 16);
    o1.z = f2bf(f3.x) | (f2bf(f3.y) << 16);
    o1.w = f2bf(f3.z) | (f2bf(f3.w) << 16);
    *reinterpret_cast<uint4*>(dst) = o0;
    *reinterpret_cast<uint4*>(dst + 8) = o1;
}
__device__ __forceinline__ void stage16_b16(const __hip_bfloat16* __restrict__ src,
                                            __hip_bfloat16* dst){
    const uint4* s = reinterpret_cast<const uint4*>(src);
    uint4* d = reinterpret_cast<uint4*>(dst);
    d[0] = s[0]; d[1] = s[1];
}
// pack 16 f32 (4x float4 in regs) -> 16 bf16 in LDS
__device__ __forceinline__ void pack16(const float4* f, __hip_bfloat16* dst){
    uint4 o0, o1;
    o0.x = f2bf(f[0].x) | (f2bf(f[0].y) << 16);
    o0.y = f2bf(f[0].z) | (f2bf(f[0].w) << 16);
    o0.z = f2bf(f[1].x) | (f2bf(f[1].y) << 16);
    o0.w = f2bf(f[1].z) | (f2bf(f[1].w) << 16);
    o1.x = f2bf(f[2].x) | (f2bf(f[2].y) << 16);
    o1.y = f2bf(f[2].z) | (f2bf(f[2].w) << 16);
    o1.z = f2bf(f[3].x) | (f2bf(f[3].y) << 16);
    o1.w = f2bf(f[3].z) | (f2bf(f[3].w) << 16);
    *reinterpret_cast<uint4*>(dst) = o0;
    *reinterpret_cast<uint4*>(dst + 8) = o1;
}

// ---------------- one-time f32 -> bf16 conversion of x + 6 weights ----------------
__global__ void conv_bf16(
    const float* s0, const float* s1, const float* s2, const float* s3,
    const float* s4, const float* s5, const float* s6,
    __hip_bfloat16* d0, __hip_bfloat16* d1, __hip_bfloat16* d2, __hip_bfloat16* d3,
    __hip_bfloat16* d4, __hip_bfloat16* d5, __hip_bfloat16* d6)
{
    const int which = blockIdx.y;
    const float* s; __hip_bfloat16* d; int n;
    switch (which) {
        case 0: s = s0; d = d0; n = 2097152; break;
        case 1: s = s1; d = d1; n = 262144; break;
        case 2: s = s2; d = d2; n = 262144; break;
        case 3: s = s3; d = d3; n = 262144; break;
        case 4: s = s4; d = d4; n = 266240; break;
        case 5: s = s5; d = d5; n = 262144; break;
        default: s = s6; d = d6; n = 262144; break;
    }
    const int base = (blockIdx.x * 256 + threadIdx.x) * 4;
    if (base >= n) return;
    const float4 f = *reinterpret_cast<const float4*>(s + base);
    uint2 o;
    o.x = f2bf(f.x) | (f2bf(f.y) << 16);
    o.y = f2bf(f.z) | (f2bf(f.w) << 16);
    *reinterpret_cast<uint2*>(d + base) = o;
}

// ---------------- fused QKV projection (MFMA) — R11-verbatim ----------------
template<int B16>
__global__ __launch_bounds__(256) void qkv_gemm(
    const void* __restrict__ x,
    const void* __restrict__ Wq, const float* __restrict__ bq,
    const void* __restrict__ Wk, const float* __restrict__ bk,
    const void* __restrict__ Wv, const float* __restrict__ bv,
    __hip_bfloat16* __restrict__ qb,
    __hip_bfloat16* __restrict__ kb,
    __hip_bfloat16* __restrict__ vT)
{
    __shared__ __hip_bfloat16 As[64][72];
    __shared__ __hip_bfloat16 Bs[64][72];
    const int tid = threadIdx.x;
    const int which = blockIdx.x >> 3;
    const int col0 = (blockIdx.x & 7) * 64;
    const int row0 = blockIdx.y * 64;
    const int wv = tid >> 6, lane = tid & 63, quad = lane >> 4, m16 = lane & 15;
    const int sr = tid >> 2;
    const int sc = (tid & 3) * 16;
    const void* W    = (which == 0) ? Wq : (which == 1) ? Wk : Wv;
    const float* bias = (which == 0) ? bq : (which == 1) ? bk : bv;

    f32x4 acc[4];
    #pragma unroll
    for (int nt = 0; nt < 4; ++nt) acc[nt] = (f32x4){0.f, 0.f, 0.f, 0.f};

    for (int k0 = 0; k0 < 512; k0 += 64) {
        if (B16) {
            stage16_b16((const __hip_bfloat16*)x + (size_t)(row0 + sr) * EE + k0 + sc, &As[sr][sc]);
            stage16_b16((const __hip_bfloat16*)W + (size_t)(col0 + sr) * EE + k0 + sc, &Bs[sr][sc]);
        } else {
            stage16_f32((const float*)x + (size_t)(row0 + sr) * EE + k0 + sc, &As[sr][sc]);
            stage16_f32((const float*)W + (size_t)(col0 + sr) * EE + k0 + sc, &Bs[sr][sc]);
        }
        __syncthreads();
        #pragma unroll
        for (int ks = 0; ks < 2; ++ks) {
            const short8 a = *reinterpret_cast<const short8*>(
                &As[wv * 16 + m16][ks * 32 + quad * 8]);
            #pragma unroll
            for (int nt = 0; nt < 4; ++nt) {
                const short8 b = *reinterpret_cast<const short8*>(
                    &Bs[nt * 16 + m16][ks * 32 + quad * 8]);
                acc[nt] = __builtin_amdgcn_mfma_f32_16x16x32_bf16(a, b, acc[nt], 0, 0, 0);
            }
        }
        __syncthreads();
    }

    if (which == 2) {
        #pragma unroll
        for (int nt = 0; nt < 4; ++nt) {
            const float bb = bias[col0 + nt * 16 + m16];
            #pragma unroll
            for (int r = 0; r < 4; ++r)
                Bs[wv * 16 + quad * 4 + r][nt * 16 + m16] =
                    __float2bfloat16(acc[nt][r] + bb);
        }
        __syncthreads();
        const int bb2 = row0 >> 11;
        const int j0 = row0 & (SS - 1);
        const int er = tid >> 2;
        const int js = (tid & 3) * 16;
        unsigned pk[8];
        #pragma unroll
        for (int p = 0; p < 8; ++p) {
            const unsigned lo = *reinterpret_cast<const unsigned short*>(&Bs[js + 2*p][er]);
            const unsigned hi = *reinterpret_cast<const unsigned short*>(&Bs[js + 2*p + 1][er]);
            pk[p] = lo | (hi << 16);
        }
        uint4 s0; s0.x = pk[0]; s0.y = pk[1]; s0.z = pk[2]; s0.w = pk[3];
        uint4 s1; s1.x = pk[4]; s1.y = pk[5]; s1.z = pk[6]; s1.w = pk[7];
        __hip_bfloat16* dst = vT + ((size_t)(bb2 * EE + col0 + er)) * SS + j0 + js;
        *reinterpret_cast<uint4*>(dst) = s0;
        *reinterpret_cast<uint4*>(dst + 8) = s1;
    } else {
        __hip_bfloat16* C = (which == 0) ? qb : kb;
        #pragma unroll
        for (int nt = 0; nt < 4; ++nt) {
            const int gn = col0 + nt * 16 + m16;
            const float bb = bias[gn];
            #pragma unroll
            for (int r = 0; r < 4; ++r) {
                const int gm = row0 + wv * 16 + quad * 4 + r;
                C[(size_t)gm * EE + gn] = __float2bfloat16(acc[nt][r] + bb);
            }
        }
    }
}

// ---------------- MFMA GEMM (MLP1 / MLP2+combine / out-proj) — R12-verbatim ----------------
template<int MODE, int AB16, int WB16, int CF32>
__global__ __launch_bounds__(256) void gemm_bt(
    const void* __restrict__ Av,
    const void* __restrict__ Wv_,
    const float* __restrict__ bias,
    void* __restrict__ Cv,
    int ldb,
    const __hip_bfloat16* __restrict__ pvPp,
    const int* __restrict__ cntIp,
    const int* __restrict__ slotJp,
    const float* __restrict__ slotWp,
    const float* __restrict__ xf)
{
    __shared__ __hip_bfloat16 As[2][64][72];
    __shared__ __hip_bfloat16 Bs[2][64][72];
    const int tid = threadIdx.x;
    const int col0 = blockIdx.x * 64;
    const int row0 = blockIdx.y * 64;
    const int wv = tid >> 6, lane = tid & 63, quad = lane >> 4, m16 = lane & 15;
    const int sr = tid >> 2;
    const int sc = (tid & 3) * 16;

    f32x4 acc[4];
    #pragma unroll
    for (int nt = 0; nt < 4; ++nt) acc[nt] = (f32x4){0.f, 0.f, 0.f, 0.f};

    {   // prologue: tile 0 -> buffer 0
        if (AB16)
            stage16_b16((const __hip_bfloat16*)Av + (size_t)(row0 + sr) * EE + sc, &As[0][sr][sc]);
        else
            stage16_f32((const float*)Av + (size_t)(row0 + sr) * EE + sc, &As[0][sr][sc]);
        if (WB16)
            stage16_b16((const __hip_bfloat16*)Wv_ + (size_t)(col0 + sr) * ldb + sc, &Bs[0][sr][sc]);
        else
            stage16_f32((const float*)Wv_ + (size_t)(col0 + sr) * ldb + sc, &Bs[0][sr][sc]);
    }

    for (int kt = 0; kt < 8; ++kt) {
        __syncthreads();                       // buffer kt&1 ready
        uint4 ra[2], rb[2];
        float4 fa[4], fb[4];
        if (kt + 1 < 8) {                      // issue-early: next tile -> regs
            const int k0 = (kt + 1) * 64;
            if (AB16) {
                const uint4* s = reinterpret_cast<const uint4*>(
                    (const __hip_bfloat16*)Av + (size_t)(row0 + sr) * EE + k0 + sc);
                ra[0] = s[0]; ra[1] = s[1];
            } else {
                const float4* s = reinterpret_cast<const float4*>(
                    (const float*)Av + (size_t)(row0 + sr) * EE + k0 + sc);
                fa[0] = s[0]; fa[1] = s[1]; fa[2] = s[2]; fa[3] = s[3];
            }
            if (WB16) {
                const uint4* s = reinterpret_cast<const uint4*>(
                    (const __hip_bfloat16*)Wv_ + (size_t)(col0 + sr) * ldb + k0 + sc);
                rb[0] = s[0]; rb[1] = s[1];
            } else {
                const float4* s = reinterpret_cast<const float4*>(
                    (const float*)Wv_ + (size_t)(col0 + sr) * ldb + k0 + sc);
                fb[0] = s[0]; fb[1] = s[1]; fb[2] = s[2]; fb[3] = s[3];
            }
        }
        const int cur = kt & 1;
        #pragma unroll
        for (int ks = 0; ks < 2; ++ks) {
            const short8 a = *reinterpret_cast<const short8*>(
                &As[cur][wv * 16 + m16][ks * 32 + quad * 8]);
            #pragma unroll
            for (int nt = 0; nt < 4; ++nt) {
                const short8 b = *reinterpret_cast<const short8*>(
                    &Bs[cur][nt * 16 + m16][ks * 32 + quad * 8]);
                acc[nt] = __builtin_amdgcn_mfma_f32_16x16x32_bf16(a, b, acc[nt], 0, 0, 0);
            }
        }
        if (kt + 1 < 8) {                      // write-late into the spare buffer
            const int nb = (kt + 1) & 1;
            if (AB16) {
                uint4* d = reinterpret_cast<uint4*>(&As[nb][sr][sc]);
                d[0] = ra[0]; d[1] = ra[1];
            } else pack16(fa, &As[nb][sr][sc]);
            if (WB16) {
                uint4* d = reinterpret_cast<uint4*>(&Bs[nb][sr][sc]);
                d[0] = rb[0]; d[1] = rb[1];
            } else pack16(fb, &Bs[nb][sr][sc]);
        }
    }

    if (MODE == 2) {                           // MLP2 + fused pv-combine
        #pragma unroll
        for (int r = 0; r < 4; ++r) {
            const int gm = row0 + wv * 16 + quad * 4 + r;
            const int cn = cntIp[gm];
            const int bloc = gm >> 11;
            #pragma unroll
            for (int nt = 0; nt < 4; ++nt) {
                const int gn = col0 + nt * 16 + m16;
                const size_t ci = (size_t)gm * EE + gn;
                float c = acc[nt][r] + bias[gn];
                #pragma unroll
                for (int cc = 0; cc < JCP; ++cc)
                    c += b2f(reinterpret_cast<const short*>(pvPp)
                             [(size_t)cc * NN * EE + ci]);
                if (cn > 0) {                  // exact rare path: masked mean
                    const float inv = 1.f / (float)cn;
                    const int ns = cn < 16 ? cn : 16;
                    for (int t = 0; t < ns; ++t) {
                        const int j = slotJp[(size_t)gm * 16 + t];
                        c += slotWp[(size_t)gm * 16 + t] * inv *
                             xf[((size_t)bloc * SS + j) * EE + gn];
                    }
                }
                ((__hip_bfloat16*)Cv)[ci] = __float2bfloat16(c);
            }
        }
        return;
    }

    #pragma unroll
    for (int nt = 0; nt < 4; ++nt) {
        const int gn = col0 + nt * 16 + m16;
        float bb = bias[gn];
        if (MODE == 1) {
            float ts = 0.f;
            #pragma unroll
            for (int h = 0; h < 8; ++h) {
                const size_t wi = (size_t)gn * ldb + 512 + h;
                ts += WB16 ? (float)((const __hip_bfloat16*)Wv_)[wi]
                           : ((const float*)Wv_)[wi];
            }
            bb += ts * (1.0f / (float)SS);
        }
        #pragma unroll
        for (int r = 0; r < 4; ++r) {
            const int gm = row0 + wv * 16 + quad * 4 + r;
            const size_t ci = (size_t)gm * EE + gn;
            float c = acc[nt][r] + bb;
            if (MODE == 1) c = 0.5f * c * (1.0f + erff(c * 0.70710678118654752f));
            if (CF32) ((float*)Cv)[ci] = c;
            else      ((__hip_bfloat16*)Cv)[ci] = __float2bfloat16(c);
        }
    }
}

// ---------------- K1: partial softmax denominators (R13-verbatim) ----------------
__global__ __launch_bounds__(256) void attn_denoms(
    const __hip_bfloat16* __restrict__ qws,
    const __hip_bfloat16* __restrict__ kws,
    float* __restrict__ dnP,
    int* __restrict__ cntI)
{
    __shared__ __hip_bfloat16 KL[2][16][520];   // 33.3 KB
    const int tid = threadIdx.x;
    const int wv = tid >> 6, lane = tid & 63, quad = lane >> 4, m16 = lane & 15;
    const int jc = blockIdx.x;              // 8 chunks x 256 j
    const int it = blockIdx.y;              // 64 tiles x 32 i
    const int b  = blockIdx.z;
    const size_t g0 = (size_t)b * SS + it * 32;
    const size_t gb = (size_t)b * SS;
    const int ih = wv & 1, hh = wv >> 1;

    if (jc == 0 && tid < 32) cntI[g0 + tid] = 0;

    short8 aq[4][2];
    #pragma unroll
    for (int hp = 0; hp < 4; ++hp)
        #pragma unroll
        for (int ks = 0; ks < 2; ++ks)
            aq[hp][ks] = *reinterpret_cast<const short8*>(
                qws + (g0 + ih * 16 + m16) * EE + (hh * 4 + hp) * 64 + ks * 32 + quad * 8);

    float dph[4][4];
    #pragma unroll
    for (int hp = 0; hp < 4; ++hp)
        #pragma unroll
        for (int r = 0; r < 4; ++r) dph[hp][r] = 0.f;

    {   // prologue: tile 0 -> KL[0]; each wave stages 4 rows (1 DMA per row)
        #pragma unroll
        for (int rr = 0; rr < 4; ++rr) {
            const int row = wv * 4 + rr;
            const __hip_bfloat16* g = kws + (gb + jc * 256 + row) * EE + lane * 8;
            __builtin_amdgcn_global_load_lds(
                (gu32*)(const void*)g, (lu32*)(void*)&KL[0][row][0], 16, 0, 0);
        }
    }

    for (int jt = 0; jt < 16; ++jt) {
        __syncthreads();                       // vmcnt drained: KL[jt&1] ready
        if (jt + 1 < 16) {                     // issue next tile into spare buffer
            #pragma unroll
            for (int rr = 0; rr < 4; ++rr) {
                const int row = wv * 4 + rr;
                const __hip_bfloat16* g =
                    kws + (gb + jc * 256 + (jt + 1) * 16 + row) * EE + lane * 8;
                __builtin_amdgcn_global_load_lds(
                    (gu32*)(const void*)g,
                    (lu32*)(void*)&KL[(jt + 1) & 1][row][0], 16, 0, 0);
            }
        }
        __builtin_amdgcn_s_setprio(1);
        #pragma unroll
        for (int hp = 0; hp < 4; ++hp) {
            const short8 b0 = *reinterpret_cast<const short8*>(
                &KL[jt & 1][m16][(hh * 4 + hp) * 64 + quad * 8]);
            const short8 b1 = *reinterpret_cast<const short8*>(
                &KL[jt & 1][m16][(hh * 4 + hp) * 64 + 32 + quad * 8]);
            f32x4 c = {0.f, 0.f, 0.f, 0.f};
            c = __builtin_amdgcn_mfma_f32_16x16x32_bf16(aq[hp][0], b0, c, 0, 0, 0);
            c = __builtin_amdgcn_mfma_f32_16x16x32_bf16(aq[hp][1], b1, c, 0, 0, 0);
            #pragma unroll
            for (int r = 0; r < 4; ++r) dph[hp][r] += __expf(c[r] * 0.125f);
        }
        __builtin_amdgcn_s_setprio(0);
    }

    #pragma unroll
    for (int hp = 0; hp < 4; ++hp)
        #pragma unroll
        for (int off = 1; off <= 8; off <<= 1)
            #pragma unroll
            for (int r = 0; r < 4; ++r) dph[hp][r] += __shfl_xor(dph[hp][r], off, 64);
    if (m16 == 0) {
        const size_t i = (size_t)it * 32 + ih * 16 + quad * 4;
        #pragma unroll
        for (int hp = 0; hp < 4; ++hp)
            #pragma unroll
            for (int r = 0; r < 4; ++r)
                dnP[((size_t)(jc * BB + b) * SS + i + r) * HH + hh * 4 + hp] = dph[hp][r];
    }
}

// ---------------- K2: fused ew + PV (double-buffered gload_lds, 1 barrier/step) ----------------
// R13's DMA staging + KL/ewT double-buffering: gload-DMAs for step st+1 issue
// at the TOP of step st; the score phase (16 MFMA + 32 exp) covers the load
// latency; the single barrier's vmcnt drain publishes KL[st+1] AND ewTd[cur].
// Barriers: 32 -> 17. Hazards: all buffer crossings separated by >=1 barrier
// (KL buffers alternate; ewTd[cur] next written at st+2 > barrier(st+1)).
// LDS 72.8 KB -> 2 blocks/CU (current effective residency). V loads stay late.
__global__ __launch_bounds__(256, 2) void attn_ewpv(
    const __hip_bfloat16* __restrict__ qws,
    const __hip_bfloat16* __restrict__ kws,
    const __hip_bfloat16* __restrict__ vTg,
    const float* __restrict__ dnP,
    int* __restrict__ cntI,
    int* __restrict__ slotJ,
    float* __restrict__ slotW,
    __hip_bfloat16* __restrict__ pvP)
{
    __shared__ __hip_bfloat16 KL[2][32][520];  // 66.6 KB (KL[0] = epilogue bounce)
    __shared__ __hip_bfloat16 ewTd[2][32][40]; // 5.1 KB
    __shared__ float invd[HH][32];             // 1 KB
    const int tid = threadIdx.x;
    const int wv = tid >> 6, lane = tid & 63, quad = lane >> 4, m16 = lane & 15;
    const int jc = blockIdx.x;               // 4 chunks x 512 j
    const int it = blockIdx.y;               // 64 tiles x 32 i
    const int b  = blockIdx.z;
    const size_t gb = (size_t)b * SS;
    const size_t g0 = gb + it * 32;
    const int ih = wv & 1;                   // i-half for score phase
    const int jh = wv >> 1;                  // j-half for score phase

    {   // denominators -> 0.125/D (head-mean folded in); 256 thr = HH*32 exactly
        const int h = tid >> 5, i = tid & 31;
        float s = 0.f;
        #pragma unroll
        for (int c = 0; c < JC1; ++c)
            s += dnP[((size_t)(c * BB + b) * SS + it * 32 + i) * HH + h];
        invd[h][i] = 0.125f / s;
    }

    short8 aq[HH][2];
    #pragma unroll
    for (int h = 0; h < HH; ++h)
        #pragma unroll
        for (int ks = 0; ks < 2; ++ks)
            aq[h][ks] = *reinterpret_cast<const short8*>(
                qws + (g0 + ih * 16 + m16) * EE + h * 64 + ks * 32 + quad * 8);

    f32x4 acc[2][8];
    #pragma unroll
    for (int mf = 0; mf < 2; ++mf)
        #pragma unroll
        for (int nf = 0; nf < 8; ++nf) acc[mf][nf] = (f32x4){0.f, 0.f, 0.f, 0.f};

    // per-lane V row base: e = wv*128 + nf*16 + m16, k-offset quad*8
    const __hip_bfloat16* vrow0 = vTg + ((size_t)b * EE + wv * 128 + m16) * SS + quad * 8;

    {   // prologue: K subtile 0 -> KL[0] (8 DMAs per wave, 1 per row)
        #pragma unroll
        for (int rr = 0; rr < 8; ++rr) {
            const int row = wv * 8 + rr;
            const __hip_bfloat16* g = kws + (gb + jc * 512 + row) * EE + lane * 8;
            __builtin_amdgcn_global_load_lds(
                (gu32*)(const void*)g, (lu32*)(void*)&KL[0][row][0], 16, 0, 0);
        }
    }
    __syncthreads();                           // KL[0] + invd ready

    for (int st = 0; st < 16; ++st) {
        const int j0 = jc * 512 + st * 32;
        const int cur = st & 1;
        if (st + 1 < 16) {                     // issue-early: next K subtile DMAs
            #pragma unroll
            for (int rr = 0; rr < 8; ++rr) {
                const int row = wv * 8 + rr;
                const __hip_bfloat16* g = kws + (gb + j0 + 32 + row) * EE + lane * 8;
                __builtin_amdgcn_global_load_lds(
                    (gu32*)(const void*)g,
                    (lu32*)(void*)&KL[cur ^ 1][row][0], 16, 0, 0);
            }
        }

        // scores: wave's (ih, jh) quadrant of the 32x32 tile, all heads
        float wsum[4] = {0.f, 0.f, 0.f, 0.f};
        __builtin_amdgcn_s_setprio(1);
        #pragma unroll
        for (int h = 0; h < HH; ++h) {
            const short8 b0 = *reinterpret_cast<const short8*>(
                &KL[cur][jh * 16 + m16][h * 64 + quad * 8]);
            const short8 b1 = *reinterpret_cast<const short8*>(
                &KL[cur][jh * 16 + m16][h * 64 + 32 + quad * 8]);
            f32x4 c = {0.f, 0.f, 0.f, 0.f};
            c = __builtin_amdgcn_mfma_f32_16x16x32_bf16(aq[h][0], b0, c, 0, 0, 0);
            c = __builtin_amdgcn_mfma_f32_16x16x32_bf16(aq[h][1], b1, c, 0, 0, 0);
            #pragma unroll
            for (int r = 0; r < 4; ++r)
                wsum[r] += __expf(c[r] * 0.125f) * invd[h][ih * 16 + quad * 4 + r];
        }
        __builtin_amdgcn_s_setprio(0);
        #pragma unroll
        for (int r = 0; r < 4; ++r) {
            const __hip_bfloat16 wb = __float2bfloat16(wsum[r]);
            ewTd[cur][ih * 16 + quad * 4 + r][jh * 16 + m16] = wb;
            if ((float)wb > 0.1f) {            // rare: adjacency crossing
                const int li = ih * 16 + quad * 4 + r;
                const int idx = atomicAdd(&cntI[g0 + li], 1);
                if (idx < 16) {
                    slotJ[((size_t)g0 + li) * 16 + idx] = j0 + jh * 16 + m16;
                    slotW[((size_t)g0 + li) * 16 + idx] = (float)wb;
                }
            }
        }
        __syncthreads();   // publishes ewTd[cur] AND KL[cur^1] (vmcnt drain after score)

        // PV: V B-frags straight from global (L2-resident), consumed immediately
        {
            short8 vb[8];
            #pragma unroll
            for (int nf = 0; nf < 8; ++nf)
                vb[nf] = *reinterpret_cast<const short8*>(vrow0 + (size_t)(nf * 16) * SS + j0);
            const short8 a0 = *reinterpret_cast<const short8*>(&ewTd[cur][m16][quad * 8]);
            const short8 a1 = *reinterpret_cast<const short8*>(&ewTd[cur][16 + m16][quad * 8]);
            __builtin_amdgcn_s_setprio(1);
            #pragma unroll
            for (int nf = 0; nf < 8; ++nf) {
                acc[0][nf] = __builtin_amdgcn_mfma_f32_16x16x32_bf16(a0, vb[nf], acc[0][nf], 0, 0, 0);
                acc[1][nf] = __builtin_amdgcn_mfma_f32_16x16x32_bf16(a1, vb[nf], acc[1][nf], 0, 0, 0);
            }
            __builtin_amdgcn_s_setprio(0);
        }
    }

    // epilogue: bounce acc through KL[0] for coalesced bf16 writes
    // (KL[0] last read at score(14), all waves past sync(15); safe)
    #pragma unroll
    for (int mf = 0; mf < 2; ++mf)
        #pragma unroll
        for (int nf = 0; nf < 8; ++nf)
            #pragma unroll
            for (int r = 0; r < 4; ++r)
                KL[0][mf * 16 + quad * 4 + r][wv * 128 + nf * 16 + m16] =
                    __float2bfloat16(acc[mf][nf][r]);
    __syncthreads();
    const int orow = tid >> 3;
    const int oc = (tid & 7) * 64;
    const uint4* s = reinterpret_cast<const uint4*>(&KL[0][orow][oc]);
    uint4* d = reinterpret_cast<uint4*>(
        pvP + ((size_t)jc * NN + g0 + orow) * EE + oc);
    #pragma unroll
    for (int q = 0; q < 8; ++q) d[q] = s[q];
}

extern "C" void kernel_launch(void* const* d_in, const int* in_sizes, int n_in,
                              void* d_out, int out_size, void* d_ws, size_t ws_size,
                              hipStream_t stream)
{
    const float* x   = (const float*)d_in[0];
    const float* Wq  = (const float*)d_in[1];
    const float* bq  = (const float*)d_in[2];
    const float* Wk  = (const float*)d_in[3];
    const float* bk  = (const float*)d_in[4];
    const float* Wv  = (const float*)d_in[5];
    const float* bv  = (const float*)d_in[6];
    const float* Wm1 = (const float*)d_in[7];
    const float* bm1 = (const float*)d_in[8];
    const float* Wm2 = (const float*)d_in[9];
    const float* bm2 = (const float*)d_in[10];
    const float* Wo  = (const float*)d_in[11];
    const float* bo  = (const float*)d_in[12];

    char* ws = (char*)d_ws;
    const size_t MB = 1024 * 1024;
    __hip_bfloat16* qb = (__hip_bfloat16*)(ws + 0);        // q            4MB
    __hip_bfloat16* kb = (__hip_bfloat16*)(ws + 4*MB);     // k -> hm      4MB
    __hip_bfloat16* vT = (__hip_bfloat16*)(ws + 8*MB);     // V^T [b][e][j] 4MB
    __hip_bfloat16* pvP = (__hip_bfloat16*)(ws + 12*MB);   // PV partials [4][NN][EE] 16MB
    float* dnP = (float*)(ws + 28*MB);                     // denom partials 1MB
    int*   cntI = (int*)(ws + 29*MB);                      // neighbor cnt  16KB
    int*   slotJ = (int*)(ws + 29*MB + 64*1024);           // crossing j    256KB
    float* slotW = (float*)(ws + 29*MB + 384*1024);        // crossing w    256KB
    const bool EXT = (ws_size >= 38 * MB);
    __hip_bfloat16* xb   = (__hip_bfloat16*)(ws + 30*MB);          // 4MB
    __hip_bfloat16* wqb  = (__hip_bfloat16*)(ws + 34*MB);
    __hip_bfloat16* wkb  = (__hip_bfloat16*)(ws + 34*MB + 512*1024);
    __hip_bfloat16* wvb  = (__hip_bfloat16*)(ws + 35*MB);
    __hip_bfloat16* wm1b = (__hip_bfloat16*)(ws + 35*MB + 512*1024);
    __hip_bfloat16* wm2b = (__hip_bfloat16*)(ws + 36*MB + 256*1024);
    __hip_bfloat16* wob  = (__hip_bfloat16*)(ws + 36*MB + 768*1024);

    dim3 blk(256, 1, 1);
    dim3 gg(EE / 64, NN / 64, 1);

    if (EXT) {
        conv_bf16<<<dim3(2048, 7, 1), blk, 0, stream>>>(
            x, Wq, Wk, Wv, Wm1, Wm2, Wo, xb, wqb, wkb, wvb, wm1b, wm2b, wob);
        qkv_gemm<1><<<dim3(24, NN / 64, 1), blk, 0, stream>>>(
            xb, wqb, bq, wkb, bk, wvb, bv, qb, kb, vT);
    } else {
        qkv_gemm<0><<<dim3(24, NN / 64, 1), blk, 0, stream>>>(
            x, Wq, bq, Wk, bk, Wv, bv, qb, kb, vT);
    }
    attn_denoms<<<dim3(JC1, SS / 32, BB), blk, 0, stream>>>(qb, kb, dnP, cntI);
    attn_ewpv<<<dim3(JCP, SS / 32, BB), blk, 0, stream>>>(
        qb, kb, vT, dnP, cntI, slotJ, slotW, pvP);
    if (EXT) {
        gemm_bt<1,1,1,0><<<gg, blk, 0, stream>>>(xb, wm1b, bm1, kb, EE + HH,
            nullptr, nullptr, nullptr, nullptr, nullptr);
        gemm_bt<2,1,1,0><<<gg, blk, 0, stream>>>(kb, wm2b, bm2, qb, EE,
            pvP, cntI, slotJ, slotW, x);
        gemm_bt<0,1,1,1><<<gg, blk, 0, stream>>>(qb, wob, bo, d_out, EE,
            nullptr, nullptr, nullptr, nullptr, nullptr);
    } else {
        gemm_bt<1,0,0,0><<<gg, blk, 0, stream>>>(x, Wm1, bm1, kb, EE + HH,
            nullptr, nullptr, nullptr, nullptr, nullptr);
        gemm_bt<2,1,0,0><<<gg, blk, 0, stream>>>(kb, Wm2, bm2, qb, EE,
            pvP, cntI, slotJ, slotW, x);
        gemm_bt<0,1,0,1><<<gg, blk, 0, stream>>>(qb, Wo, bo, d_out, EE,
            nullptr, nullptr, nullptr, nullptr, nullptr);
    }
}

// Round 15
// 205.590 us; speedup vs baseline: 1.2699x; 1.0569x over previous
//
#include <hip/hip_runtime.h>
#include <hip/hip_bf16.h>
#include <math.h>

#define BB 2
#define SS 2048
#define EE 512
#define HH 8
#define NN (BB*SS)
#define SST (SS/32)   // 64 j-tiles of 32
#define JC1 8   // denoms j-chunks (256 j each)
#define JCP 4   // fused ew+pv j-chunks (512 j each)

typedef __attribute__((ext_vector_type(8))) short short8;
typedef __attribute__((ext_vector_type(4))) float f32x4;
typedef const __attribute__((address_space(1))) unsigned int gu32;
typedef __attribute__((address_space(3))) unsigned int lu32;

__device__ __forceinline__ float b2f(short v){
    return __uint_as_float(((unsigned)(unsigned short)v) << 16);
}
__device__ __forceinline__ unsigned f2bf(float f){
    unsigned u = __float_as_uint(f);
    u += 0x7fffu + ((u >> 16) & 1u);
    return u >> 16;
}
__device__ __forceinline__ void stage16_f32(const float* __restrict__ src,
                                            __hip_bfloat16* dst){
    const float4 f0 = *reinterpret_cast<const float4*>(src);
    const float4 f1 = *reinterpret_cast<const float4*>(src + 4);
    const float4 f2 = *reinterpret_cast<const float4*>(src + 8);
    const float4 f3 = *reinterpret_cast<const float4*>(src + 12);
    uint4 o0, o1;
    o0.x = f2bf(f0.x) | (f2bf(f0.y) << 16);
    o0.y = f2bf(f0.z) | (f2bf(f0.w) << 16);
    o0.z = f2bf(f1.x) | (f2bf(f1.y) << 16);
    o0.w = f2bf(f1.z) | (f2bf(f1.w) << 16);
    o1.x = f2bf(f2.x) | (f2bf(f2.y) << 16);
    o1.y = f2bf(f2.z) | (f2bf(f2.w) << 16);
    o1.z = f2bf(f3.x) | (f2bf(f3.y) << 16);
    o1.w = f2bf(f3.z) | (f2bf(f3.w) << 16);
    *reinterpret_cast<uint4*>(dst) = o0;
    *reinterpret_cast<uint4*>(dst + 8) = o1;
}
__device__ __forceinline__ void stage16_b16(const __hip_bfloat16* __restrict__ src,
                                            __hip_bfloat16* dst){
    const uint4* s = reinterpret_cast<const uint4*>(src);
    uint4* d = reinterpret_cast<uint4*>(dst);
    d[0] = s[0]; d[1] = s[1];
}
// pack 16 f32 (4x float4 in regs) -> 16 bf16 in LDS
__device__ __forceinline__ void pack16(const float4* f, __hip_bfloat16* dst){
    uint4 o0, o1;
    o0.x = f2bf(f[0].x) | (f2bf(f[0].y) << 16);
    o0.y = f2bf(f[0].z) | (f2bf(f[0].w) << 16);
    o0.z = f2bf(f[1].x) | (f2bf(f[1].y) << 16);
    o0.w = f2bf(f[1].z) | (f2bf(f[1].w) << 16);
    o1.x = f2bf(f[2].x) | (f2bf(f[2].y) << 16);
    o1.y = f2bf(f[2].z) | (f2bf(f[2].w) << 16);
    o1.z = f2bf(f[3].x) | (f2bf(f[3].y) << 16);
    o1.w = f2bf(f[3].z) | (f2bf(f[3].w) << 16);
    *reinterpret_cast<uint4*>(dst) = o0;
    *reinterpret_cast<uint4*>(dst + 8) = o1;
}

// ---------------- one-time f32 -> bf16 conversion of x + 6 weights ----------------
__global__ void conv_bf16(
    const float* s0, const float* s1, const float* s2, const float* s3,
    const float* s4, const float* s5, const float* s6,
    __hip_bfloat16* d0, __hip_bfloat16* d1, __hip_bfloat16* d2, __hip_bfloat16* d3,
    __hip_bfloat16* d4, __hip_bfloat16* d5, __hip_bfloat16* d6)
{
    const int which = blockIdx.y;
    const float* s; __hip_bfloat16* d; int n;
    switch (which) {
        case 0: s = s0; d = d0; n = 2097152; break;
        case 1: s = s1; d = d1; n = 262144; break;
        case 2: s = s2; d = d2; n = 262144; break;
        case 3: s = s3; d = d3; n = 262144; break;
        case 4: s = s4; d = d4; n = 266240; break;
        case 5: s = s5; d = d5; n = 262144; break;
        default: s = s6; d = d6; n = 262144; break;
    }
    const int base = (blockIdx.x * 256 + threadIdx.x) * 4;
    if (base >= n) return;
    const float4 f = *reinterpret_cast<const float4*>(s + base);
    uint2 o;
    o.x = f2bf(f.x) | (f2bf(f.y) << 16);
    o.y = f2bf(f.z) | (f2bf(f.w) << 16);
    *reinterpret_cast<uint2*>(d + base) = o;
}

// ---------------- fused QKV projection (MFMA) ----------------
// which==2 now stores V in j-tiled layout: vT2[b][j>>5][e][j&31]
// (32-j x 512-e subtiles contiguous -> ewpv V loads fully coalesced).
template<int B16>
__global__ __launch_bounds__(256) void qkv_gemm(
    const void* __restrict__ x,
    const void* __restrict__ Wq, const float* __restrict__ bq,
    const void* __restrict__ Wk, const float* __restrict__ bk,
    const void* __restrict__ Wv, const float* __restrict__ bv,
    __hip_bfloat16* __restrict__ qb,
    __hip_bfloat16* __restrict__ kb,
    __hip_bfloat16* __restrict__ vT)
{
    __shared__ __hip_bfloat16 As[64][72];
    __shared__ __hip_bfloat16 Bs[64][72];
    const int tid = threadIdx.x;
    const int which = blockIdx.x >> 3;
    const int col0 = (blockIdx.x & 7) * 64;
    const int row0 = blockIdx.y * 64;
    const int wv = tid >> 6, lane = tid & 63, quad = lane >> 4, m16 = lane & 15;
    const int sr = tid >> 2;
    const int sc = (tid & 3) * 16;
    const void* W    = (which == 0) ? Wq : (which == 1) ? Wk : Wv;
    const float* bias = (which == 0) ? bq : (which == 1) ? bk : bv;

    f32x4 acc[4];
    #pragma unroll
    for (int nt = 0; nt < 4; ++nt) acc[nt] = (f32x4){0.f, 0.f, 0.f, 0.f};

    for (int k0 = 0; k0 < 512; k0 += 64) {
        if (B16) {
            stage16_b16((const __hip_bfloat16*)x + (size_t)(row0 + sr) * EE + k0 + sc, &As[sr][sc]);
            stage16_b16((const __hip_bfloat16*)W + (size_t)(col0 + sr) * EE + k0 + sc, &Bs[sr][sc]);
        } else {
            stage16_f32((const float*)x + (size_t)(row0 + sr) * EE + k0 + sc, &As[sr][sc]);
            stage16_f32((const float*)W + (size_t)(col0 + sr) * EE + k0 + sc, &Bs[sr][sc]);
        }
        __syncthreads();
        #pragma unroll
        for (int ks = 0; ks < 2; ++ks) {
            const short8 a = *reinterpret_cast<const short8*>(
                &As[wv * 16 + m16][ks * 32 + quad * 8]);
            #pragma unroll
            for (int nt = 0; nt < 4; ++nt) {
                const short8 b = *reinterpret_cast<const short8*>(
                    &Bs[nt * 16 + m16][ks * 32 + quad * 8]);
                acc[nt] = __builtin_amdgcn_mfma_f32_16x16x32_bf16(a, b, acc[nt], 0, 0, 0);
            }
        }
        __syncthreads();
    }

    if (which == 2) {
        #pragma unroll
        for (int nt = 0; nt < 4; ++nt) {
            const float bb = bias[col0 + nt * 16 + m16];
            #pragma unroll
            for (int r = 0; r < 4; ++r)
                Bs[wv * 16 + quad * 4 + r][nt * 16 + m16] =
                    __float2bfloat16(acc[nt][r] + bb);
        }
        __syncthreads();
        const int bb2 = row0 >> 11;
        const int j0 = row0 & (SS - 1);
        const int er = tid >> 2;
        const int js = (tid & 3) * 16;
        unsigned pk[8];
        #pragma unroll
        for (int p = 0; p < 8; ++p) {
            const unsigned lo = *reinterpret_cast<const unsigned short*>(&Bs[js + 2*p][er]);
            const unsigned hi = *reinterpret_cast<const unsigned short*>(&Bs[js + 2*p + 1][er]);
            pk[p] = lo | (hi << 16);
        }
        uint4 s0; s0.x = pk[0]; s0.y = pk[1]; s0.z = pk[2]; s0.w = pk[3];
        uint4 s1; s1.x = pk[4]; s1.y = pk[5]; s1.z = pk[6]; s1.w = pk[7];
        // j-tiled store: tile jt = (j0+js)>>5 (js%32 in {0,16} -> 16-run stays in-tile)
        __hip_bfloat16* dst = vT +
            (((size_t)(bb2 * SST + ((j0 + js) >> 5)) * EE + col0 + er) * 32 + (js & 31));
        *reinterpret_cast<uint4*>(dst) = s0;
        *reinterpret_cast<uint4*>(dst + 8) = s1;
    } else {
        __hip_bfloat16* C = (which == 0) ? qb : kb;
        #pragma unroll
        for (int nt = 0; nt < 4; ++nt) {
            const int gn = col0 + nt * 16 + m16;
            const float bb = bias[gn];
            #pragma unroll
            for (int r = 0; r < 4; ++r) {
                const int gm = row0 + wv * 16 + quad * 4 + r;
                C[(size_t)gm * EE + gn] = __float2bfloat16(acc[nt][r] + bb);
            }
        }
    }
}

// ---------------- MFMA GEMM (MLP1 / MLP2+combine / out-proj) — R12-verbatim ----------------
template<int MODE, int AB16, int WB16, int CF32>
__global__ __launch_bounds__(256) void gemm_bt(
    const void* __restrict__ Av,
    const void* __restrict__ Wv_,
    const float* __restrict__ bias,
    void* __restrict__ Cv,
    int ldb,
    const __hip_bfloat16* __restrict__ pvPp,
    const int* __restrict__ cntIp,
    const int* __restrict__ slotJp,
    const float* __restrict__ slotWp,
    const float* __restrict__ xf)
{
    __shared__ __hip_bfloat16 As[2][64][72];
    __shared__ __hip_bfloat16 Bs[2][64][72];
    const int tid = threadIdx.x;
    const int col0 = blockIdx.x * 64;
    const int row0 = blockIdx.y * 64;
    const int wv = tid >> 6, lane = tid & 63, quad = lane >> 4, m16 = lane & 15;
    const int sr = tid >> 2;
    const int sc = (tid & 3) * 16;

    f32x4 acc[4];
    #pragma unroll
    for (int nt = 0; nt < 4; ++nt) acc[nt] = (f32x4){0.f, 0.f, 0.f, 0.f};

    {   // prologue: tile 0 -> buffer 0
        if (AB16)
            stage16_b16((const __hip_bfloat16*)Av + (size_t)(row0 + sr) * EE + sc, &As[0][sr][sc]);
        else
            stage16_f32((const float*)Av + (size_t)(row0 + sr) * EE + sc, &As[0][sr][sc]);
        if (WB16)
            stage16_b16((const __hip_bfloat16*)Wv_ + (size_t)(col0 + sr) * ldb + sc, &Bs[0][sr][sc]);
        else
            stage16_f32((const float*)Wv_ + (size_t)(col0 + sr) * ldb + sc, &Bs[0][sr][sc]);
    }

    for (int kt = 0; kt < 8; ++kt) {
        __syncthreads();                       // buffer kt&1 ready
        uint4 ra[2], rb[2];
        float4 fa[4], fb[4];
        if (kt + 1 < 8) {                      // issue-early: next tile -> regs
            const int k0 = (kt + 1) * 64;
            if (AB16) {
                const uint4* s = reinterpret_cast<const uint4*>(
                    (const __hip_bfloat16*)Av + (size_t)(row0 + sr) * EE + k0 + sc);
                ra[0] = s[0]; ra[1] = s[1];
            } else {
                const float4* s = reinterpret_cast<const float4*>(
                    (const float*)Av + (size_t)(row0 + sr) * EE + k0 + sc);
                fa[0] = s[0]; fa[1] = s[1]; fa[2] = s[2]; fa[3] = s[3];
            }
            if (WB16) {
                const uint4* s = reinterpret_cast<const uint4*>(
                    (const __hip_bfloat16*)Wv_ + (size_t)(col0 + sr) * ldb + k0 + sc);
                rb[0] = s[0]; rb[1] = s[1];
            } else {
                const float4* s = reinterpret_cast<const float4*>(
                    (const float*)Wv_ + (size_t)(col0 + sr) * ldb + k0 + sc);
                fb[0] = s[0]; fb[1] = s[1]; fb[2] = s[2]; fb[3] = s[3];
            }
        }
        const int cur = kt & 1;
        #pragma unroll
        for (int ks = 0; ks < 2; ++ks) {
            const short8 a = *reinterpret_cast<const short8*>(
                &As[cur][wv * 16 + m16][ks * 32 + quad * 8]);
            #pragma unroll
            for (int nt = 0; nt < 4; ++nt) {
                const short8 b = *reinterpret_cast<const short8*>(
                    &Bs[cur][nt * 16 + m16][ks * 32 + quad * 8]);
                acc[nt] = __builtin_amdgcn_mfma_f32_16x16x32_bf16(a, b, acc[nt], 0, 0, 0);
            }
        }
        if (kt + 1 < 8) {                      // write-late into the spare buffer
            const int nb = (kt + 1) & 1;
            if (AB16) {
                uint4* d = reinterpret_cast<uint4*>(&As[nb][sr][sc]);
                d[0] = ra[0]; d[1] = ra[1];
            } else pack16(fa, &As[nb][sr][sc]);
            if (WB16) {
                uint4* d = reinterpret_cast<uint4*>(&Bs[nb][sr][sc]);
                d[0] = rb[0]; d[1] = rb[1];
            } else pack16(fb, &Bs[nb][sr][sc]);
        }
    }

    if (MODE == 2) {                           // MLP2 + fused pv-combine
        #pragma unroll
        for (int r = 0; r < 4; ++r) {
            const int gm = row0 + wv * 16 + quad * 4 + r;
            const int cn = cntIp[gm];
            const int bloc = gm >> 11;
            #pragma unroll
            for (int nt = 0; nt < 4; ++nt) {
                const int gn = col0 + nt * 16 + m16;
                const size_t ci = (size_t)gm * EE + gn;
                float c = acc[nt][r] + bias[gn];
                #pragma unroll
                for (int cc = 0; cc < JCP; ++cc)
                    c += b2f(reinterpret_cast<const short*>(pvPp)
                             [(size_t)cc * NN * EE + ci]);
                if (cn > 0) {                  // exact rare path: masked mean
                    const float inv = 1.f / (float)cn;
                    const int ns = cn < 16 ? cn : 16;
                    for (int t = 0; t < ns; ++t) {
                        const int j = slotJp[(size_t)gm * 16 + t];
                        c += slotWp[(size_t)gm * 16 + t] * inv *
                             xf[((size_t)bloc * SS + j) * EE + gn];
                    }
                }
                ((__hip_bfloat16*)Cv)[ci] = __float2bfloat16(c);
            }
        }
        return;
    }

    #pragma unroll
    for (int nt = 0; nt < 4; ++nt) {
        const int gn = col0 + nt * 16 + m16;
        float bb = bias[gn];
        if (MODE == 1) {
            float ts = 0.f;
            #pragma unroll
            for (int h = 0; h < 8; ++h) {
                const size_t wi = (size_t)gn * ldb + 512 + h;
                ts += WB16 ? (float)((const __hip_bfloat16*)Wv_)[wi]
                           : ((const float*)Wv_)[wi];
            }
            bb += ts * (1.0f / (float)SS);
        }
        #pragma unroll
        for (int r = 0; r < 4; ++r) {
            const int gm = row0 + wv * 16 + quad * 4 + r;
            const size_t ci = (size_t)gm * EE + gn;
            float c = acc[nt][r] + bb;
            if (MODE == 1) c = 0.5f * c * (1.0f + erff(c * 0.70710678118654752f));
            if (CF32) ((float*)Cv)[ci] = c;
            else      ((__hip_bfloat16*)Cv)[ci] = __float2bfloat16(c);
        }
    }
}

// ---------------- K1: partial softmax denominators (R13-verbatim) ----------------
__global__ __launch_bounds__(256) void attn_denoms(
    const __hip_bfloat16* __restrict__ qws,
    const __hip_bfloat16* __restrict__ kws,
    float* __restrict__ dnP,
    int* __restrict__ cntI)
{
    __shared__ __hip_bfloat16 KL[2][16][520];   // 33.3 KB
    const int tid = threadIdx.x;
    const int wv = tid >> 6, lane = tid & 63, quad = lane >> 4, m16 = lane & 15;
    const int jc = blockIdx.x;              // 8 chunks x 256 j
    const int it = blockIdx.y;              // 64 tiles x 32 i
    const int b  = blockIdx.z;
    const size_t g0 = (size_t)b * SS + it * 32;
    const size_t gb = (size_t)b * SS;
    const int ih = wv & 1, hh = wv >> 1;

    if (jc == 0 && tid < 32) cntI[g0 + tid] = 0;

    short8 aq[4][2];
    #pragma unroll
    for (int hp = 0; hp < 4; ++hp)
        #pragma unroll
        for (int ks = 0; ks < 2; ++ks)
            aq[hp][ks] = *reinterpret_cast<const short8*>(
                qws + (g0 + ih * 16 + m16) * EE + (hh * 4 + hp) * 64 + ks * 32 + quad * 8);

    float dph[4][4];
    #pragma unroll
    for (int hp = 0; hp < 4; ++hp)
        #pragma unroll
        for (int r = 0; r < 4; ++r) dph[hp][r] = 0.f;

    {   // prologue: tile 0 -> KL[0]; each wave stages 4 rows (1 DMA per row)
        #pragma unroll
        for (int rr = 0; rr < 4; ++rr) {
            const int row = wv * 4 + rr;
            const __hip_bfloat16* g = kws + (gb + jc * 256 + row) * EE + lane * 8;
            __builtin_amdgcn_global_load_lds(
                (gu32*)(const void*)g, (lu32*)(void*)&KL[0][row][0], 16, 0, 0);
        }
    }

    for (int jt = 0; jt < 16; ++jt) {
        __syncthreads();                       // vmcnt drained: KL[jt&1] ready
        if (jt + 1 < 16) {                     // issue next tile into spare buffer
            #pragma unroll
            for (int rr = 0; rr < 4; ++rr) {
                const int row = wv * 4 + rr;
                const __hip_bfloat16* g =
                    kws + (gb + jc * 256 + (jt + 1) * 16 + row) * EE + lane * 8;
                __builtin_amdgcn_global_load_lds(
                    (gu32*)(const void*)g,
                    (lu32*)(void*)&KL[(jt + 1) & 1][row][0], 16, 0, 0);
            }
        }
        __builtin_amdgcn_s_setprio(1);
        #pragma unroll
        for (int hp = 0; hp < 4; ++hp) {
            const short8 b0 = *reinterpret_cast<const short8*>(
                &KL[jt & 1][m16][(hh * 4 + hp) * 64 + quad * 8]);
            const short8 b1 = *reinterpret_cast<const short8*>(
                &KL[jt & 1][m16][(hh * 4 + hp) * 64 + 32 + quad * 8]);
            f32x4 c = {0.f, 0.f, 0.f, 0.f};
            c = __builtin_amdgcn_mfma_f32_16x16x32_bf16(aq[hp][0], b0, c, 0, 0, 0);
            c = __builtin_amdgcn_mfma_f32_16x16x32_bf16(aq[hp][1], b1, c, 0, 0, 0);
            #pragma unroll
            for (int r = 0; r < 4; ++r) dph[hp][r] += __expf(c[r] * 0.125f);
        }
        __builtin_amdgcn_s_setprio(0);
    }

    #pragma unroll
    for (int hp = 0; hp < 4; ++hp)
        #pragma unroll
        for (int off = 1; off <= 8; off <<= 1)
            #pragma unroll
            for (int r = 0; r < 4; ++r) dph[hp][r] += __shfl_xor(dph[hp][r], off, 64);
    if (m16 == 0) {
        const size_t i = (size_t)it * 32 + ih * 16 + quad * 4;
        #pragma unroll
        for (int hp = 0; hp < 4; ++hp)
            #pragma unroll
            for (int r = 0; r < 4; ++r)
                dnP[((size_t)(jc * BB + b) * SS + i + r) * HH + hh * 4 + hp] = dph[hp][r];
    }
}

// ---------------- K2: fused ew + PV (R14 pipeline + j-tiled coalesced V) ----------------
// R14's double-buffered gload_lds pipeline unchanged. ONLY the V access
// changed: vT is now [b][j/32][e][j%32], so each vb[nf] load is a wave-
// contiguous 2 KB read (was 16 rows x 64 B at 4 KB stride = 16 scattered
// transactions per load). Numerics bit-identical (pure layout permutation).
__global__ __launch_bounds__(256, 2) void attn_ewpv(
    const __hip_bfloat16* __restrict__ qws,
    const __hip_bfloat16* __restrict__ kws,
    const __hip_bfloat16* __restrict__ vTg,
    const float* __restrict__ dnP,
    int* __restrict__ cntI,
    int* __restrict__ slotJ,
    float* __restrict__ slotW,
    __hip_bfloat16* __restrict__ pvP)
{
    __shared__ __hip_bfloat16 KL[2][32][520];  // 66.6 KB (KL[0] = epilogue bounce)
    __shared__ __hip_bfloat16 ewTd[2][32][40]; // 5.1 KB
    __shared__ float invd[HH][32];             // 1 KB
    const int tid = threadIdx.x;
    const int wv = tid >> 6, lane = tid & 63, quad = lane >> 4, m16 = lane & 15;
    const int jc = blockIdx.x;               // 4 chunks x 512 j
    const int it = blockIdx.y;               // 64 tiles x 32 i
    const int b  = blockIdx.z;
    const size_t gb = (size_t)b * SS;
    const size_t g0 = gb + it * 32;
    const int ih = wv & 1;                   // i-half for score phase
    const int jh = wv >> 1;                  // j-half for score phase

    {   // denominators -> 0.125/D (head-mean folded in); 256 thr = HH*32 exactly
        const int h = tid >> 5, i = tid & 31;
        float s = 0.f;
        #pragma unroll
        for (int c = 0; c < JC1; ++c)
            s += dnP[((size_t)(c * BB + b) * SS + it * 32 + i) * HH + h];
        invd[h][i] = 0.125f / s;
    }

    short8 aq[HH][2];
    #pragma unroll
    for (int h = 0; h < HH; ++h)
        #pragma unroll
        for (int ks = 0; ks < 2; ++ks)
            aq[h][ks] = *reinterpret_cast<const short8*>(
                qws + (g0 + ih * 16 + m16) * EE + h * 64 + ks * 32 + quad * 8);

    f32x4 acc[2][8];
    #pragma unroll
    for (int mf = 0; mf < 2; ++mf)
        #pragma unroll
        for (int nf = 0; nf < 8; ++nf) acc[mf][nf] = (f32x4){0.f, 0.f, 0.f, 0.f};

    // j-tiled V: lane base for subtile jt = jc*16+st:
    //   vTg + ((b*SST + jt)*EE + wv*128 + m16)*32 + quad*8; vb[nf] at +nf*512
    const __hip_bfloat16* vtile0 =
        vTg + (((size_t)b * SST + jc * 16) * EE + wv * 128 + m16) * 32 + quad * 8;

    {   // prologue: K subtile 0 -> KL[0] (8 DMAs per wave, 1 per row)
        #pragma unroll
        for (int rr = 0; rr < 8; ++rr) {
            const int row = wv * 8 + rr;
            const __hip_bfloat16* g = kws + (gb + jc * 512 + row) * EE + lane * 8;
            __builtin_amdgcn_global_load_lds(
                (gu32*)(const void*)g, (lu32*)(void*)&KL[0][row][0], 16, 0, 0);
        }
    }
    __syncthreads();                           // KL[0] + invd ready

    for (int st = 0; st < 16; ++st) {
        const int j0 = jc * 512 + st * 32;
        const int cur = st & 1;
        if (st + 1 < 16) {                     // issue-early: next K subtile DMAs
            #pragma unroll
            for (int rr = 0; rr < 8; ++rr) {
                const int row = wv * 8 + rr;
                const __hip_bfloat16* g = kws + (gb + j0 + 32 + row) * EE + lane * 8;
                __builtin_amdgcn_global_load_lds(
                    (gu32*)(const void*)g,
                    (lu32*)(void*)&KL[cur ^ 1][row][0], 16, 0, 0);
            }
        }

        // scores: wave's (ih, jh) quadrant of the 32x32 tile, all heads
        float wsum[4] = {0.f, 0.f, 0.f, 0.f};
        __builtin_amdgcn_s_setprio(1);
        #pragma unroll
        for (int h = 0; h < HH; ++h) {
            const short8 b0 = *reinterpret_cast<const short8*>(
                &KL[cur][jh * 16 + m16][h * 64 + quad * 8]);
            const short8 b1 = *reinterpret_cast<const short8*>(
                &KL[cur][jh * 16 + m16][h * 64 + 32 + quad * 8]);
            f32x4 c = {0.f, 0.f, 0.f, 0.f};
            c = __builtin_amdgcn_mfma_f32_16x16x32_bf16(aq[h][0], b0, c, 0, 0, 0);
            c = __builtin_amdgcn_mfma_f32_16x16x32_bf16(aq[h][1], b1, c, 0, 0, 0);
            #pragma unroll
            for (int r = 0; r < 4; ++r)
                wsum[r] += __expf(c[r] * 0.125f) * invd[h][ih * 16 + quad * 4 + r];
        }
        __builtin_amdgcn_s_setprio(0);
        #pragma unroll
        for (int r = 0; r < 4; ++r) {
            const __hip_bfloat16 wb = __float2bfloat16(wsum[r]);
            ewTd[cur][ih * 16 + quad * 4 + r][jh * 16 + m16] = wb;
            if ((float)wb > 0.1f) {            // rare: adjacency crossing
                const int li = ih * 16 + quad * 4 + r;
                const int idx = atomicAdd(&cntI[g0 + li], 1);
                if (idx < 16) {
                    slotJ[((size_t)g0 + li) * 16 + idx] = j0 + jh * 16 + m16;
                    slotW[((size_t)g0 + li) * 16 + idx] = (float)wb;
                }
            }
        }
        __syncthreads();   // publishes ewTd[cur] AND KL[cur^1] (vmcnt drain after score)

        // PV: V B-frags from j-tiled vT (fully coalesced), consumed immediately
        {
            const __hip_bfloat16* vt = vtile0 + (size_t)st * EE * 32;
            short8 vb[8];
            #pragma unroll
            for (int nf = 0; nf < 8; ++nf)
                vb[nf] = *reinterpret_cast<const short8*>(vt + nf * 512);
            const short8 a0 = *reinterpret_cast<const short8*>(&ewTd[cur][m16][quad * 8]);
            const short8 a1 = *reinterpret_cast<const short8*>(&ewTd[cur][16 + m16][quad * 8]);
            __builtin_amdgcn_s_setprio(1);
            #pragma unroll
            for (int nf = 0; nf < 8; ++nf) {
                acc[0][nf] = __builtin_amdgcn_mfma_f32_16x16x32_bf16(a0, vb[nf], acc[0][nf], 0, 0, 0);
                acc[1][nf] = __builtin_amdgcn_mfma_f32_16x16x32_bf16(a1, vb[nf], acc[1][nf], 0, 0, 0);
            }
            __builtin_amdgcn_s_setprio(0);
        }
    }

    // epilogue: bounce acc through KL[0] for coalesced bf16 writes
    #pragma unroll
    for (int mf = 0; mf < 2; ++mf)
        #pragma unroll
        for (int nf = 0; nf < 8; ++nf)
            #pragma unroll
            for (int r = 0; r < 4; ++r)
                KL[0][mf * 16 + quad * 4 + r][wv * 128 + nf * 16 + m16] =
                    __float2bfloat16(acc[mf][nf][r]);
    __syncthreads();
    const int orow = tid >> 3;
    const int oc = (tid & 7) * 64;
    const uint4* s = reinterpret_cast<const uint4*>(&KL[0][orow][oc]);
    uint4* d = reinterpret_cast<uint4*>(
        pvP + ((size_t)jc * NN + g0 + orow) * EE + oc);
    #pragma unroll
    for (int q = 0; q < 8; ++q) d[q] = s[q];
}

extern "C" void kernel_launch(void* const* d_in, const int* in_sizes, int n_in,
                              void* d_out, int out_size, void* d_ws, size_t ws_size,
                              hipStream_t stream)
{
    const float* x   = (const float*)d_in[0];
    const float* Wq  = (const float*)d_in[1];
    const float* bq  = (const float*)d_in[2];
    const float* Wk  = (const float*)d_in[3];
    const float* bk  = (const float*)d_in[4];
    const float* Wv  = (const float*)d_in[5];
    const float* bv  = (const float*)d_in[6];
    const float* Wm1 = (const float*)d_in[7];
    const float* bm1 = (const float*)d_in[8];
    const float* Wm2 = (const float*)d_in[9];
    const float* bm2 = (const float*)d_in[10];
    const float* Wo  = (const float*)d_in[11];
    const float* bo  = (const float*)d_in[12];

    char* ws = (char*)d_ws;
    const size_t MB = 1024 * 1024;
    __hip_bfloat16* qb = (__hip_bfloat16*)(ws + 0);        // q            4MB
    __hip_bfloat16* kb = (__hip_bfloat16*)(ws + 4*MB);     // k -> hm      4MB
    __hip_bfloat16* vT = (__hip_bfloat16*)(ws + 8*MB);     // V j-tiled [b][j/32][e][j%32] 4MB
    __hip_bfloat16* pvP = (__hip_bfloat16*)(ws + 12*MB);   // PV partials [4][NN][EE] 16MB
    float* dnP = (float*)(ws + 28*MB);                     // denom partials 1MB
    int*   cntI = (int*)(ws + 29*MB);                      // neighbor cnt  16KB
    int*   slotJ = (int*)(ws + 29*MB + 64*1024);           // crossing j    256KB
    float* slotW = (float*)(ws + 29*MB + 384*1024);        // crossing w    256KB
    const bool EXT = (ws_size >= 38 * MB);
    __hip_bfloat16* xb   = (__hip_bfloat16*)(ws + 30*MB);          // 4MB
    __hip_bfloat16* wqb  = (__hip_bfloat16*)(ws + 34*MB);
    __hip_bfloat16* wkb  = (__hip_bfloat16*)(ws + 34*MB + 512*1024);
    __hip_bfloat16* wvb  = (__hip_bfloat16*)(ws + 35*MB);
    __hip_bfloat16* wm1b = (__hip_bfloat16*)(ws + 35*MB + 512*1024);
    __hip_bfloat16* wm2b = (__hip_bfloat16*)(ws + 36*MB + 256*1024);
    __hip_bfloat16* wob  = (__hip_bfloat16*)(ws + 36*MB + 768*1024);

    dim3 blk(256, 1, 1);
    dim3 gg(EE / 64, NN / 64, 1);

    if (EXT) {
        conv_bf16<<<dim3(2048, 7, 1), blk, 0, stream>>>(
            x, Wq, Wk, Wv, Wm1, Wm2, Wo, xb, wqb, wkb, wvb, wm1b, wm2b, wob);
        qkv_gemm<1><<<dim3(24, NN / 64, 1), blk, 0, stream>>>(
            xb, wqb, bq, wkb, bk, wvb, bv, qb, kb, vT);
    } else {
        qkv_gemm<0><<<dim3(24, NN / 64, 1), blk, 0, stream>>>(
            x, Wq, bq, Wk, bk, Wv, bv, qb, kb, vT);
    }
    attn_denoms<<<dim3(JC1, SS / 32, BB), blk, 0, stream>>>(qb, kb, dnP, cntI);
    attn_ewpv<<<dim3(JCP, SS / 32, BB), blk, 0, stream>>>(
        qb, kb, vT, dnP, cntI, slotJ, slotW, pvP);
    if (EXT) {
        gemm_bt<1,1,1,0><<<gg, blk, 0, stream>>>(xb, wm1b, bm1, kb, EE + HH,
            nullptr, nullptr, nullptr, nullptr, nullptr);
        gemm_bt<2,1,1,0><<<gg, blk, 0, stream>>>(kb, wm2b, bm2, qb, EE,
            pvP, cntI, slotJ, slotW, x);
        gemm_bt<0,1,1,1><<<gg, blk, 0, stream>>>(qb, wob, bo, d_out, EE,
            nullptr, nullptr, nullptr, nullptr, nullptr);
    } else {
        gemm_bt<1,0,0,0><<<gg, blk, 0, stream>>>(x, Wm1, bm1, kb, EE + HH,
            nullptr, nullptr, nullptr, nullptr, nullptr);
        gemm_bt<2,1,0,0><<<gg, blk, 0, stream>>>(kb, Wm2, bm2, qb, EE,
            pvP, cntI, slotJ, slotW, x);
        gemm_bt<0,1,0,1><<<gg, blk, 0, stream>>>(qb, Wo, bo, d_out, EE,
            nullptr, nullptr, nullptr, nullptr, nullptr);
    }
}

// Round 16
// 203.043 us; speedup vs baseline: 1.2858x; 1.0125x over previous
//
#include <hip/hip_runtime.h>
#include <hip/hip_bf16.h>
#include <math.h>

#define BB 2
#define SS 2048
#define EE 512
#define HH 8
#define NN (BB*SS)
#define SST (SS/32)   // 64 j-tiles of 32
#define JC1 8   // denoms j-chunks (256 j each)
#define JCP 4   // fused ew+pv j-chunks (512 j each)

typedef __attribute__((ext_vector_type(8))) short short8;
typedef __attribute__((ext_vector_type(4))) float f32x4;
typedef const __attribute__((address_space(1))) unsigned int gu32;
typedef __attribute__((address_space(3))) unsigned int lu32;

__device__ __forceinline__ float b2f(short v){
    return __uint_as_float(((unsigned)(unsigned short)v) << 16);
}
__device__ __forceinline__ unsigned f2bf(float f){
    unsigned u = __float_as_uint(f);
    u += 0x7fffu + ((u >> 16) & 1u);
    return u >> 16;
}
__device__ __forceinline__ void stage16_f32(const float* __restrict__ src,
                                            __hip_bfloat16* dst){
    const float4 f0 = *reinterpret_cast<const float4*>(src);
    const float4 f1 = *reinterpret_cast<const float4*>(src + 4);
    const float4 f2 = *reinterpret_cast<const float4*>(src + 8);
    const float4 f3 = *reinterpret_cast<const float4*>(src + 12);
    uint4 o0, o1;
    o0.x = f2bf(f0.x) | (f2bf(f0.y) << 16);
    o0.y = f2bf(f0.z) | (f2bf(f0.w) << 16);
    o0.z = f2bf(f1.x) | (f2bf(f1.y) << 16);
    o0.w = f2bf(f1.z) | (f2bf(f1.w) << 16);
    o1.x = f2bf(f2.x) | (f2bf(f2.y) << 16);
    o1.y = f2bf(f2.z) | (f2bf(f2.w) << 16);
    o1.z = f2bf(f3.x) | (f2bf(f3.y) << 16);
    o1.w = f2bf(f3.z) | (f2bf(f3.w) << 16);
    *reinterpret_cast<uint4*>(dst) = o0;
    *reinterpret_cast<uint4*>(dst + 8) = o1;
}
__device__ __forceinline__ void stage16_b16(const __hip_bfloat16* __restrict__ src,
                                            __hip_bfloat16* dst){
    const uint4* s = reinterpret_cast<const uint4*>(src);
    uint4* d = reinterpret_cast<uint4*>(dst);
    d[0] = s[0]; d[1] = s[1];
}
// pack 16 f32 (4x float4 in regs) -> 16 bf16 in LDS
__device__ __forceinline__ void pack16(const float4* f, __hip_bfloat16* dst){
    uint4 o0, o1;
    o0.x = f2bf(f[0].x) | (f2bf(f[0].y) << 16);
    o0.y = f2bf(f[0].z) | (f2bf(f[0].w) << 16);
    o0.z = f2bf(f[1].x) | (f2bf(f[1].y) << 16);
    o0.w = f2bf(f[1].z) | (f2bf(f[1].w) << 16);
    o1.x = f2bf(f[2].x) | (f2bf(f[2].y) << 16);
    o1.y = f2bf(f[2].z) | (f2bf(f[2].w) << 16);
    o1.z = f2bf(f[3].x) | (f2bf(f[3].y) << 16);
    o1.w = f2bf(f[3].z) | (f2bf(f[3].w) << 16);
    *reinterpret_cast<uint4*>(dst) = o0;
    *reinterpret_cast<uint4*>(dst + 8) = o1;
}

// ---------------- one-time f32 -> bf16 conversion of x + 6 weights ----------------
__global__ void conv_bf16(
    const float* s0, const float* s1, const float* s2, const float* s3,
    const float* s4, const float* s5, const float* s6,
    __hip_bfloat16* d0, __hip_bfloat16* d1, __hip_bfloat16* d2, __hip_bfloat16* d3,
    __hip_bfloat16* d4, __hip_bfloat16* d5, __hip_bfloat16* d6)
{
    const int which = blockIdx.y;
    const float* s; __hip_bfloat16* d; int n;
    switch (which) {
        case 0: s = s0; d = d0; n = 2097152; break;
        case 1: s = s1; d = d1; n = 262144; break;
        case 2: s = s2; d = d2; n = 262144; break;
        case 3: s = s3; d = d3; n = 262144; break;
        case 4: s = s4; d = d4; n = 266240; break;
        case 5: s = s5; d = d5; n = 262144; break;
        default: s = s6; d = d6; n = 262144; break;
    }
    const int base = (blockIdx.x * 256 + threadIdx.x) * 4;
    if (base >= n) return;
    const float4 f = *reinterpret_cast<const float4*>(s + base);
    uint2 o;
    o.x = f2bf(f.x) | (f2bf(f.y) << 16);
    o.y = f2bf(f.z) | (f2bf(f.w) << 16);
    *reinterpret_cast<uint2*>(d + base) = o;
}

// ---------------- fused QKV projection (MFMA) ----------------
// which==2 stores V in j-tiled layout: vT2[b][j>>5][e][j&31]
// (32-j x 512-e subtiles contiguous -> ewpv V loads fully coalesced).
template<int B16>
__global__ __launch_bounds__(256) void qkv_gemm(
    const void* __restrict__ x,
    const void* __restrict__ Wq, const float* __restrict__ bq,
    const void* __restrict__ Wk, const float* __restrict__ bk,
    const void* __restrict__ Wv, const float* __restrict__ bv,
    __hip_bfloat16* __restrict__ qb,
    __hip_bfloat16* __restrict__ kb,
    __hip_bfloat16* __restrict__ vT)
{
    __shared__ __hip_bfloat16 As[64][72];
    __shared__ __hip_bfloat16 Bs[64][72];
    const int tid = threadIdx.x;
    const int which = blockIdx.x >> 3;
    const int col0 = (blockIdx.x & 7) * 64;
    const int row0 = blockIdx.y * 64;
    const int wv = tid >> 6, lane = tid & 63, quad = lane >> 4, m16 = lane & 15;
    const int sr = tid >> 2;
    const int sc = (tid & 3) * 16;
    const void* W    = (which == 0) ? Wq : (which == 1) ? Wk : Wv;
    const float* bias = (which == 0) ? bq : (which == 1) ? bk : bv;

    f32x4 acc[4];
    #pragma unroll
    for (int nt = 0; nt < 4; ++nt) acc[nt] = (f32x4){0.f, 0.f, 0.f, 0.f};

    for (int k0 = 0; k0 < 512; k0 += 64) {
        if (B16) {
            stage16_b16((const __hip_bfloat16*)x + (size_t)(row0 + sr) * EE + k0 + sc, &As[sr][sc]);
            stage16_b16((const __hip_bfloat16*)W + (size_t)(col0 + sr) * EE + k0 + sc, &Bs[sr][sc]);
        } else {
            stage16_f32((const float*)x + (size_t)(row0 + sr) * EE + k0 + sc, &As[sr][sc]);
            stage16_f32((const float*)W + (size_t)(col0 + sr) * EE + k0 + sc, &Bs[sr][sc]);
        }
        __syncthreads();
        #pragma unroll
        for (int ks = 0; ks < 2; ++ks) {
            const short8 a = *reinterpret_cast<const short8*>(
                &As[wv * 16 + m16][ks * 32 + quad * 8]);
            #pragma unroll
            for (int nt = 0; nt < 4; ++nt) {
                const short8 b = *reinterpret_cast<const short8*>(
                    &Bs[nt * 16 + m16][ks * 32 + quad * 8]);
                acc[nt] = __builtin_amdgcn_mfma_f32_16x16x32_bf16(a, b, acc[nt], 0, 0, 0);
            }
        }
        __syncthreads();
    }

    if (which == 2) {
        #pragma unroll
        for (int nt = 0; nt < 4; ++nt) {
            const float bb = bias[col0 + nt * 16 + m16];
            #pragma unroll
            for (int r = 0; r < 4; ++r)
                Bs[wv * 16 + quad * 4 + r][nt * 16 + m16] =
                    __float2bfloat16(acc[nt][r] + bb);
        }
        __syncthreads();
        const int bb2 = row0 >> 11;
        const int j0 = row0 & (SS - 1);
        const int er = tid >> 2;
        const int js = (tid & 3) * 16;
        unsigned pk[8];
        #pragma unroll
        for (int p = 0; p < 8; ++p) {
            const unsigned lo = *reinterpret_cast<const unsigned short*>(&Bs[js + 2*p][er]);
            const unsigned hi = *reinterpret_cast<const unsigned short*>(&Bs[js + 2*p + 1][er]);
            pk[p] = lo | (hi << 16);
        }
        uint4 s0; s0.x = pk[0]; s0.y = pk[1]; s0.z = pk[2]; s0.w = pk[3];
        uint4 s1; s1.x = pk[4]; s1.y = pk[5]; s1.z = pk[6]; s1.w = pk[7];
        // j-tiled store: tile jt = (j0+js)>>5 (js%32 in {0,16} -> 16-run stays in-tile)
        __hip_bfloat16* dst = vT +
            (((size_t)(bb2 * SST + ((j0 + js) >> 5)) * EE + col0 + er) * 32 + (js & 31));
        *reinterpret_cast<uint4*>(dst) = s0;
        *reinterpret_cast<uint4*>(dst + 8) = s1;
    } else {
        __hip_bfloat16* C = (which == 0) ? qb : kb;
        #pragma unroll
        for (int nt = 0; nt < 4; ++nt) {
            const int gn = col0 + nt * 16 + m16;
            const float bb = bias[gn];
            #pragma unroll
            for (int r = 0; r < 4; ++r) {
                const int gm = row0 + wv * 16 + quad * 4 + r;
                C[(size_t)gm * EE + gn] = __float2bfloat16(acc[nt][r] + bb);
            }
        }
    }
}

// ---------------- MFMA GEMM (MLP1 / MLP2+combine / out-proj) — R12-verbatim ----------------
template<int MODE, int AB16, int WB16, int CF32>
__global__ __launch_bounds__(256) void gemm_bt(
    const void* __restrict__ Av,
    const void* __restrict__ Wv_,
    const float* __restrict__ bias,
    void* __restrict__ Cv,
    int ldb,
    const __hip_bfloat16* __restrict__ pvPp,
    const int* __restrict__ cntIp,
    const int* __restrict__ slotJp,
    const float* __restrict__ slotWp,
    const float* __restrict__ xf)
{
    __shared__ __hip_bfloat16 As[2][64][72];
    __shared__ __hip_bfloat16 Bs[2][64][72];
    const int tid = threadIdx.x;
    const int col0 = blockIdx.x * 64;
    const int row0 = blockIdx.y * 64;
    const int wv = tid >> 6, lane = tid & 63, quad = lane >> 4, m16 = lane & 15;
    const int sr = tid >> 2;
    const int sc = (tid & 3) * 16;

    f32x4 acc[4];
    #pragma unroll
    for (int nt = 0; nt < 4; ++nt) acc[nt] = (f32x4){0.f, 0.f, 0.f, 0.f};

    {   // prologue: tile 0 -> buffer 0
        if (AB16)
            stage16_b16((const __hip_bfloat16*)Av + (size_t)(row0 + sr) * EE + sc, &As[0][sr][sc]);
        else
            stage16_f32((const float*)Av + (size_t)(row0 + sr) * EE + sc, &As[0][sr][sc]);
        if (WB16)
            stage16_b16((const __hip_bfloat16*)Wv_ + (size_t)(col0 + sr) * ldb + sc, &Bs[0][sr][sc]);
        else
            stage16_f32((const float*)Wv_ + (size_t)(col0 + sr) * ldb + sc, &Bs[0][sr][sc]);
    }

    for (int kt = 0; kt < 8; ++kt) {
        __syncthreads();                       // buffer kt&1 ready
        uint4 ra[2], rb[2];
        float4 fa[4], fb[4];
        if (kt + 1 < 8) {                      // issue-early: next tile -> regs
            const int k0 = (kt + 1) * 64;
            if (AB16) {
                const uint4* s = reinterpret_cast<const uint4*>(
                    (const __hip_bfloat16*)Av + (size_t)(row0 + sr) * EE + k0 + sc);
                ra[0] = s[0]; ra[1] = s[1];
            } else {
                const float4* s = reinterpret_cast<const float4*>(
                    (const float*)Av + (size_t)(row0 + sr) * EE + k0 + sc);
                fa[0] = s[0]; fa[1] = s[1]; fa[2] = s[2]; fa[3] = s[3];
            }
            if (WB16) {
                const uint4* s = reinterpret_cast<const uint4*>(
                    (const __hip_bfloat16*)Wv_ + (size_t)(col0 + sr) * ldb + k0 + sc);
                rb[0] = s[0]; rb[1] = s[1];
            } else {
                const float4* s = reinterpret_cast<const float4*>(
                    (const float*)Wv_ + (size_t)(col0 + sr) * ldb + k0 + sc);
                fb[0] = s[0]; fb[1] = s[1]; fb[2] = s[2]; fb[3] = s[3];
            }
        }
        const int cur = kt & 1;
        #pragma unroll
        for (int ks = 0; ks < 2; ++ks) {
            const short8 a = *reinterpret_cast<const short8*>(
                &As[cur][wv * 16 + m16][ks * 32 + quad * 8]);
            #pragma unroll
            for (int nt = 0; nt < 4; ++nt) {
                const short8 b = *reinterpret_cast<const short8*>(
                    &Bs[cur][nt * 16 + m16][ks * 32 + quad * 8]);
                acc[nt] = __builtin_amdgcn_mfma_f32_16x16x32_bf16(a, b, acc[nt], 0, 0, 0);
            }
        }
        if (kt + 1 < 8) {                      // write-late into the spare buffer
            const int nb = (kt + 1) & 1;
            if (AB16) {
                uint4* d = reinterpret_cast<uint4*>(&As[nb][sr][sc]);
                d[0] = ra[0]; d[1] = ra[1];
            } else pack16(fa, &As[nb][sr][sc]);
            if (WB16) {
                uint4* d = reinterpret_cast<uint4*>(&Bs[nb][sr][sc]);
                d[0] = rb[0]; d[1] = rb[1];
            } else pack16(fb, &Bs[nb][sr][sc]);
        }
    }

    if (MODE == 2) {                           // MLP2 + fused pv-combine
        #pragma unroll
        for (int r = 0; r < 4; ++r) {
            const int gm = row0 + wv * 16 + quad * 4 + r;
            const int cn = cntIp[gm];
            const int bloc = gm >> 11;
            #pragma unroll
            for (int nt = 0; nt < 4; ++nt) {
                const int gn = col0 + nt * 16 + m16;
                const size_t ci = (size_t)gm * EE + gn;
                float c = acc[nt][r] + bias[gn];
                #pragma unroll
                for (int cc = 0; cc < JCP; ++cc)
                    c += b2f(reinterpret_cast<const short*>(pvPp)
                             [(size_t)cc * NN * EE + ci]);
                if (cn > 0) {                  // exact rare path: masked mean
                    const float inv = 1.f / (float)cn;
                    const int ns = cn < 16 ? cn : 16;
                    for (int t = 0; t < ns; ++t) {
                        const int j = slotJp[(size_t)gm * 16 + t];
                        c += slotWp[(size_t)gm * 16 + t] * inv *
                             xf[((size_t)bloc * SS + j) * EE + gn];
                    }
                }
                ((__hip_bfloat16*)Cv)[ci] = __float2bfloat16(c);
            }
        }
        return;
    }

    #pragma unroll
    for (int nt = 0; nt < 4; ++nt) {
        const int gn = col0 + nt * 16 + m16;
        float bb = bias[gn];
        if (MODE == 1) {
            float ts = 0.f;
            #pragma unroll
            for (int h = 0; h < 8; ++h) {
                const size_t wi = (size_t)gn * ldb + 512 + h;
                ts += WB16 ? (float)((const __hip_bfloat16*)Wv_)[wi]
                           : ((const float*)Wv_)[wi];
            }
            bb += ts * (1.0f / (float)SS);
        }
        #pragma unroll
        for (int r = 0; r < 4; ++r) {
            const int gm = row0 + wv * 16 + quad * 4 + r;
            const size_t ci = (size_t)gm * EE + gn;
            float c = acc[nt][r] + bb;
            if (MODE == 1) c = 0.5f * c * (1.0f + erff(c * 0.70710678118654752f));
            if (CF32) ((float*)Cv)[ci] = c;
            else      ((__hip_bfloat16*)Cv)[ci] = __float2bfloat16(c);
        }
    }
}

// ---------------- K1: partial softmax denominators (R13-verbatim) ----------------
__global__ __launch_bounds__(256) void attn_denoms(
    const __hip_bfloat16* __restrict__ qws,
    const __hip_bfloat16* __restrict__ kws,
    float* __restrict__ dnP,
    int* __restrict__ cntI)
{
    __shared__ __hip_bfloat16 KL[2][16][520];   // 33.3 KB
    const int tid = threadIdx.x;
    const int wv = tid >> 6, lane = tid & 63, quad = lane >> 4, m16 = lane & 15;
    const int jc = blockIdx.x;              // 8 chunks x 256 j
    const int it = blockIdx.y;              // 64 tiles x 32 i
    const int b  = blockIdx.z;
    const size_t g0 = (size_t)b * SS + it * 32;
    const size_t gb = (size_t)b * SS;
    const int ih = wv & 1, hh = wv >> 1;

    if (jc == 0 && tid < 32) cntI[g0 + tid] = 0;

    short8 aq[4][2];
    #pragma unroll
    for (int hp = 0; hp < 4; ++hp)
        #pragma unroll
        for (int ks = 0; ks < 2; ++ks)
            aq[hp][ks] = *reinterpret_cast<const short8*>(
                qws + (g0 + ih * 16 + m16) * EE + (hh * 4 + hp) * 64 + ks * 32 + quad * 8);

    float dph[4][4];
    #pragma unroll
    for (int hp = 0; hp < 4; ++hp)
        #pragma unroll
        for (int r = 0; r < 4; ++r) dph[hp][r] = 0.f;

    {   // prologue: tile 0 -> KL[0]; each wave stages 4 rows (1 DMA per row)
        #pragma unroll
        for (int rr = 0; rr < 4; ++rr) {
            const int row = wv * 4 + rr;
            const __hip_bfloat16* g = kws + (gb + jc * 256 + row) * EE + lane * 8;
            __builtin_amdgcn_global_load_lds(
                (gu32*)(const void*)g, (lu32*)(void*)&KL[0][row][0], 16, 0, 0);
        }
    }

    for (int jt = 0; jt < 16; ++jt) {
        __syncthreads();                       // vmcnt drained: KL[jt&1] ready
        if (jt + 1 < 16) {                     // issue next tile into spare buffer
            #pragma unroll
            for (int rr = 0; rr < 4; ++rr) {
                const int row = wv * 4 + rr;
                const __hip_bfloat16* g =
                    kws + (gb + jc * 256 + (jt + 1) * 16 + row) * EE + lane * 8;
                __builtin_amdgcn_global_load_lds(
                    (gu32*)(const void*)g,
                    (lu32*)(void*)&KL[(jt + 1) & 1][row][0], 16, 0, 0);
            }
        }
        __builtin_amdgcn_s_setprio(1);
        #pragma unroll
        for (int hp = 0; hp < 4; ++hp) {
            const short8 b0 = *reinterpret_cast<const short8*>(
                &KL[jt & 1][m16][(hh * 4 + hp) * 64 + quad * 8]);
            const short8 b1 = *reinterpret_cast<const short8*>(
                &KL[jt & 1][m16][(hh * 4 + hp) * 64 + 32 + quad * 8]);
            f32x4 c = {0.f, 0.f, 0.f, 0.f};
            c = __builtin_amdgcn_mfma_f32_16x16x32_bf16(aq[hp][0], b0, c, 0, 0, 0);
            c = __builtin_amdgcn_mfma_f32_16x16x32_bf16(aq[hp][1], b1, c, 0, 0, 0);
            #pragma unroll
            for (int r = 0; r < 4; ++r) dph[hp][r] += __expf(c[r] * 0.125f);
        }
        __builtin_amdgcn_s_setprio(0);
    }

    #pragma unroll
    for (int hp = 0; hp < 4; ++hp)
        #pragma unroll
        for (int off = 1; off <= 8; off <<= 1)
            #pragma unroll
            for (int r = 0; r < 4; ++r) dph[hp][r] += __shfl_xor(dph[hp][r], off, 64);
    if (m16 == 0) {
        const size_t i = (size_t)it * 32 + ih * 16 + quad * 4;
        #pragma unroll
        for (int hp = 0; hp < 4; ++hp)
            #pragma unroll
            for (int r = 0; r < 4; ++r)
                dnP[((size_t)(jc * BB + b) * SS + i + r) * HH + hh * 4 + hp] = dph[hp][r];
    }
}

// ---------------- K2: fused ew + PV (R15 + V issue-early) ----------------
// R15's pipeline with ONE change: vb[8] global loads issue BEFORE the barrier
// (right after ewT/slot writes). The barrier's vmcnt(0) drain already waits on
// the K-DMA prefetch, so the V loads ride the same drain -> PV finds vb in
// registers with zero exposed latency (was ~200cy naked L2 round-trip x16).
// No hazard: vb is global-only. Cost: +16 VGPR across barrier (budget 256).
__global__ __launch_bounds__(256, 2) void attn_ewpv(
    const __hip_bfloat16* __restrict__ qws,
    const __hip_bfloat16* __restrict__ kws,
    const __hip_bfloat16* __restrict__ vTg,
    const float* __restrict__ dnP,
    int* __restrict__ cntI,
    int* __restrict__ slotJ,
    float* __restrict__ slotW,
    __hip_bfloat16* __restrict__ pvP)
{
    __shared__ __hip_bfloat16 KL[2][32][520];  // 66.6 KB (KL[0] = epilogue bounce)
    __shared__ __hip_bfloat16 ewTd[2][32][40]; // 5.1 KB
    __shared__ float invd[HH][32];             // 1 KB
    const int tid = threadIdx.x;
    const int wv = tid >> 6, lane = tid & 63, quad = lane >> 4, m16 = lane & 15;
    const int jc = blockIdx.x;               // 4 chunks x 512 j
    const int it = blockIdx.y;               // 64 tiles x 32 i
    const int b  = blockIdx.z;
    const size_t gb = (size_t)b * SS;
    const size_t g0 = gb + it * 32;
    const int ih = wv & 1;                   // i-half for score phase
    const int jh = wv >> 1;                  // j-half for score phase

    {   // denominators -> 0.125/D (head-mean folded in); 256 thr = HH*32 exactly
        const int h = tid >> 5, i = tid & 31;
        float s = 0.f;
        #pragma unroll
        for (int c = 0; c < JC1; ++c)
            s += dnP[((size_t)(c * BB + b) * SS + it * 32 + i) * HH + h];
        invd[h][i] = 0.125f / s;
    }

    short8 aq[HH][2];
    #pragma unroll
    for (int h = 0; h < HH; ++h)
        #pragma unroll
        for (int ks = 0; ks < 2; ++ks)
            aq[h][ks] = *reinterpret_cast<const short8*>(
                qws + (g0 + ih * 16 + m16) * EE + h * 64 + ks * 32 + quad * 8);

    f32x4 acc[2][8];
    #pragma unroll
    for (int mf = 0; mf < 2; ++mf)
        #pragma unroll
        for (int nf = 0; nf < 8; ++nf) acc[mf][nf] = (f32x4){0.f, 0.f, 0.f, 0.f};

    // j-tiled V: lane base for subtile jt = jc*16+st:
    //   vTg + ((b*SST + jt)*EE + wv*128 + m16)*32 + quad*8; vb[nf] at +nf*512
    const __hip_bfloat16* vtile0 =
        vTg + (((size_t)b * SST + jc * 16) * EE + wv * 128 + m16) * 32 + quad * 8;

    {   // prologue: K subtile 0 -> KL[0] (8 DMAs per wave, 1 per row)
        #pragma unroll
        for (int rr = 0; rr < 8; ++rr) {
            const int row = wv * 8 + rr;
            const __hip_bfloat16* g = kws + (gb + jc * 512 + row) * EE + lane * 8;
            __builtin_amdgcn_global_load_lds(
                (gu32*)(const void*)g, (lu32*)(void*)&KL[0][row][0], 16, 0, 0);
        }
    }
    __syncthreads();                           // KL[0] + invd ready

    for (int st = 0; st < 16; ++st) {
        const int j0 = jc * 512 + st * 32;
        const int cur = st & 1;
        if (st + 1 < 16) {                     // issue-early: next K subtile DMAs
            #pragma unroll
            for (int rr = 0; rr < 8; ++rr) {
                const int row = wv * 8 + rr;
                const __hip_bfloat16* g = kws + (gb + j0 + 32 + row) * EE + lane * 8;
                __builtin_amdgcn_global_load_lds(
                    (gu32*)(const void*)g,
                    (lu32*)(void*)&KL[cur ^ 1][row][0], 16, 0, 0);
            }
        }

        // scores: wave's (ih, jh) quadrant of the 32x32 tile, all heads
        float wsum[4] = {0.f, 0.f, 0.f, 0.f};
        __builtin_amdgcn_s_setprio(1);
        #pragma unroll
        for (int h = 0; h < HH; ++h) {
            const short8 b0 = *reinterpret_cast<const short8*>(
                &KL[cur][jh * 16 + m16][h * 64 + quad * 8]);
            const short8 b1 = *reinterpret_cast<const short8*>(
                &KL[cur][jh * 16 + m16][h * 64 + 32 + quad * 8]);
            f32x4 c = {0.f, 0.f, 0.f, 0.f};
            c = __builtin_amdgcn_mfma_f32_16x16x32_bf16(aq[h][0], b0, c, 0, 0, 0);
            c = __builtin_amdgcn_mfma_f32_16x16x32_bf16(aq[h][1], b1, c, 0, 0, 0);
            #pragma unroll
            for (int r = 0; r < 4; ++r)
                wsum[r] += __expf(c[r] * 0.125f) * invd[h][ih * 16 + quad * 4 + r];
        }
        __builtin_amdgcn_s_setprio(0);
        #pragma unroll
        for (int r = 0; r < 4; ++r) {
            const __hip_bfloat16 wb = __float2bfloat16(wsum[r]);
            ewTd[cur][ih * 16 + quad * 4 + r][jh * 16 + m16] = wb;
            if ((float)wb > 0.1f) {            // rare: adjacency crossing
                const int li = ih * 16 + quad * 4 + r;
                const int idx = atomicAdd(&cntI[g0 + li], 1);
                if (idx < 16) {
                    slotJ[((size_t)g0 + li) * 16 + idx] = j0 + jh * 16 + m16;
                    slotW[((size_t)g0 + li) * 16 + idx] = (float)wb;
                }
            }
        }

        // issue-early: V B-frags for THIS step (drain rides the barrier's vmcnt)
        short8 vb[8];
        {
            const __hip_bfloat16* vt = vtile0 + (size_t)st * EE * 32;
            #pragma unroll
            for (int nf = 0; nf < 8; ++nf)
                vb[nf] = *reinterpret_cast<const short8*>(vt + nf * 512);
        }
        __syncthreads();   // publishes ewTd[cur], KL[cur^1]; vb loads drained too

        // PV: vb already in registers; consume immediately
        {
            const short8 a0 = *reinterpret_cast<const short8*>(&ewTd[cur][m16][quad * 8]);
            const short8 a1 = *reinterpret_cast<const short8*>(&ewTd[cur][16 + m16][quad * 8]);
            __builtin_amdgcn_s_setprio(1);
            #pragma unroll
            for (int nf = 0; nf < 8; ++nf) {
                acc[0][nf] = __builtin_amdgcn_mfma_f32_16x16x32_bf16(a0, vb[nf], acc[0][nf], 0, 0, 0);
                acc[1][nf] = __builtin_amdgcn_mfma_f32_16x16x32_bf16(a1, vb[nf], acc[1][nf], 0, 0, 0);
            }
            __builtin_amdgcn_s_setprio(0);
        }
    }

    // epilogue: bounce acc through KL[0] for coalesced bf16 writes
    #pragma unroll
    for (int mf = 0; mf < 2; ++mf)
        #pragma unroll
        for (int nf = 0; nf < 8; ++nf)
            #pragma unroll
            for (int r = 0; r < 4; ++r)
                KL[0][mf * 16 + quad * 4 + r][wv * 128 + nf * 16 + m16] =
                    __float2bfloat16(acc[mf][nf][r]);
    __syncthreads();
    const int orow = tid >> 3;
    const int oc = (tid & 7) * 64;
    const uint4* s = reinterpret_cast<const uint4*>(&KL[0][orow][oc]);
    uint4* d = reinterpret_cast<uint4*>(
        pvP + ((size_t)jc * NN + g0 + orow) * EE + oc);
    #pragma unroll
    for (int q = 0; q < 8; ++q) d[q] = s[q];
}

extern "C" void kernel_launch(void* const* d_in, const int* in_sizes, int n_in,
                              void* d_out, int out_size, void* d_ws, size_t ws_size,
                              hipStream_t stream)
{
    const float* x   = (const float*)d_in[0];
    const float* Wq  = (const float*)d_in[1];
    const float* bq  = (const float*)d_in[2];
    const float* Wk  = (const float*)d_in[3];
    const float* bk  = (const float*)d_in[4];
    const float* Wv  = (const float*)d_in[5];
    const float* bv  = (const float*)d_in[6];
    const float* Wm1 = (const float*)d_in[7];
    const float* bm1 = (const float*)d_in[8];
    const float* Wm2 = (const float*)d_in[9];
    const float* bm2 = (const float*)d_in[10];
    const float* Wo  = (const float*)d_in[11];
    const float* bo  = (const float*)d_in[12];

    char* ws = (char*)d_ws;
    const size_t MB = 1024 * 1024;
    __hip_bfloat16* qb = (__hip_bfloat16*)(ws + 0);        // q            4MB
    __hip_bfloat16* kb = (__hip_bfloat16*)(ws + 4*MB);     // k -> hm      4MB
    __hip_bfloat16* vT = (__hip_bfloat16*)(ws + 8*MB);     // V j-tiled [b][j/32][e][j%32] 4MB
    __hip_bfloat16* pvP = (__hip_bfloat16*)(ws + 12*MB);   // PV partials [4][NN][EE] 16MB
    float* dnP = (float*)(ws + 28*MB);                     // denom partials 1MB
    int*   cntI = (int*)(ws + 29*MB);                      // neighbor cnt  16KB
    int*   slotJ = (int*)(ws + 29*MB + 64*1024);           // crossing j    256KB
    float* slotW = (float*)(ws + 29*MB + 384*1024);        // crossing w    256KB
    const bool EXT = (ws_size >= 38 * MB);
    __hip_bfloat16* xb   = (__hip_bfloat16*)(ws + 30*MB);          // 4MB
    __hip_bfloat16* wqb  = (__hip_bfloat16*)(ws + 34*MB);
    __hip_bfloat16* wkb  = (__hip_bfloat16*)(ws + 34*MB + 512*1024);
    __hip_bfloat16* wvb  = (__hip_bfloat16*)(ws + 35*MB);
    __hip_bfloat16* wm1b = (__hip_bfloat16*)(ws + 35*MB + 512*1024);
    __hip_bfloat16* wm2b = (__hip_bfloat16*)(ws + 36*MB + 256*1024);
    __hip_bfloat16* wob  = (__hip_bfloat16*)(ws + 36*MB + 768*1024);

    dim3 blk(256, 1, 1);
    dim3 gg(EE / 64, NN / 64, 1);

    if (EXT) {
        conv_bf16<<<dim3(2048, 7, 1), blk, 0, stream>>>(
            x, Wq, Wk, Wv, Wm1, Wm2, Wo, xb, wqb, wkb, wvb, wm1b, wm2b, wob);
        qkv_gemm<1><<<dim3(24, NN / 64, 1), blk, 0, stream>>>(
            xb, wqb, bq, wkb, bk, wvb, bv, qb, kb, vT);
    } else {
        qkv_gemm<0><<<dim3(24, NN / 64, 1), blk, 0, stream>>>(
            x, Wq, bq, Wk, bk, Wv, bv, qb, kb, vT);
    }
    attn_denoms<<<dim3(JC1, SS / 32, BB), blk, 0, stream>>>(qb, kb, dnP, cntI);
    attn_ewpv<<<dim3(JCP, SS / 32, BB), blk, 0, stream>>>(
        qb, kb, vT, dnP, cntI, slotJ, slotW, pvP);
    if (EXT) {
        gemm_bt<1,1,1,0><<<gg, blk, 0, stream>>>(xb, wm1b, bm1, kb, EE + HH,
            nullptr, nullptr, nullptr, nullptr, nullptr);
        gemm_bt<2,1,1,0><<<gg, blk, 0, stream>>>(kb, wm2b, bm2, qb, EE,
            pvP, cntI, slotJ, slotW, x);
        gemm_bt<0,1,1,1><<<gg, blk, 0, stream>>>(qb, wob, bo, d_out, EE,
            nullptr, nullptr, nullptr, nullptr, nullptr);
    } else {
        gemm_bt<1,0,0,0><<<gg, blk, 0, stream>>>(x, Wm1, bm1, kb, EE + HH,
            nullptr, nullptr, nullptr, nullptr, nullptr);
        gemm_bt<2,1,0,0><<<gg, blk, 0, stream>>>(kb, Wm2, bm2, qb, EE,
            pvP, cntI, slotJ, slotW, x);
        gemm_bt<0,1,0,1><<<gg, blk, 0, stream>>>(qb, Wo, bo, d_out, EE,
            nullptr, nullptr, nullptr, nullptr, nullptr);
    }
}